// Round 8
// baseline (2458.525 us; speedup 1.0000x reference)
//
#include <hip/hip_runtime.h>
#include <math.h>

#define NS 16
#define NC 4
#define NH 256
#define BATCH 262144
#define EPB 16      // elements per block
#define HSTR 264    // LDS row stride in halves (528 B); 4-bank rotation/row (no swizzle — R6)

typedef _Float16 half8 __attribute__((ext_vector_type(8)));
typedef _Float16 half4v __attribute__((ext_vector_type(4)));
typedef _Float16 half2v __attribute__((ext_vector_type(2)));
typedef float f32x4 __attribute__((ext_vector_type(4)));

#define MFMA16(a, b, c) __builtin_amdgcn_mfma_f32_16x16x32_f16((a), (b), (c), 0, 0, 0)

// ---------- ws layout (in halves) ----------
#define OFF_W2HI   0
#define OFF_W2LO   65536
#define OFF_W3HI   131072
#define OFF_W3LO   196608
#define OFF_W2THI  262144
#define OFF_W2TLO  327680
#define OFF_W3THI  393216
#define OFF_W3TLO  458752
#define OFF_W1PHI  524288
#define OFF_W1PLO  532480
#define OFF_W1THI  540672
#define OFF_W1TLO  544768
#define OFF_W4HI   548864
#define OFF_W4LO   552960
#define WS_HALVES  557056   // * 2 bytes = 1,114,112

__device__ __forceinline__ float logsigf(float a) {
    return fminf(a, 0.f) - __logf(1.f + __expf(-fabsf(a)));
}
__device__ __forceinline__ float siggf(float a) {   // sigma(-a)
    return 1.f / (1.f + __expf(a));
}
__device__ __forceinline__ void split2(float x, _Float16& h, _Float16& l) {
    h = (_Float16)x;
    l = (_Float16)(x - (float)h);
}
__device__ __forceinline__ float wsum16(float v) {
    v += __shfl_xor(v, 1, 64);
    v += __shfl_xor(v, 2, 64);
    v += __shfl_xor(v, 4, 64);
    v += __shfl_xor(v, 8, 64);
    return v;
}
__device__ __forceinline__ unsigned h2u(half2v h) {
    union { half2v h; unsigned u; } c; c.h = h; return c.u;
}
__device__ __forceinline__ half2v u2h(unsigned u) {
    union { half2v h; unsigned u; } c; c.u = u; return c.h;
}
__device__ __forceinline__ uint2 packg(const float g[4]) {
    half2v a, b;
    a[0] = (_Float16)g[0]; a[1] = (_Float16)g[1];
    b[0] = (_Float16)g[2]; b[1] = (_Float16)g[3];
    return make_uint2(h2u(a), h2u(b));
}

// ---------------- prep kernels ----------------
extern "C" __global__ void __launch_bounds__(256)
prep_big(const float* __restrict__ W2, const float* __restrict__ W3,
         _Float16* __restrict__ ws) {
    const int mat = blockIdx.y;
    const float* W = mat ? W3 : W2;
    _Float16* Whi  = ws + (mat ? OFF_W3HI  : OFF_W2HI);
    _Float16* Wlo  = Whi + 65536;
    _Float16* WThi = ws + (mat ? OFF_W3THI : OFF_W2THI);
    _Float16* WTlo = WThi + 65536;
    const int r = blockIdx.x, c = threadIdx.x;
    float x = W[r * NH + c];
    _Float16 h, l; split2(x, h, l);
    Whi[r * NH + c] = h;  Wlo[r * NH + c] = l;
    WThi[c * NH + r] = h; WTlo[c * NH + r] = l;
}

extern "C" __global__ void __launch_bounds__(256)
prep_small(const float* __restrict__ W1, const float* __restrict__ W4,
           _Float16* __restrict__ ws) {
    _Float16* W1phi = ws + OFF_W1PHI;
    _Float16* W1plo = ws + OFF_W1PLO;
    _Float16* W1Thi = ws + OFF_W1THI;
    _Float16* W1Tlo = ws + OFF_W1TLO;
    _Float16* W4hi  = ws + OFF_W4HI;
    _Float16* W4lo  = ws + OFF_W4LO;
    const int t = threadIdx.x;   // 0..255 (= W1 row)
    #pragma unroll
    for (int s = 0; s < NS; s++) {
        float x = W1[t * NS + s];
        _Float16 h, l; split2(x, h, l);
        W1phi[t * 32 + s] = h;        W1plo[t * 32 + s] = l;
        W1phi[t * 32 + 16 + s] = (_Float16)0.f;
        W1plo[t * 32 + 16 + s] = (_Float16)0.f;
        W1Thi[s * NH + t] = h;        W1Tlo[s * NH + t] = l;
    }
    #pragma unroll
    for (int q = 0; q < 16; q++) {
        int idx = q * 256 + t;       // covers rows 0..15 of W4
        float x = W4[idx];
        _Float16 h, l; split2(x, h, l);
        W4hi[idx] = h; W4lo[idx] = l;
    }
}

// ---------------- main fused MFMA kernel ----------------
// 256 threads = 4 waves, EPB=16. Wave w owns hidden rows 64w..64w+63
// (4 m-tiles). Forward N=16 (1 e-tile), 3-term f16-split. Backward:
// 2 passes x 8 elems (32 cotangent cols = 2 n-tiles), single-term f16,
// acc2[4][2]=32 AGPR. Gates packed f16x2 in uint2 (24 arch regs).
// LDS ~25.5 KB. Small blocks quantize CU residency better: at ~160
// total regs -> 12 waves/CU -> 3 independent blocks (vs R7's 1x8-wave
// block); their barrier drains overlap other blocks' MFMA bursts.

__device__ __forceinline__ void gemm_fwd(const _Float16* __restrict__ Ahi,
                                         const _Float16* __restrict__ Alo,
                                         const _Float16* U,
                                         int w, int lo16, int hi4, f32x4 acc[4]) {
    #pragma unroll
    for (int ks = 0; ks < 8; ks++) {
        int boff = lo16 * HSTR + ks * 32 + hi4 * 8;
        half8 bh = *(const half8*)&U[boff];
        half8 bl = *(const half8*)&U[16 * HSTR + boff];
        #pragma unroll
        for (int m = 0; m < 4; m++) {
            int woff = (64 * w + 16 * m + lo16) * NH + ks * 32 + hi4 * 8;
            half8 ah = *(const half8*)&Ahi[woff];
            half8 al = *(const half8*)&Alo[woff];
            acc[m] = MFMA16(ah, bh, acc[m]);
            acc[m] = MFMA16(al, bh, acc[m]);
            acc[m] = MFMA16(ah, bl, acc[m]);
        }
    }
}

// single-term f16 backward GEMM: A = W^T hi only, B = M hi only, 2 n-tiles
__device__ __forceinline__ void gemm_bwd1(const _Float16* __restrict__ Ahi,
                                          const _Float16* U,
                                          int w, int lo16, int hi4, f32x4 acc[4][2]) {
    #pragma unroll
    for (int ks = 0; ks < 8; ks++) {
        half8 bh[2];
        #pragma unroll
        for (int n = 0; n < 2; n++)
            bh[n] = *(const half8*)&U[(16 * n + lo16) * HSTR + ks * 32 + hi4 * 8];
        #pragma unroll
        for (int m = 0; m < 4; m++) {
            int woff = (64 * w + 16 * m + lo16) * NH + ks * 32 + hi4 * 8;
            half8 ah = *(const half8*)&Ahi[woff];
            #pragma unroll
            for (int n = 0; n < 2; n++)
                acc[m][n] = MFMA16(ah, bh[n], acc[m][n]);
        }
    }
}

__global__ void __launch_bounds__(256, 3)
comet_mfma(const float* __restrict__ Z,
           const float* __restrict__ W4,
           const _Float16* __restrict__ ws,
           float* __restrict__ OUT)
{
    const _Float16* W2hi  = ws + OFF_W2HI;
    const _Float16* W2lo  = ws + OFF_W2LO;
    const _Float16* W3hi  = ws + OFF_W3HI;
    const _Float16* W3lo  = ws + OFF_W3LO;
    const _Float16* W2Thi = ws + OFF_W2THI;
    const _Float16* W3Thi = ws + OFF_W3THI;
    const _Float16* W1phi = ws + OFF_W1PHI;
    const _Float16* W1plo = ws + OFF_W1PLO;
    const _Float16* W1Thi = ws + OFF_W1THI;
    const _Float16* W4hi  = ws + OFF_W4HI;
    const _Float16* W4lo  = ws + OFF_W4LO;

    // union: forward H-hi rows 0..15 (by elem), H-lo rows 16..31;
    // backward M-hi rows 0..31 (by cotangent col)
    __shared__ __align__(16) _Float16 U[32 * HSTR];    // 16,896 B
    __shared__ __align__(16) float Jfin[16 * 66];      //  4,224 B
    __shared__ __align__(16) float Db[4 * 272];        //  4,352 B

    const int tid  = threadIdx.x;
    const int l    = tid & 63, w = tid >> 6;
    const int lo16 = l & 15, hi4 = l >> 4;
    const int ebase = blockIdx.x * EPB;
    const int c4 = lo16 & 3;

    // ---- V (rows 16..19 of W4) in registers: 4 m-tiles ----
    float4 vreg[4];
    #pragma unroll
    for (int m = 0; m < 4; m++)
        vreg[m] = *(const float4*)&W4[(NS + c4) * NH + 64 * w + 16 * m + 4 * hi4];

    uint2 g1u[4], g2u[4], g3u[4];   // packed f16 gates [m], 4 r-values each

    // ---- F1 : a1 = W1p @ Zpad ; B-frag direct from global ----
    {
        f32x4 acc[4];
        #pragma unroll
        for (int m = 0; m < 4; m++) acc[m] = (f32x4)(0.f);
        half8 bh, bl;
        if (hi4 < 2) {
            const float* zp = &Z[(size_t)(ebase + lo16) * NS + hi4 * 8];
            float4 z0 = *(const float4*)zp;
            float4 z1 = *(const float4*)(zp + 4);
            float zz[8] = {z0.x, z0.y, z0.z, z0.w, z1.x, z1.y, z1.z, z1.w};
            #pragma unroll
            for (int r = 0; r < 8; r++) {
                _Float16 h, lo; split2(zz[r], h, lo);
                bh[r] = h; bl[r] = lo;
            }
        } else {
            #pragma unroll
            for (int r = 0; r < 8; r++) { bh[r] = (_Float16)0.f; bl[r] = (_Float16)0.f; }
        }
        #pragma unroll
        for (int m = 0; m < 4; m++) {
            int woff = (64 * w + 16 * m + lo16) * 32 + hi4 * 8;
            half8 ah = *(const half8*)&W1phi[woff];
            half8 al = *(const half8*)&W1plo[woff];
            acc[m] = MFMA16(ah, bh, acc[m]);
            acc[m] = MFMA16(al, bh, acc[m]);
            acc[m] = MFMA16(ah, bl, acc[m]);
        }
        #pragma unroll
        for (int m = 0; m < 4; m++) {
            int hoff = lo16 * HSTR + 64 * w + 16 * m + 4 * hi4;
            float gv[4];
            half4v nh, nl;
            #pragma unroll
            for (int r = 0; r < 4; r++) {
                float a = acc[m][r];
                gv[r] = siggf(a);
                float hv = logsigf(a);
                _Float16 xh, xl; split2(hv, xh, xl);
                nh[r] = xh; nl[r] = xl;
            }
            g1u[m] = packg(gv);
            *(half4v*)&U[hoff] = nh;
            *(half4v*)&U[16 * HSTR + hoff] = nl;
        }
    }
    __syncthreads();

    // ---- F2, F3 ----
    #pragma unroll
    for (int L = 0; L < 2; L++) {
        f32x4 acc[4];
        #pragma unroll
        for (int m = 0; m < 4; m++) acc[m] = (f32x4)(0.f);
        gemm_fwd(L ? W3hi : W2hi, L ? W3lo : W2lo, U, w, lo16, hi4, acc);
        __syncthreads();   // all reads of H done before update
        #pragma unroll
        for (int m = 0; m < 4; m++) {
            int hoff = lo16 * HSTR + 64 * w + 16 * m + 4 * hi4;
            half4v oh = *(const half4v*)&U[hoff];
            half4v ol = *(const half4v*)&U[16 * HSTR + hoff];
            float gv[4];
            half4v nh, nl;
            #pragma unroll
            for (int r = 0; r < 4; r++) {
                float a = acc[m][r];
                gv[r] = siggf(a);
                float hv = (float)oh[r] + (float)ol[r] + logsigf(a);
                _Float16 xh, xl; split2(hv, xh, xl);
                nh[r] = xh; nl[r] = xl;
            }
            if (L) g3u[m] = packg(gv); else g2u[m] = packg(gv);
            *(half4v*)&U[hoff] = nh;
            *(half4v*)&U[16 * HSTR + hoff] = nl;
        }
        __syncthreads();
    }

    // ---- F4 : d = W4[0:16] @ h3 ; wave w does ks = 2w, 2w+1 (3-term) ----
    {
        f32x4 acc = (f32x4)(0.f);
        #pragma unroll
        for (int i = 0; i < 2; i++) {
            int ks = 2 * w + i;
            int boff = lo16 * HSTR + ks * 32 + hi4 * 8;
            half8 bh = *(const half8*)&U[boff];
            half8 bl = *(const half8*)&U[16 * HSTR + boff];
            int woff = lo16 * NH + ks * 32 + hi4 * 8;
            half8 ah = *(const half8*)&W4hi[woff];
            half8 al = *(const half8*)&W4lo[woff];
            acc = MFMA16(ah, bh, acc);
            acc = MFMA16(al, bh, acc);
            acc = MFMA16(ah, bl, acc);
        }
        #pragma unroll
        for (int r = 0; r < 4; r++)
            Db[w * 272 + lo16 * 17 + 4 * hi4 + r] = acc[r];   // [w][e][s]
    }
    __syncthreads();   // H (union) dead; M may be written

    // ---- backward: 2 passes x 8 elems (32 cotangent cols), f16-single ----
    #pragma unroll
    for (int p = 0; p < 2; p++) {
        // m3 = V .* d3
        #pragma unroll
        for (int m = 0; m < 4; m++)
            #pragma unroll
            for (int n = 0; n < 2; n++) {
                const int src = (l & 48) | (8 * p + 4 * n + (lo16 >> 2));
                unsigned ux = (unsigned)__shfl((int)g3u[m].x, src, 64);
                unsigned uy = (unsigned)__shfl((int)g3u[m].y, src, 64);
                half2v h0 = u2h(ux), h1 = u2h(uy);
                float g[4] = {(float)h0[0], (float)h0[1], (float)h1[0], (float)h1[1]};
                half4v vh;
                #pragma unroll
                for (int r = 0; r < 4; r++)
                    vh[r] = (_Float16)(vreg[m][r] * g[r]);
                *(half4v*)&U[(16 * n + lo16) * HSTR + 64 * w + 16 * m + 4 * hi4] = vh;
            }
        __syncthreads();

        // B3: G2 = W3^T @ m3  (single-term)
        f32x4 acc2[4][2];
        #pragma unroll
        for (int m = 0; m < 4; m++)
            #pragma unroll
            for (int n = 0; n < 2; n++) acc2[m][n] = (f32x4)(0.f);
        gemm_bwd1(W3Thi, U, w, lo16, hi4, acc2);
        __syncthreads();   // readers of m3 done

        // g2 = V + G2 (f32 skip, exact) ; m2 = g2 .* d2 ; keep g2 in acc2
        #pragma unroll
        for (int m = 0; m < 4; m++)
            #pragma unroll
            for (int n = 0; n < 2; n++) {
                const int src = (l & 48) | (8 * p + 4 * n + (lo16 >> 2));
                unsigned ux = (unsigned)__shfl((int)g2u[m].x, src, 64);
                unsigned uy = (unsigned)__shfl((int)g2u[m].y, src, 64);
                half2v h0 = u2h(ux), h1 = u2h(uy);
                float g[4] = {(float)h0[0], (float)h0[1], (float)h1[0], (float)h1[1]};
                half4v vh;
                #pragma unroll
                for (int r = 0; r < 4; r++) {
                    float gg2 = vreg[m][r] + acc2[m][n][r];
                    acc2[m][n][r] = gg2;
                    vh[r] = (_Float16)(gg2 * g[r]);
                }
                *(half4v*)&U[(16 * n + lo16) * HSTR + 64 * w + 16 * m + 4 * hi4] = vh;
            }
        __syncthreads();

        // B2: g1tot = g2 + W2^T @ m2  (single-term, accumulate onto acc2)
        gemm_bwd1(W2Thi, U, w, lo16, hi4, acc2);
        __syncthreads();

        // m1 = g1tot .* d1
        #pragma unroll
        for (int m = 0; m < 4; m++)
            #pragma unroll
            for (int n = 0; n < 2; n++) {
                const int src = (l & 48) | (8 * p + 4 * n + (lo16 >> 2));
                unsigned ux = (unsigned)__shfl((int)g1u[m].x, src, 64);
                unsigned uy = (unsigned)__shfl((int)g1u[m].y, src, 64);
                half2v h0 = u2h(ux), h1 = u2h(uy);
                float g[4] = {(float)h0[0], (float)h0[1], (float)h1[0], (float)h1[1]};
                half4v vh;
                #pragma unroll
                for (int r = 0; r < 4; r++)
                    vh[r] = (_Float16)(acc2[m][n][r] * g[r]);
                *(half4v*)&U[(16 * n + lo16) * HSTR + 64 * w + 16 * m + 4 * hi4] = vh;
            }
        __syncthreads();

        // J: J_p = W1^T @ m1 ; waves 0,1 full-K (single-term), direct Jfin
        if (w < 2) {
            f32x4 accj = (f32x4)(0.f);
            #pragma unroll
            for (int ks = 0; ks < 8; ks++) {
                int boff = (16 * w + lo16) * HSTR + ks * 32 + hi4 * 8;
                half8 bh = *(const half8*)&U[boff];
                int woff = lo16 * NH + ks * 32 + hi4 * 8;
                half8 ah = *(const half8*)&W1Thi[woff];
                accj = MFMA16(ah, bh, accj);
            }
            #pragma unroll
            for (int r = 0; r < 4; r++)
                Jfin[(4 * hi4 + r) * 66 + 32 * p + 16 * w + lo16] = accj[r];
        }
        __syncthreads();
    }

    // ---- projection: e = 4w + hi4, s = lo16 ----
    {
        const int e = 4 * w + hi4, s = lo16;
        float acol[4];
        #pragma unroll
        for (int c = 0; c < 4; c++) acol[c] = Jfin[s * 66 + 4 * e + c];
        float dval = Db[e * 17 + s] + Db[272 + e * 17 + s]
                   + Db[544 + e * 17 + s] + Db[816 + e * 17 + s];
        #pragma unroll
        for (int c = 0; c < 4; c++) {
            float n2 = wsum16(acol[c] * acol[c]);
            float inv = (n2 > 1e-30f) ? (1.0f / sqrtf(n2)) : 0.0f;
            float q = acol[c] * inv;
            #pragma unroll
            for (int cc = c + 1; cc < 4; cc++) {
                float pj = wsum16(acol[cc] * q);
                acol[cc] -= pj * q;
            }
            float pd = wsum16(dval * q);
            dval -= pd * q;
        }
        OUT[(size_t)(ebase + e) * NS + s] = dval;
    }
}

// ---------------- f32 fallback (round-1 kernel) ----------------
__device__ __forceinline__ float dot4f(float4 a, float4 b) {
    return a.x*b.x + a.y*b.y + a.z*b.z + a.w*b.w;
}

__global__ void __launch_bounds__(256, 2)
comet_fused_f32(const float* __restrict__ Z,
                const float* __restrict__ W1,
                const float* __restrict__ W2,
                const float* __restrict__ W3,
                const float* __restrict__ W4,
                float* __restrict__ OUT)
{
    __shared__ __align__(16) float h_lds[4][4][NH];
    __shared__ __align__(16) float m_lds[4][4][NH][NC];

    const int l = threadIdx.x & 63;
    const int w = threadIdx.x >> 6;
    float (*hb)[NH]     = h_lds[w];
    float (*mb)[NH][NC] = m_lds[w];
    const int ebase = (blockIdx.x * 4 + w) * 4;

    float d1g[4][4], d2g[4][4], d3g[4][4];

    {
        float acc[4][4];
        #pragma unroll
        for (int j = 0; j < 4; j++)
            #pragma unroll
            for (int e = 0; e < 4; e++) acc[j][e] = 0.f;
        #pragma unroll
        for (int s4 = 0; s4 < 4; s4++) {
            float4 wf[4];
            #pragma unroll
            for (int j = 0; j < 4; j++)
                wf[j] = *(const float4*)&W1[(l + 64*j) * NS + s4*4];
            #pragma unroll
            for (int e = 0; e < 4; e++) {
                float4 xv = *(const float4*)&Z[(ebase + e) * NS + s4*4];
                #pragma unroll
                for (int j = 0; j < 4; j++) acc[j][e] += dot4f(wf[j], xv);
            }
        }
        #pragma unroll
        for (int j = 0; j < 4; j++)
            #pragma unroll
            for (int e = 0; e < 4; e++) {
                float a = acc[j][e];
                d1g[j][e] = siggf(a);
                hb[e][l + 64*j] = logsigf(a);
            }
    }
    __syncthreads();

#define FWD_LAYER(WPTR, GARR)                                                   \
    {                                                                           \
        float acc[4][4];                                                        \
        _Pragma("unroll")                                                       \
        for (int j = 0; j < 4; j++) {                                           \
            _Pragma("unroll")                                                   \
            for (int e = 0; e < 4; e++) acc[j][e] = 0.f;                        \
        }                                                                       \
        _Pragma("unroll 2")                                                     \
        for (int kk = 0; kk < NH; kk += 4) {                                    \
            float wv[4][4];                                                     \
            _Pragma("unroll")                                                   \
            for (int j = 0; j < 4; j++) {                                       \
                float4 t = *(const float4*)&WPTR[(l + 64*j) * NH + kk];         \
                wv[0][j] = t.x; wv[1][j] = t.y; wv[2][j] = t.z; wv[3][j] = t.w; \
            }                                                                   \
            _Pragma("unroll")                                                   \
            for (int e = 0; e < 4; e++) {                                       \
                float4 hv = *(const float4*)&hb[e][kk];                         \
                _Pragma("unroll")                                               \
                for (int j = 0; j < 4; j++)                                     \
                    acc[j][e] += wv[0][j]*hv.x + wv[1][j]*hv.y                  \
                               + wv[2][j]*hv.z + wv[3][j]*hv.w;                 \
            }                                                                   \
        }                                                                       \
        __syncthreads();                                                        \
        _Pragma("unroll")                                                       \
        for (int j = 0; j < 4; j++) {                                           \
            _Pragma("unroll")                                                   \
            for (int e = 0; e < 4; e++) {                                       \
                float a = acc[j][e];                                            \
                GARR[j][e] = siggf(a);                                          \
                hb[e][l + 64*j] += logsigf(a);                                  \
            }                                                                   \
        }                                                                       \
        __syncthreads();                                                        \
    }

    FWD_LAYER(W2, d2g)
    FWD_LAYER(W3, d3g)
#undef FWD_LAYER

    const int e4 = l >> 4, s4 = l & 15;
    float dval = 0.f;
    {
        #pragma unroll 2
        for (int kk = 0; kk < NH; kk += 4) {
            float4 wf = *(const float4*)&W4[s4 * NH + kk];
            float4 hv = *(const float4*)&hb[e4][kk];
            dval += dot4f(wf, hv);
        }
    }

    float gacc[4][4][4];
    float vf[4][4];
    #pragma unroll
    for (int c = 0; c < 4; c++)
        #pragma unroll
        for (int j = 0; j < 4; j++)
            vf[c][j] = W4[(NS + c) * NH + l + 64*j];
    #pragma unroll
    for (int e = 0; e < 4; e++)
        #pragma unroll
        for (int c = 0; c < 4; c++)
            #pragma unroll
            for (int j = 0; j < 4; j++)
                gacc[e][c][j] = vf[c][j];
    #pragma unroll
    for (int j = 0; j < 4; j++)
        #pragma unroll
        for (int e = 0; e < 4; e++) {
            float g = d3g[j][e];
            float4 mv = make_float4(vf[0][j]*g, vf[1][j]*g, vf[2][j]*g, vf[3][j]*g);
            *(float4*)&mb[e][l + 64*j][0] = mv;
        }
    __syncthreads();

#define BWD_GEMM(WPTR)                                                          \
    {                                                                           \
        _Pragma("unroll 2")                                                     \
        for (int r = 0; r < NH; r++) {                                          \
            float wc[4];                                                        \
            _Pragma("unroll")                                                   \
            for (int j = 0; j < 4; j++) wc[j] = WPTR[r * NH + l + 64*j];        \
            _Pragma("unroll")                                                   \
            for (int e = 0; e < 4; e++) {                                       \
                float4 mv = *(const float4*)&mb[e][r][0];                       \
                _Pragma("unroll")                                               \
                for (int j = 0; j < 4; j++) {                                   \
                    gacc[e][0][j] += wc[j]*mv.x;                                \
                    gacc[e][1][j] += wc[j]*mv.y;                                \
                    gacc[e][2][j] += wc[j]*mv.z;                                \
                    gacc[e][3][j] += wc[j]*mv.w;                                \
                }                                                               \
            }                                                                   \
        }                                                                       \
    }

    BWD_GEMM(W3)
    __syncthreads();
    #pragma unroll
    for (int j = 0; j < 4; j++)
        #pragma unroll
        for (int e = 0; e < 4; e++) {
            float g = d2g[j][e];
            float4 mv = make_float4(gacc[e][0][j]*g, gacc[e][1][j]*g,
                                    gacc[e][2][j]*g, gacc[e][3][j]*g);
            *(float4*)&mb[e][l + 64*j][0] = mv;
        }
    __syncthreads();
    BWD_GEMM(W2)
#undef BWD_GEMM
    __syncthreads();
    #pragma unroll
    for (int j = 0; j < 4; j++)
        #pragma unroll
        for (int e = 0; e < 4; e++) {
            float g = d1g[j][e];
            float4 mv = make_float4(gacc[e][0][j]*g, gacc[e][1][j]*g,
                                    gacc[e][2][j]*g, gacc[e][3][j]*g);
            *(float4*)&mb[e][l + 64*j][0] = mv;
        }
    __syncthreads();

    const int c4 = l >> 4;
    float jv[4] = {0.f, 0.f, 0.f, 0.f};
    #pragma unroll 4
    for (int r = 0; r < NH; r++) {
        float w1v = W1[r * NS + s4];
        #pragma unroll
        for (int e = 0; e < 4; e++) jv[e] += mb[e][r][c4] * w1v;
    }
    __syncthreads();

    float* jlds = (float*)hb;
    #pragma unroll
    for (int e = 0; e < 4; e++) jlds[e * 64 + c4 * 16 + s4] = jv[e];
    __syncthreads();

    float acol[4];
    acol[0] = jlds[e4 * 64 +      s4];
    acol[1] = jlds[e4 * 64 + 16 + s4];
    acol[2] = jlds[e4 * 64 + 32 + s4];
    acol[3] = jlds[e4 * 64 + 48 + s4];
    #pragma unroll
    for (int c = 0; c < 4; c++) {
        float n2 = wsum16(acol[c] * acol[c]);
        float inv = (n2 > 1e-30f) ? (1.0f / sqrtf(n2)) : 0.0f;
        float q = acol[c] * inv;
        #pragma unroll
        for (int cc = c + 1; cc < 4; cc++) {
            float p = wsum16(acol[cc] * q);
            acol[cc] -= p * q;
        }
        float pd = wsum16(dval * q);
        dval -= pd * q;
    }
    OUT[ebase * NS + l] = dval;
}

extern "C" void kernel_launch(void* const* d_in, const int* in_sizes, int n_in,
                              void* d_out, int out_size, void* d_ws, size_t ws_size,
                              hipStream_t stream) {
    const float* Z  = (const float*)d_in[0];
    const float* W1 = (const float*)d_in[1];
    const float* W2 = (const float*)d_in[2];
    const float* W3 = (const float*)d_in[3];
    const float* W4 = (const float*)d_in[4];
    float* OUT = (float*)d_out;

    const size_t need = (size_t)WS_HALVES * sizeof(_Float16);

    if (ws_size >= need) {
        _Float16* ws = (_Float16*)d_ws;
        hipLaunchKernelGGL(prep_big, dim3(NH, 2), dim3(NH), 0, stream, W2, W3, ws);
        hipLaunchKernelGGL(prep_small, dim3(1), dim3(NH), 0, stream, W1, W4, ws);
        hipLaunchKernelGGL(comet_mfma, dim3(BATCH / EPB), dim3(256), 0, stream,
                           Z, W4, ws, OUT);
    } else {
        hipLaunchKernelGGL(comet_fused_f32, dim3(BATCH / 16), dim3(256), 0, stream,
                           Z, W1, W2, W3, W4, OUT);
    }
}

// Round 9
// 2077.885 us; speedup vs baseline: 1.1832x; 1.1832x over previous
//
#include <hip/hip_runtime.h>
#include <math.h>

#define NS 16
#define NC 4
#define NH 256
#define BATCH 262144
#define EPB 16      // elements per block
#define HSTR 264    // LDS row stride in halves (528 B); 4-bank rotation/row (no swizzle — R6)

typedef _Float16 half8 __attribute__((ext_vector_type(8)));
typedef _Float16 half4v __attribute__((ext_vector_type(4)));
typedef _Float16 half2v __attribute__((ext_vector_type(2)));
typedef float f32x4 __attribute__((ext_vector_type(4)));

#define MFMA16(a, b, c) __builtin_amdgcn_mfma_f32_16x16x32_f16((a), (b), (c), 0, 0, 0)

// ---------- ws layout (in halves) ----------
#define OFF_W2HI   0
#define OFF_W2LO   65536
#define OFF_W3HI   131072
#define OFF_W3LO   196608
#define OFF_W2THI  262144
#define OFF_W2TLO  327680
#define OFF_W3THI  393216
#define OFF_W3TLO  458752
#define OFF_W1PHI  524288
#define OFF_W1PLO  532480
#define OFF_W1THI  540672
#define OFF_W1TLO  544768
#define OFF_W4HI   548864
#define OFF_W4LO   552960
#define WS_HALVES  557056   // * 2 bytes = 1,114,112

__device__ __forceinline__ float logsigf(float a) {
    return fminf(a, 0.f) - __logf(1.f + __expf(-fabsf(a)));
}
__device__ __forceinline__ float siggf(float a) {   // sigma(-a)
    return 1.f / (1.f + __expf(a));
}
__device__ __forceinline__ void split2(float x, _Float16& h, _Float16& l) {
    h = (_Float16)x;
    l = (_Float16)(x - (float)h);
}
__device__ __forceinline__ float wsum16(float v) {
    v += __shfl_xor(v, 1, 64);
    v += __shfl_xor(v, 2, 64);
    v += __shfl_xor(v, 4, 64);
    v += __shfl_xor(v, 8, 64);
    return v;
}
__device__ __forceinline__ unsigned h2u(half2v h) {
    union { half2v h; unsigned u; } c; c.h = h; return c.u;
}
__device__ __forceinline__ half2v u2h(unsigned u) {
    union { half2v h; unsigned u; } c; c.u = u; return c.h;
}
__device__ __forceinline__ uint2 packg(const float g[4]) {
    half2v a, b;
    a[0] = (_Float16)g[0]; a[1] = (_Float16)g[1];
    b[0] = (_Float16)g[2]; b[1] = (_Float16)g[3];
    return make_uint2(h2u(a), h2u(b));
}

// ---------------- prep kernels ----------------
extern "C" __global__ void __launch_bounds__(256)
prep_big(const float* __restrict__ W2, const float* __restrict__ W3,
         _Float16* __restrict__ ws) {
    const int mat = blockIdx.y;
    const float* W = mat ? W3 : W2;
    _Float16* Whi  = ws + (mat ? OFF_W3HI  : OFF_W2HI);
    _Float16* Wlo  = Whi + 65536;
    _Float16* WThi = ws + (mat ? OFF_W3THI : OFF_W2THI);
    _Float16* WTlo = WThi + 65536;
    const int r = blockIdx.x, c = threadIdx.x;
    float x = W[r * NH + c];
    _Float16 h, l; split2(x, h, l);
    Whi[r * NH + c] = h;  Wlo[r * NH + c] = l;
    WThi[c * NH + r] = h; WTlo[c * NH + r] = l;
}

extern "C" __global__ void __launch_bounds__(256)
prep_small(const float* __restrict__ W1, const float* __restrict__ W4,
           _Float16* __restrict__ ws) {
    _Float16* W1phi = ws + OFF_W1PHI;
    _Float16* W1plo = ws + OFF_W1PLO;
    _Float16* W1Thi = ws + OFF_W1THI;
    _Float16* W1Tlo = ws + OFF_W1TLO;
    _Float16* W4hi  = ws + OFF_W4HI;
    _Float16* W4lo  = ws + OFF_W4LO;
    const int t = threadIdx.x;   // 0..255 (= W1 row)
    #pragma unroll
    for (int s = 0; s < NS; s++) {
        float x = W1[t * NS + s];
        _Float16 h, l; split2(x, h, l);
        W1phi[t * 32 + s] = h;        W1plo[t * 32 + s] = l;
        W1phi[t * 32 + 16 + s] = (_Float16)0.f;
        W1plo[t * 32 + 16 + s] = (_Float16)0.f;
        W1Thi[s * NH + t] = h;        W1Tlo[s * NH + t] = l;
    }
    #pragma unroll
    for (int q = 0; q < 16; q++) {
        int idx = q * 256 + t;       // covers rows 0..15 of W4
        float x = W4[idx];
        _Float16 h, l; split2(x, h, l);
        W4hi[idx] = h; W4lo[idx] = l;
    }
}

// ---------------- main fused MFMA kernel ----------------
// 256 threads = 4 waves, EPB=16. Wave w owns hidden rows 64w..64w+63
// (4 m-tiles). Forward N=16 (1 e-tile), 3-term f16-split. Backward:
// 2 passes x 8 elems (32 cotangent cols = 2 n-tiles), single-term f16,
// acc2[4][2]=32 AGPR. Gates packed f16x2 in uint2 (24 arch regs).
// LDS ~25.5 KB. launch_bounds(256,2): empirical VGPR cap = 256/arg = 128
// -> no spill (R5/R7); (256,3)=cap 84 spilled 4 GB (R8); (512,4)=cap 64
// spilled (R4). At ~128 VGPR: 16 waves/CU = 4 independent blocks whose
// barrier drains overlap each other's MFMA bursts.

__device__ __forceinline__ void gemm_fwd(const _Float16* __restrict__ Ahi,
                                         const _Float16* __restrict__ Alo,
                                         const _Float16* U,
                                         int w, int lo16, int hi4, f32x4 acc[4]) {
    #pragma unroll
    for (int ks = 0; ks < 8; ks++) {
        int boff = lo16 * HSTR + ks * 32 + hi4 * 8;
        half8 bh = *(const half8*)&U[boff];
        half8 bl = *(const half8*)&U[16 * HSTR + boff];
        #pragma unroll
        for (int m = 0; m < 4; m++) {
            int woff = (64 * w + 16 * m + lo16) * NH + ks * 32 + hi4 * 8;
            half8 ah = *(const half8*)&Ahi[woff];
            half8 al = *(const half8*)&Alo[woff];
            acc[m] = MFMA16(ah, bh, acc[m]);
            acc[m] = MFMA16(al, bh, acc[m]);
            acc[m] = MFMA16(ah, bl, acc[m]);
        }
    }
}

// single-term f16 backward GEMM: A = W^T hi only, B = M hi only, 2 n-tiles
__device__ __forceinline__ void gemm_bwd1(const _Float16* __restrict__ Ahi,
                                          const _Float16* U,
                                          int w, int lo16, int hi4, f32x4 acc[4][2]) {
    #pragma unroll
    for (int ks = 0; ks < 8; ks++) {
        half8 bh[2];
        #pragma unroll
        for (int n = 0; n < 2; n++)
            bh[n] = *(const half8*)&U[(16 * n + lo16) * HSTR + ks * 32 + hi4 * 8];
        #pragma unroll
        for (int m = 0; m < 4; m++) {
            int woff = (64 * w + 16 * m + lo16) * NH + ks * 32 + hi4 * 8;
            half8 ah = *(const half8*)&Ahi[woff];
            #pragma unroll
            for (int n = 0; n < 2; n++)
                acc[m][n] = MFMA16(ah, bh[n], acc[m][n]);
        }
    }
}

__global__ void __launch_bounds__(256, 2)
comet_mfma(const float* __restrict__ Z,
           const float* __restrict__ W4,
           const _Float16* __restrict__ ws,
           float* __restrict__ OUT)
{
    const _Float16* W2hi  = ws + OFF_W2HI;
    const _Float16* W2lo  = ws + OFF_W2LO;
    const _Float16* W3hi  = ws + OFF_W3HI;
    const _Float16* W3lo  = ws + OFF_W3LO;
    const _Float16* W2Thi = ws + OFF_W2THI;
    const _Float16* W3Thi = ws + OFF_W3THI;
    const _Float16* W1phi = ws + OFF_W1PHI;
    const _Float16* W1plo = ws + OFF_W1PLO;
    const _Float16* W1Thi = ws + OFF_W1THI;
    const _Float16* W4hi  = ws + OFF_W4HI;
    const _Float16* W4lo  = ws + OFF_W4LO;

    // union: forward H-hi rows 0..15 (by elem), H-lo rows 16..31;
    // backward M-hi rows 0..31 (by cotangent col)
    __shared__ __align__(16) _Float16 U[32 * HSTR];    // 16,896 B
    __shared__ __align__(16) float Jfin[16 * 66];      //  4,224 B
    __shared__ __align__(16) float Db[4 * 272];        //  4,352 B

    const int tid  = threadIdx.x;
    const int l    = tid & 63, w = tid >> 6;
    const int lo16 = l & 15, hi4 = l >> 4;
    const int ebase = blockIdx.x * EPB;
    const int c4 = lo16 & 3;

    // ---- V (rows 16..19 of W4) in registers: 4 m-tiles ----
    float4 vreg[4];
    #pragma unroll
    for (int m = 0; m < 4; m++)
        vreg[m] = *(const float4*)&W4[(NS + c4) * NH + 64 * w + 16 * m + 4 * hi4];

    uint2 g1u[4], g2u[4], g3u[4];   // packed f16 gates [m], 4 r-values each

    // ---- F1 : a1 = W1p @ Zpad ; B-frag direct from global ----
    {
        f32x4 acc[4];
        #pragma unroll
        for (int m = 0; m < 4; m++) acc[m] = (f32x4)(0.f);
        half8 bh, bl;
        if (hi4 < 2) {
            const float* zp = &Z[(size_t)(ebase + lo16) * NS + hi4 * 8];
            float4 z0 = *(const float4*)zp;
            float4 z1 = *(const float4*)(zp + 4);
            float zz[8] = {z0.x, z0.y, z0.z, z0.w, z1.x, z1.y, z1.z, z1.w};
            #pragma unroll
            for (int r = 0; r < 8; r++) {
                _Float16 h, lo; split2(zz[r], h, lo);
                bh[r] = h; bl[r] = lo;
            }
        } else {
            #pragma unroll
            for (int r = 0; r < 8; r++) { bh[r] = (_Float16)0.f; bl[r] = (_Float16)0.f; }
        }
        #pragma unroll
        for (int m = 0; m < 4; m++) {
            int woff = (64 * w + 16 * m + lo16) * 32 + hi4 * 8;
            half8 ah = *(const half8*)&W1phi[woff];
            half8 al = *(const half8*)&W1plo[woff];
            acc[m] = MFMA16(ah, bh, acc[m]);
            acc[m] = MFMA16(al, bh, acc[m]);
            acc[m] = MFMA16(ah, bl, acc[m]);
        }
        #pragma unroll
        for (int m = 0; m < 4; m++) {
            int hoff = lo16 * HSTR + 64 * w + 16 * m + 4 * hi4;
            float gv[4];
            half4v nh, nl;
            #pragma unroll
            for (int r = 0; r < 4; r++) {
                float a = acc[m][r];
                gv[r] = siggf(a);
                float hv = logsigf(a);
                _Float16 xh, xl; split2(hv, xh, xl);
                nh[r] = xh; nl[r] = xl;
            }
            g1u[m] = packg(gv);
            *(half4v*)&U[hoff] = nh;
            *(half4v*)&U[16 * HSTR + hoff] = nl;
        }
    }
    __syncthreads();

    // ---- F2, F3 ----
    #pragma unroll
    for (int L = 0; L < 2; L++) {
        f32x4 acc[4];
        #pragma unroll
        for (int m = 0; m < 4; m++) acc[m] = (f32x4)(0.f);
        gemm_fwd(L ? W3hi : W2hi, L ? W3lo : W2lo, U, w, lo16, hi4, acc);
        __syncthreads();   // all reads of H done before update
        #pragma unroll
        for (int m = 0; m < 4; m++) {
            int hoff = lo16 * HSTR + 64 * w + 16 * m + 4 * hi4;
            half4v oh = *(const half4v*)&U[hoff];
            half4v ol = *(const half4v*)&U[16 * HSTR + hoff];
            float gv[4];
            half4v nh, nl;
            #pragma unroll
            for (int r = 0; r < 4; r++) {
                float a = acc[m][r];
                gv[r] = siggf(a);
                float hv = (float)oh[r] + (float)ol[r] + logsigf(a);
                _Float16 xh, xl; split2(hv, xh, xl);
                nh[r] = xh; nl[r] = xl;
            }
            if (L) g3u[m] = packg(gv); else g2u[m] = packg(gv);
            *(half4v*)&U[hoff] = nh;
            *(half4v*)&U[16 * HSTR + hoff] = nl;
        }
        __syncthreads();
    }

    // ---- F4 : d = W4[0:16] @ h3 ; wave w does ks = 2w, 2w+1 (3-term) ----
    {
        f32x4 acc = (f32x4)(0.f);
        #pragma unroll
        for (int i = 0; i < 2; i++) {
            int ks = 2 * w + i;
            int boff = lo16 * HSTR + ks * 32 + hi4 * 8;
            half8 bh = *(const half8*)&U[boff];
            half8 bl = *(const half8*)&U[16 * HSTR + boff];
            int woff = lo16 * NH + ks * 32 + hi4 * 8;
            half8 ah = *(const half8*)&W4hi[woff];
            half8 al = *(const half8*)&W4lo[woff];
            acc = MFMA16(ah, bh, acc);
            acc = MFMA16(al, bh, acc);
            acc = MFMA16(ah, bl, acc);
        }
        #pragma unroll
        for (int r = 0; r < 4; r++)
            Db[w * 272 + lo16 * 17 + 4 * hi4 + r] = acc[r];   // [w][e][s]
    }
    __syncthreads();   // H (union) dead; M may be written

    // ---- backward: 2 passes x 8 elems (32 cotangent cols), f16-single ----
    #pragma unroll
    for (int p = 0; p < 2; p++) {
        // m3 = V .* d3
        #pragma unroll
        for (int m = 0; m < 4; m++)
            #pragma unroll
            for (int n = 0; n < 2; n++) {
                const int src = (l & 48) | (8 * p + 4 * n + (lo16 >> 2));
                unsigned ux = (unsigned)__shfl((int)g3u[m].x, src, 64);
                unsigned uy = (unsigned)__shfl((int)g3u[m].y, src, 64);
                half2v h0 = u2h(ux), h1 = u2h(uy);
                float g[4] = {(float)h0[0], (float)h0[1], (float)h1[0], (float)h1[1]};
                half4v vh;
                #pragma unroll
                for (int r = 0; r < 4; r++)
                    vh[r] = (_Float16)(vreg[m][r] * g[r]);
                *(half4v*)&U[(16 * n + lo16) * HSTR + 64 * w + 16 * m + 4 * hi4] = vh;
            }
        __syncthreads();

        // B3: G2 = W3^T @ m3  (single-term)
        f32x4 acc2[4][2];
        #pragma unroll
        for (int m = 0; m < 4; m++)
            #pragma unroll
            for (int n = 0; n < 2; n++) acc2[m][n] = (f32x4)(0.f);
        gemm_bwd1(W3Thi, U, w, lo16, hi4, acc2);
        __syncthreads();   // readers of m3 done

        // g2 = V + G2 (f32 skip, exact) ; m2 = g2 .* d2 ; keep g2 in acc2
        #pragma unroll
        for (int m = 0; m < 4; m++)
            #pragma unroll
            for (int n = 0; n < 2; n++) {
                const int src = (l & 48) | (8 * p + 4 * n + (lo16 >> 2));
                unsigned ux = (unsigned)__shfl((int)g2u[m].x, src, 64);
                unsigned uy = (unsigned)__shfl((int)g2u[m].y, src, 64);
                half2v h0 = u2h(ux), h1 = u2h(uy);
                float g[4] = {(float)h0[0], (float)h0[1], (float)h1[0], (float)h1[1]};
                half4v vh;
                #pragma unroll
                for (int r = 0; r < 4; r++) {
                    float gg2 = vreg[m][r] + acc2[m][n][r];
                    acc2[m][n][r] = gg2;
                    vh[r] = (_Float16)(gg2 * g[r]);
                }
                *(half4v*)&U[(16 * n + lo16) * HSTR + 64 * w + 16 * m + 4 * hi4] = vh;
            }
        __syncthreads();

        // B2: g1tot = g2 + W2^T @ m2  (single-term, accumulate onto acc2)
        gemm_bwd1(W2Thi, U, w, lo16, hi4, acc2);
        __syncthreads();

        // m1 = g1tot .* d1
        #pragma unroll
        for (int m = 0; m < 4; m++)
            #pragma unroll
            for (int n = 0; n < 2; n++) {
                const int src = (l & 48) | (8 * p + 4 * n + (lo16 >> 2));
                unsigned ux = (unsigned)__shfl((int)g1u[m].x, src, 64);
                unsigned uy = (unsigned)__shfl((int)g1u[m].y, src, 64);
                half2v h0 = u2h(ux), h1 = u2h(uy);
                float g[4] = {(float)h0[0], (float)h0[1], (float)h1[0], (float)h1[1]};
                half4v vh;
                #pragma unroll
                for (int r = 0; r < 4; r++)
                    vh[r] = (_Float16)(acc2[m][n][r] * g[r]);
                *(half4v*)&U[(16 * n + lo16) * HSTR + 64 * w + 16 * m + 4 * hi4] = vh;
            }
        __syncthreads();

        // J: J_p = W1^T @ m1 ; waves 0,1 full-K (single-term), direct Jfin
        if (w < 2) {
            f32x4 accj = (f32x4)(0.f);
            #pragma unroll
            for (int ks = 0; ks < 8; ks++) {
                int boff = (16 * w + lo16) * HSTR + ks * 32 + hi4 * 8;
                half8 bh = *(const half8*)&U[boff];
                int woff = lo16 * NH + ks * 32 + hi4 * 8;
                half8 ah = *(const half8*)&W1Thi[woff];
                accj = MFMA16(ah, bh, accj);
            }
            #pragma unroll
            for (int r = 0; r < 4; r++)
                Jfin[(4 * hi4 + r) * 66 + 32 * p + 16 * w + lo16] = accj[r];
        }
        __syncthreads();
    }

    // ---- projection: e = 4w + hi4, s = lo16 ----
    {
        const int e = 4 * w + hi4, s = lo16;
        float acol[4];
        #pragma unroll
        for (int c = 0; c < 4; c++) acol[c] = Jfin[s * 66 + 4 * e + c];
        float dval = Db[e * 17 + s] + Db[272 + e * 17 + s]
                   + Db[544 + e * 17 + s] + Db[816 + e * 17 + s];
        #pragma unroll
        for (int c = 0; c < 4; c++) {
            float n2 = wsum16(acol[c] * acol[c]);
            float inv = (n2 > 1e-30f) ? (1.0f / sqrtf(n2)) : 0.0f;
            float q = acol[c] * inv;
            #pragma unroll
            for (int cc = c + 1; cc < 4; cc++) {
                float pj = wsum16(acol[cc] * q);
                acol[cc] -= pj * q;
            }
            float pd = wsum16(dval * q);
            dval -= pd * q;
        }
        OUT[(size_t)(ebase + e) * NS + s] = dval;
    }
}

// ---------------- f32 fallback (round-1 kernel) ----------------
__device__ __forceinline__ float dot4f(float4 a, float4 b) {
    return a.x*b.x + a.y*b.y + a.z*b.z + a.w*b.w;
}

__global__ void __launch_bounds__(256, 2)
comet_fused_f32(const float* __restrict__ Z,
                const float* __restrict__ W1,
                const float* __restrict__ W2,
                const float* __restrict__ W3,
                const float* __restrict__ W4,
                float* __restrict__ OUT)
{
    __shared__ __align__(16) float h_lds[4][4][NH];
    __shared__ __align__(16) float m_lds[4][4][NH][NC];

    const int l = threadIdx.x & 63;
    const int w = threadIdx.x >> 6;
    float (*hb)[NH]     = h_lds[w];
    float (*mb)[NH][NC] = m_lds[w];
    const int ebase = (blockIdx.x * 4 + w) * 4;

    float d1g[4][4], d2g[4][4], d3g[4][4];

    {
        float acc[4][4];
        #pragma unroll
        for (int j = 0; j < 4; j++)
            #pragma unroll
            for (int e = 0; e < 4; e++) acc[j][e] = 0.f;
        #pragma unroll
        for (int s4 = 0; s4 < 4; s4++) {
            float4 wf[4];
            #pragma unroll
            for (int j = 0; j < 4; j++)
                wf[j] = *(const float4*)&W1[(l + 64*j) * NS + s4*4];
            #pragma unroll
            for (int e = 0; e < 4; e++) {
                float4 xv = *(const float4*)&Z[(ebase + e) * NS + s4*4];
                #pragma unroll
                for (int j = 0; j < 4; j++) acc[j][e] += dot4f(wf[j], xv);
            }
        }
        #pragma unroll
        for (int j = 0; j < 4; j++)
            #pragma unroll
            for (int e = 0; e < 4; e++) {
                float a = acc[j][e];
                d1g[j][e] = siggf(a);
                hb[e][l + 64*j] = logsigf(a);
            }
    }
    __syncthreads();

#define FWD_LAYER(WPTR, GARR)                                                   \
    {                                                                           \
        float acc[4][4];                                                        \
        _Pragma("unroll")                                                       \
        for (int j = 0; j < 4; j++) {                                           \
            _Pragma("unroll")                                                   \
            for (int e = 0; e < 4; e++) acc[j][e] = 0.f;                        \
        }                                                                       \
        _Pragma("unroll 2")                                                     \
        for (int kk = 0; kk < NH; kk += 4) {                                    \
            float wv[4][4];                                                     \
            _Pragma("unroll")                                                   \
            for (int j = 0; j < 4; j++) {                                       \
                float4 t = *(const float4*)&WPTR[(l + 64*j) * NH + kk];         \
                wv[0][j] = t.x; wv[1][j] = t.y; wv[2][j] = t.z; wv[3][j] = t.w; \
            }                                                                   \
            _Pragma("unroll")                                                   \
            for (int e = 0; e < 4; e++) {                                       \
                float4 hv = *(const float4*)&hb[e][kk];                         \
                _Pragma("unroll")                                               \
                for (int j = 0; j < 4; j++)                                     \
                    acc[j][e] += wv[0][j]*hv.x + wv[1][j]*hv.y                  \
                               + wv[2][j]*hv.z + wv[3][j]*hv.w;                 \
            }                                                                   \
        }                                                                       \
        __syncthreads();                                                        \
        _Pragma("unroll")                                                       \
        for (int j = 0; j < 4; j++) {                                           \
            _Pragma("unroll")                                                   \
            for (int e = 0; e < 4; e++) {                                       \
                float a = acc[j][e];                                            \
                GARR[j][e] = siggf(a);                                          \
                hb[e][l + 64*j] += logsigf(a);                                  \
            }                                                                   \
        }                                                                       \
        __syncthreads();                                                        \
    }

    FWD_LAYER(W2, d2g)
    FWD_LAYER(W3, d3g)
#undef FWD_LAYER

    const int e4 = l >> 4, s4 = l & 15;
    float dval = 0.f;
    {
        #pragma unroll 2
        for (int kk = 0; kk < NH; kk += 4) {
            float4 wf = *(const float4*)&W4[s4 * NH + kk];
            float4 hv = *(const float4*)&hb[e4][kk];
            dval += dot4f(wf, hv);
        }
    }

    float gacc[4][4][4];
    float vf[4][4];
    #pragma unroll
    for (int c = 0; c < 4; c++)
        #pragma unroll
        for (int j = 0; j < 4; j++)
            vf[c][j] = W4[(NS + c) * NH + l + 64*j];
    #pragma unroll
    for (int e = 0; e < 4; e++)
        #pragma unroll
        for (int c = 0; c < 4; c++)
            #pragma unroll
            for (int j = 0; j < 4; j++)
                gacc[e][c][j] = vf[c][j];
    #pragma unroll
    for (int j = 0; j < 4; j++)
        #pragma unroll
        for (int e = 0; e < 4; e++) {
            float g = d3g[j][e];
            float4 mv = make_float4(vf[0][j]*g, vf[1][j]*g, vf[2][j]*g, vf[3][j]*g);
            *(float4*)&mb[e][l + 64*j][0] = mv;
        }
    __syncthreads();

#define BWD_GEMM(WPTR)                                                          \
    {                                                                           \
        _Pragma("unroll 2")                                                     \
        for (int r = 0; r < NH; r++) {                                          \
            float wc[4];                                                        \
            _Pragma("unroll")                                                   \
            for (int j = 0; j < 4; j++) wc[j] = WPTR[r * NH + l + 64*j];        \
            _Pragma("unroll")                                                   \
            for (int e = 0; e < 4; e++) {                                       \
                float4 mv = *(const float4*)&mb[e][r][0];                       \
                _Pragma("unroll")                                               \
                for (int j = 0; j < 4; j++) {                                   \
                    gacc[e][0][j] += wc[j]*mv.x;                                \
                    gacc[e][1][j] += wc[j]*mv.y;                                \
                    gacc[e][2][j] += wc[j]*mv.z;                                \
                    gacc[e][3][j] += wc[j]*mv.w;                                \
                }                                                               \
            }                                                                   \
        }                                                                       \
    }

    BWD_GEMM(W3)
    __syncthreads();
    #pragma unroll
    for (int j = 0; j < 4; j++)
        #pragma unroll
        for (int e = 0; e < 4; e++) {
            float g = d2g[j][e];
            float4 mv = make_float4(gacc[e][0][j]*g, gacc[e][1][j]*g,
                                    gacc[e][2][j]*g, gacc[e][3][j]*g);
            *(float4*)&mb[e][l + 64*j][0] = mv;
        }
    __syncthreads();
    BWD_GEMM(W2)
#undef BWD_GEMM
    __syncthreads();
    #pragma unroll
    for (int j = 0; j < 4; j++)
        #pragma unroll
        for (int e = 0; e < 4; e++) {
            float g = d1g[j][e];
            float4 mv = make_float4(gacc[e][0][j]*g, gacc[e][1][j]*g,
                                    gacc[e][2][j]*g, gacc[e][3][j]*g);
            *(float4*)&mb[e][l + 64*j][0] = mv;
        }
    __syncthreads();

    const int c4 = l >> 4;
    float jv[4] = {0.f, 0.f, 0.f, 0.f};
    #pragma unroll 4
    for (int r = 0; r < NH; r++) {
        float w1v = W1[r * NS + s4];
        #pragma unroll
        for (int e = 0; e < 4; e++) jv[e] += mb[e][r][c4] * w1v;
    }
    __syncthreads();

    float* jlds = (float*)hb;
    #pragma unroll
    for (int e = 0; e < 4; e++) jlds[e * 64 + c4 * 16 + s4] = jv[e];
    __syncthreads();

    float acol[4];
    acol[0] = jlds[e4 * 64 +      s4];
    acol[1] = jlds[e4 * 64 + 16 + s4];
    acol[2] = jlds[e4 * 64 + 32 + s4];
    acol[3] = jlds[e4 * 64 + 48 + s4];
    #pragma unroll
    for (int c = 0; c < 4; c++) {
        float n2 = wsum16(acol[c] * acol[c]);
        float inv = (n2 > 1e-30f) ? (1.0f / sqrtf(n2)) : 0.0f;
        float q = acol[c] * inv;
        #pragma unroll
        for (int cc = c + 1; cc < 4; cc++) {
            float p = wsum16(acol[cc] * q);
            acol[cc] -= p * q;
        }
        float pd = wsum16(dval * q);
        dval -= pd * q;
    }
    OUT[ebase * NS + l] = dval;
}

extern "C" void kernel_launch(void* const* d_in, const int* in_sizes, int n_in,
                              void* d_out, int out_size, void* d_ws, size_t ws_size,
                              hipStream_t stream) {
    const float* Z  = (const float*)d_in[0];
    const float* W1 = (const float*)d_in[1];
    const float* W2 = (const float*)d_in[2];
    const float* W3 = (const float*)d_in[3];
    const float* W4 = (const float*)d_in[4];
    float* OUT = (float*)d_out;

    const size_t need = (size_t)WS_HALVES * sizeof(_Float16);

    if (ws_size >= need) {
        _Float16* ws = (_Float16*)d_ws;
        hipLaunchKernelGGL(prep_big, dim3(NH, 2), dim3(NH), 0, stream, W2, W3, ws);
        hipLaunchKernelGGL(prep_small, dim3(1), dim3(NH), 0, stream, W1, W4, ws);
        hipLaunchKernelGGL(comet_mfma, dim3(BATCH / EPB), dim3(256), 0, stream,
                           Z, W4, ws, OUT);
    } else {
        hipLaunchKernelGGL(comet_fused_f32, dim3(BATCH / 16), dim3(256), 0, stream,
                           Z, W1, W2, W3, W4, OUT);
    }
}

// Round 10
// 1028.196 us; speedup vs baseline: 2.3911x; 2.0209x over previous
//
#include <hip/hip_runtime.h>
#include <math.h>

#define NS 16
#define NC 4
#define NH 256
#define BATCH 262144
#define EPB 32      // elements per block
#define HSTR 264    // LDS row stride in halves (528 B); natural 4-bank rotation (no swizzle — R6)

typedef _Float16 half8 __attribute__((ext_vector_type(8)));
typedef _Float16 half4v __attribute__((ext_vector_type(4)));
typedef float f32x4 __attribute__((ext_vector_type(4)));

#define MFMA16(a, b, c) __builtin_amdgcn_mfma_f32_16x16x32_f16((a), (b), (c), 0, 0, 0)

// ---------- ws layout (in halves) ----------
#define OFF_W2HI   0
#define OFF_W2LO   65536
#define OFF_W3HI   131072
#define OFF_W3LO   196608
#define OFF_W2THI  262144
#define OFF_W2TLO  327680
#define OFF_W3THI  393216
#define OFF_W3TLO  458752
#define OFF_W1PHI  524288
#define OFF_W1PLO  532480
#define OFF_W1THI  540672
#define OFF_W1TLO  544768
#define OFF_W4HI   548864
#define OFF_W4LO   552960
#define WS_HALVES  557056   // * 2 bytes = 1,114,112

__device__ __forceinline__ float logsigf(float a) {
    return fminf(a, 0.f) - __logf(1.f + __expf(-fabsf(a)));
}
__device__ __forceinline__ float siggf(float a) {   // sigma(-a)
    return 1.f / (1.f + __expf(a));
}
__device__ __forceinline__ void split2(float x, _Float16& h, _Float16& l) {
    h = (_Float16)x;
    l = (_Float16)(x - (float)h);
}
__device__ __forceinline__ float wsum16(float v) {
    v += __shfl_xor(v, 1, 64);
    v += __shfl_xor(v, 2, 64);
    v += __shfl_xor(v, 4, 64);
    v += __shfl_xor(v, 8, 64);
    return v;
}

// ---------------- prep kernels ----------------
extern "C" __global__ void __launch_bounds__(256)
prep_big(const float* __restrict__ W2, const float* __restrict__ W3,
         _Float16* __restrict__ ws) {
    const int mat = blockIdx.y;
    const float* W = mat ? W3 : W2;
    _Float16* Whi  = ws + (mat ? OFF_W3HI  : OFF_W2HI);
    _Float16* Wlo  = Whi + 65536;
    _Float16* WThi = ws + (mat ? OFF_W3THI : OFF_W2THI);
    _Float16* WTlo = WThi + 65536;
    const int r = blockIdx.x, c = threadIdx.x;
    float x = W[r * NH + c];
    _Float16 h, l; split2(x, h, l);
    Whi[r * NH + c] = h;  Wlo[r * NH + c] = l;
    WThi[c * NH + r] = h; WTlo[c * NH + r] = l;
}

extern "C" __global__ void __launch_bounds__(256)
prep_small(const float* __restrict__ W1, const float* __restrict__ W4,
           _Float16* __restrict__ ws) {
    _Float16* W1phi = ws + OFF_W1PHI;
    _Float16* W1plo = ws + OFF_W1PLO;
    _Float16* W1Thi = ws + OFF_W1THI;
    _Float16* W1Tlo = ws + OFF_W1TLO;
    _Float16* W4hi  = ws + OFF_W4HI;
    _Float16* W4lo  = ws + OFF_W4LO;
    const int t = threadIdx.x;   // 0..255 (= W1 row)
    #pragma unroll
    for (int s = 0; s < NS; s++) {
        float x = W1[t * NS + s];
        _Float16 h, l; split2(x, h, l);
        W1phi[t * 32 + s] = h;        W1plo[t * 32 + s] = l;
        W1phi[t * 32 + 16 + s] = (_Float16)0.f;
        W1plo[t * 32 + 16 + s] = (_Float16)0.f;
        W1Thi[s * NH + t] = h;        W1Tlo[s * NH + t] = l;
    }
    #pragma unroll
    for (int q = 0; q < 16; q++) {
        int idx = q * 256 + t;       // covers rows 0..15 of W4
        float x = W4[idx];
        _Float16 h, l; split2(x, h, l);
        W4hi[idx] = h; W4lo[idx] = l;
    }
}

// ---------------- main fused MFMA kernel ----------------
// E=32/block, 512 threads = 8 waves. Wave w owns hidden rows 32w..32w+31
// (2 m-tiles). Forward: F1 3-term; F2/F3 SINGLE-term f16 (error analysis:
// orthonormal W, delta-d ~ 2.5e-3 abs); F4 3-term split-K over 8 waves.
// Backward: ONE merged pass, all 32 elems = 128 cotangent cols (8 n-tiles),
// single-term f16, acc2[2][8]. J over all 8 waves. Barriers ~11/block
// (R7: ~18); weight L2 per block ~0.6 MB (R7: 1.2 MB).
// U union: forward H-hi rows 0..31 (by elem), H-lo rows 32..63;
//          backward M-hi rows 0..127 (by cotangent col). LDS = 84,736 B
// -> 1 block/CU. launch_bounds(512,1): reg cap 256, no spill risk; an
// 8-wave block needs 2 waves/SIMD which fits up to 256 regs.

__device__ __forceinline__ void gemm_fwd1(const _Float16* __restrict__ Ahi,
                                          const _Float16* U,
                                          int w, int lo16, int hi4, f32x4 acc[2][2]) {
    #pragma unroll
    for (int ks = 0; ks < 8; ks++) {
        half8 bh[2];
        #pragma unroll
        for (int n = 0; n < 2; n++)
            bh[n] = *(const half8*)&U[(16 * n + lo16) * HSTR + ks * 32 + hi4 * 8];
        #pragma unroll
        for (int m = 0; m < 2; m++) {
            int woff = (32 * w + 16 * m + lo16) * NH + ks * 32 + hi4 * 8;
            half8 ah = *(const half8*)&Ahi[woff];
            #pragma unroll
            for (int n = 0; n < 2; n++)
                acc[m][n] = MFMA16(ah, bh[n], acc[m][n]);
        }
    }
}

// single-term backward GEMM over 8 n-tiles (128 cols)
__device__ __forceinline__ void gemm_bwd1(const _Float16* __restrict__ Ahi,
                                          const _Float16* U,
                                          int w, int lo16, int hi4, f32x4 acc[2][8]) {
    #pragma unroll
    for (int ks = 0; ks < 8; ks++) {
        half8 bh[8];
        #pragma unroll
        for (int n = 0; n < 8; n++)
            bh[n] = *(const half8*)&U[(16 * n + lo16) * HSTR + ks * 32 + hi4 * 8];
        #pragma unroll
        for (int m = 0; m < 2; m++) {
            int woff = (32 * w + 16 * m + lo16) * NH + ks * 32 + hi4 * 8;
            half8 ah = *(const half8*)&Ahi[woff];
            #pragma unroll
            for (int n = 0; n < 8; n++)
                acc[m][n] = MFMA16(ah, bh[n], acc[m][n]);
        }
    }
}

__global__ void __launch_bounds__(512, 1)
comet_mfma(const float* __restrict__ Z,
           const float* __restrict__ W4,
           const _Float16* __restrict__ ws,
           float* __restrict__ OUT)
{
    const _Float16* W2hi  = ws + OFF_W2HI;
    const _Float16* W3hi  = ws + OFF_W3HI;
    const _Float16* W2Thi = ws + OFF_W2THI;
    const _Float16* W3Thi = ws + OFF_W3THI;
    const _Float16* W1phi = ws + OFF_W1PHI;
    const _Float16* W1plo = ws + OFF_W1PLO;
    const _Float16* W1Thi = ws + OFF_W1THI;
    const _Float16* W4hi  = ws + OFF_W4HI;
    const _Float16* W4lo  = ws + OFF_W4LO;

    __shared__ __align__(16) _Float16 U[128 * HSTR];   // 67,584 B
    __shared__ __align__(16) float Jfin[16 * 132];     //  8,448 B
    __shared__ __align__(16) float Pb[8 * 272];        //  8,704 B  (F4 split-K partials)

    const int tid  = threadIdx.x;
    const int l    = tid & 63, w = tid >> 6;
    const int lo16 = l & 15, hi4 = l >> 4;
    const int ebase = blockIdx.x * EPB;
    const int c4 = lo16 & 3;

    // ---- V (rows 16..19 of W4) in registers ----
    float4 vreg[2];
    #pragma unroll
    for (int m = 0; m < 2; m++)
        vreg[m] = *(const float4*)&W4[(NS + c4) * NH + 32 * w + 16 * m + 4 * hi4];

    float g1[2][2][4], g2f[2][2][4], g3f[2][2][4];   // [m][e-tile][r]

    // ---- F1 : a1 = W1p @ Zpad (3-term) ; B-frag direct from global ----
    {
        f32x4 acc[2][2];
        #pragma unroll
        for (int m = 0; m < 2; m++)
            #pragma unroll
            for (int n = 0; n < 2; n++) acc[m][n] = (f32x4)(0.f);
        half8 bh[2], bl[2];
        #pragma unroll
        for (int n = 0; n < 2; n++) {
            if (hi4 < 2) {
                const float* zp = &Z[(size_t)(ebase + 16 * n + lo16) * NS + hi4 * 8];
                float4 z0 = *(const float4*)zp;
                float4 z1 = *(const float4*)(zp + 4);
                float zz[8] = {z0.x, z0.y, z0.z, z0.w, z1.x, z1.y, z1.z, z1.w};
                #pragma unroll
                for (int r = 0; r < 8; r++) {
                    _Float16 h, lo; split2(zz[r], h, lo);
                    bh[n][r] = h; bl[n][r] = lo;
                }
            } else {
                #pragma unroll
                for (int r = 0; r < 8; r++) { bh[n][r] = (_Float16)0.f; bl[n][r] = (_Float16)0.f; }
            }
        }
        #pragma unroll
        for (int m = 0; m < 2; m++) {
            int woff = (32 * w + 16 * m + lo16) * 32 + hi4 * 8;
            half8 ah = *(const half8*)&W1phi[woff];
            half8 al = *(const half8*)&W1plo[woff];
            #pragma unroll
            for (int n = 0; n < 2; n++) {
                acc[m][n] = MFMA16(ah, bh[n], acc[m][n]);
                acc[m][n] = MFMA16(al, bh[n], acc[m][n]);
                acc[m][n] = MFMA16(ah, bl[n], acc[m][n]);
            }
        }
        #pragma unroll
        for (int m = 0; m < 2; m++)
            #pragma unroll
            for (int n = 0; n < 2; n++) {
                int hoff = (16 * n + lo16) * HSTR + 32 * w + 16 * m + 4 * hi4;
                half4v nh, nl;
                #pragma unroll
                for (int r = 0; r < 4; r++) {
                    float a = acc[m][n][r];
                    g1[m][n][r] = siggf(a);
                    float hv = logsigf(a);
                    _Float16 xh, xl; split2(hv, xh, xl);
                    nh[r] = xh; nl[r] = xl;
                }
                *(half4v*)&U[hoff] = nh;
                *(half4v*)&U[32 * HSTR + hoff] = nl;
            }
    }
    __syncthreads();

    // ---- F2, F3 (single-term) ----
    #pragma unroll
    for (int L = 0; L < 2; L++) {
        f32x4 acc[2][2];
        #pragma unroll
        for (int m = 0; m < 2; m++)
            #pragma unroll
            for (int n = 0; n < 2; n++) acc[m][n] = (f32x4)(0.f);
        gemm_fwd1(L ? W3hi : W2hi, U, w, lo16, hi4, acc);
        __syncthreads();   // all reads of H done before update
        #pragma unroll
        for (int m = 0; m < 2; m++)
            #pragma unroll
            for (int n = 0; n < 2; n++) {
                int hoff = (16 * n + lo16) * HSTR + 32 * w + 16 * m + 4 * hi4;
                half4v oh = *(const half4v*)&U[hoff];
                half4v ol = *(const half4v*)&U[32 * HSTR + hoff];
                half4v nh, nl;
                #pragma unroll
                for (int r = 0; r < 4; r++) {
                    float a = acc[m][n][r];
                    float g = siggf(a);
                    if (L) g3f[m][n][r] = g; else g2f[m][n][r] = g;
                    float hv = (float)oh[r] + (float)ol[r] + logsigf(a);
                    _Float16 xh, xl; split2(hv, xh, xl);
                    nh[r] = xh; nl[r] = xl;
                }
                *(half4v*)&U[hoff] = nh;
                *(half4v*)&U[32 * HSTR + hoff] = nl;
            }
        __syncthreads();
    }

    // ---- F4 : d = W4[0:16] @ h3 ; 3-term, split-K over 8 waves ----
    {
        const int n4 = w & 1, kq = w >> 1;
        f32x4 acc = (f32x4)(0.f);
        #pragma unroll
        for (int i = 0; i < 2; i++) {
            int ks = 2 * kq + i;
            int boff = (16 * n4 + lo16) * HSTR + ks * 32 + hi4 * 8;
            half8 bh = *(const half8*)&U[boff];
            half8 bl = *(const half8*)&U[32 * HSTR + boff];
            int woff = lo16 * NH + ks * 32 + hi4 * 8;
            half8 ah = *(const half8*)&W4hi[woff];
            half8 al = *(const half8*)&W4lo[woff];
            acc = MFMA16(ah, bh, acc);
            acc = MFMA16(al, bh, acc);
            acc = MFMA16(ah, bl, acc);
        }
        #pragma unroll
        for (int r = 0; r < 4; r++)
            Pb[w * 272 + (hi4 * 4 + r) * 17 + lo16] = acc[r];
    }
    __syncthreads();   // H (union) dead; M may be written

    // ---- backward: ONE merged pass, 128 cotangent cols (8 n-tiles) ----
    // col = 16n + lo16  <->  elem E = 16*(n>>2) + 4*(n&3) + (lo16>>2), cot c = lo16&3
    // m3 = V .* d3
    #pragma unroll
    for (int m = 0; m < 2; m++)
        #pragma unroll
        for (int n = 0; n < 8; n++) {
            const int src = (l & 48) | (4 * (n & 3) + (lo16 >> 2));
            const int et = n >> 2;
            const int kbase = 32 * w + 16 * m + 4 * hi4;
            half4v vh;
            #pragma unroll
            for (int r = 0; r < 4; r++) {
                float g = __shfl(g3f[m][et][r], src, 64);
                vh[r] = (_Float16)(vreg[m][r] * g);
            }
            *(half4v*)&U[(16 * n + lo16) * HSTR + kbase] = vh;
        }
    __syncthreads();

    // B3: G2 = W3^T @ m3
    f32x4 acc2[2][8];
    #pragma unroll
    for (int m = 0; m < 2; m++)
        #pragma unroll
        for (int n = 0; n < 8; n++) acc2[m][n] = (f32x4)(0.f);
    gemm_bwd1(W3Thi, U, w, lo16, hi4, acc2);
    __syncthreads();   // readers of m3 done

    // g2 = V + G2 (f32 skip, exact) ; m2 = g2 .* d2 ; keep g2 in acc2
    #pragma unroll
    for (int m = 0; m < 2; m++)
        #pragma unroll
        for (int n = 0; n < 8; n++) {
            const int src = (l & 48) | (4 * (n & 3) + (lo16 >> 2));
            const int et = n >> 2;
            const int kbase = 32 * w + 16 * m + 4 * hi4;
            half4v vh;
            #pragma unroll
            for (int r = 0; r < 4; r++) {
                float gg2 = vreg[m][r] + acc2[m][n][r];
                acc2[m][n][r] = gg2;
                float g = __shfl(g2f[m][et][r], src, 64);
                vh[r] = (_Float16)(gg2 * g);
            }
            *(half4v*)&U[(16 * n + lo16) * HSTR + kbase] = vh;
        }
    __syncthreads();

    // B2: g1tot = g2 + W2^T @ m2  (accumulate onto acc2)
    gemm_bwd1(W2Thi, U, w, lo16, hi4, acc2);
    __syncthreads();

    // m1 = g1tot .* d1
    #pragma unroll
    for (int m = 0; m < 2; m++)
        #pragma unroll
        for (int n = 0; n < 8; n++) {
            const int src = (l & 48) | (4 * (n & 3) + (lo16 >> 2));
            const int et = n >> 2;
            const int kbase = 32 * w + 16 * m + 4 * hi4;
            half4v vh;
            #pragma unroll
            for (int r = 0; r < 4; r++) {
                float g = __shfl(g1[m][et][r], src, 64);
                vh[r] = (_Float16)(acc2[m][n][r] * g);
            }
            *(half4v*)&U[(16 * n + lo16) * HSTR + kbase] = vh;
        }
    __syncthreads();

    // J = W1^T @ m1 ; all 8 waves, wave w = n-tile w, full K
    {
        f32x4 accj = (f32x4)(0.f);
        #pragma unroll
        for (int ks = 0; ks < 8; ks++) {
            int boff = (16 * w + lo16) * HSTR + ks * 32 + hi4 * 8;
            half8 bh = *(const half8*)&U[boff];
            int woff = lo16 * NH + ks * 32 + hi4 * 8;
            half8 ah = *(const half8*)&W1Thi[woff];
            accj = MFMA16(ah, bh, accj);
        }
        #pragma unroll
        for (int r = 0; r < 4; r++)
            Jfin[(4 * hi4 + r) * 132 + 16 * w + lo16] = accj[r];
    }
    __syncthreads();

    // ---- projection: e = 4w + hi4, s = lo16 ----
    {
        const int e = 4 * w + hi4, s = lo16;
        float acol[4];
        #pragma unroll
        for (int c = 0; c < 4; c++) acol[c] = Jfin[s * 132 + 4 * e + c];
        const int n4 = e >> 4, c16 = e & 15;
        float dval = 0.f;
        #pragma unroll
        for (int kq = 0; kq < 4; kq++)
            dval += Pb[(2 * kq + n4) * 272 + s * 17 + c16];
        #pragma unroll
        for (int c = 0; c < 4; c++) {
            float n2 = wsum16(acol[c] * acol[c]);
            float inv = (n2 > 1e-30f) ? (1.0f / sqrtf(n2)) : 0.0f;
            float q = acol[c] * inv;
            #pragma unroll
            for (int cc = c + 1; cc < 4; cc++) {
                float pj = wsum16(acol[cc] * q);
                acol[cc] -= pj * q;
            }
            float pd = wsum16(dval * q);
            dval -= pd * q;
        }
        OUT[(size_t)(ebase + e) * NS + s] = dval;
    }
}

// ---------------- f32 fallback (round-1 kernel) ----------------
__device__ __forceinline__ float dot4f(float4 a, float4 b) {
    return a.x*b.x + a.y*b.y + a.z*b.z + a.w*b.w;
}

__global__ void __launch_bounds__(256, 2)
comet_fused_f32(const float* __restrict__ Z,
                const float* __restrict__ W1,
                const float* __restrict__ W2,
                const float* __restrict__ W3,
                const float* __restrict__ W4,
                float* __restrict__ OUT)
{
    __shared__ __align__(16) float h_lds[4][4][NH];
    __shared__ __align__(16) float m_lds[4][4][NH][NC];

    const int l = threadIdx.x & 63;
    const int w = threadIdx.x >> 6;
    float (*hb)[NH]     = h_lds[w];
    float (*mb)[NH][NC] = m_lds[w];
    const int ebase = (blockIdx.x * 4 + w) * 4;

    float d1g[4][4], d2g[4][4], d3g[4][4];

    {
        float acc[4][4];
        #pragma unroll
        for (int j = 0; j < 4; j++)
            #pragma unroll
            for (int e = 0; e < 4; e++) acc[j][e] = 0.f;
        #pragma unroll
        for (int s4 = 0; s4 < 4; s4++) {
            float4 wf[4];
            #pragma unroll
            for (int j = 0; j < 4; j++)
                wf[j] = *(const float4*)&W1[(l + 64*j) * NS + s4*4];
            #pragma unroll
            for (int e = 0; e < 4; e++) {
                float4 xv = *(const float4*)&Z[(ebase + e) * NS + s4*4];
                #pragma unroll
                for (int j = 0; j < 4; j++) acc[j][e] += dot4f(wf[j], xv);
            }
        }
        #pragma unroll
        for (int j = 0; j < 4; j++)
            #pragma unroll
            for (int e = 0; e < 4; e++) {
                float a = acc[j][e];
                d1g[j][e] = siggf(a);
                hb[e][l + 64*j] = logsigf(a);
            }
    }
    __syncthreads();

#define FWD_LAYER(WPTR, GARR)                                                   \
    {                                                                           \
        float acc[4][4];                                                        \
        _Pragma("unroll")                                                       \
        for (int j = 0; j < 4; j++) {                                           \
            _Pragma("unroll")                                                   \
            for (int e = 0; e < 4; e++) acc[j][e] = 0.f;                        \
        }                                                                       \
        _Pragma("unroll 2")                                                     \
        for (int kk = 0; kk < NH; kk += 4) {                                    \
            float wv[4][4];                                                     \
            _Pragma("unroll")                                                   \
            for (int j = 0; j < 4; j++) {                                       \
                float4 t = *(const float4*)&WPTR[(l + 64*j) * NH + kk];         \
                wv[0][j] = t.x; wv[1][j] = t.y; wv[2][j] = t.z; wv[3][j] = t.w; \
            }                                                                   \
            _Pragma("unroll")                                                   \
            for (int e = 0; e < 4; e++) {                                       \
                float4 hv = *(const float4*)&hb[e][kk];                         \
                _Pragma("unroll")                                               \
                for (int j = 0; j < 4; j++)                                     \
                    acc[j][e] += wv[0][j]*hv.x + wv[1][j]*hv.y                  \
                               + wv[2][j]*hv.z + wv[3][j]*hv.w;                 \
            }                                                                   \
        }                                                                       \
        __syncthreads();                                                        \
        _Pragma("unroll")                                                       \
        for (int j = 0; j < 4; j++) {                                           \
            _Pragma("unroll")                                                   \
            for (int e = 0; e < 4; e++) {                                       \
                float a = acc[j][e];                                            \
                GARR[j][e] = siggf(a);                                          \
                hb[e][l + 64*j] += logsigf(a);                                  \
            }                                                                   \
        }                                                                       \
        __syncthreads();                                                        \
    }

    FWD_LAYER(W2, d2g)
    FWD_LAYER(W3, d3g)
#undef FWD_LAYER

    const int e4 = l >> 4, s4 = l & 15;
    float dval = 0.f;
    {
        #pragma unroll 2
        for (int kk = 0; kk < NH; kk += 4) {
            float4 wf = *(const float4*)&W4[s4 * NH + kk];
            float4 hv = *(const float4*)&hb[e4][kk];
            dval += dot4f(wf, hv);
        }
    }

    float gacc[4][4][4];
    float vf[4][4];
    #pragma unroll
    for (int c = 0; c < 4; c++)
        #pragma unroll
        for (int j = 0; j < 4; j++)
            vf[c][j] = W4[(NS + c) * NH + l + 64*j];
    #pragma unroll
    for (int e = 0; e < 4; e++)
        #pragma unroll
        for (int c = 0; c < 4; c++)
            #pragma unroll
            for (int j = 0; j < 4; j++)
                gacc[e][c][j] = vf[c][j];
    #pragma unroll
    for (int j = 0; j < 4; j++)
        #pragma unroll
        for (int e = 0; e < 4; e++) {
            float g = d3g[j][e];
            float4 mv = make_float4(vf[0][j]*g, vf[1][j]*g, vf[2][j]*g, vf[3][j]*g);
            *(float4*)&mb[e][l + 64*j][0] = mv;
        }
    __syncthreads();

#define BWD_GEMM(WPTR)                                                          \
    {                                                                           \
        _Pragma("unroll 2")                                                     \
        for (int r = 0; r < NH; r++) {                                          \
            float wc[4];                                                        \
            _Pragma("unroll")                                                   \
            for (int j = 0; j < 4; j++) wc[j] = WPTR[r * NH + l + 64*j];        \
            _Pragma("unroll")                                                   \
            for (int e = 0; e < 4; e++) {                                       \
                float4 mv = *(const float4*)&mb[e][r][0];                       \
                _Pragma("unroll")                                               \
                for (int j = 0; j < 4; j++) {                                   \
                    gacc[e][0][j] += wc[j]*mv.x;                                \
                    gacc[e][1][j] += wc[j]*mv.y;                                \
                    gacc[e][2][j] += wc[j]*mv.z;                                \
                    gacc[e][3][j] += wc[j]*mv.w;                                \
                }                                                               \
            }                                                                   \
        }                                                                       \
    }

    BWD_GEMM(W3)
    __syncthreads();
    #pragma unroll
    for (int j = 0; j < 4; j++)
        #pragma unroll
        for (int e = 0; e < 4; e++) {
            float g = d2g[j][e];
            float4 mv = make_float4(gacc[e][0][j]*g, gacc[e][1][j]*g,
                                    gacc[e][2][j]*g, gacc[e][3][j]*g);
            *(float4*)&mb[e][l + 64*j][0] = mv;
        }
    __syncthreads();
    BWD_GEMM(W2)
#undef BWD_GEMM
    __syncthreads();
    #pragma unroll
    for (int j = 0; j < 4; j++)
        #pragma unroll
        for (int e = 0; e < 4; e++) {
            float g = d1g[j][e];
            float4 mv = make_float4(gacc[e][0][j]*g, gacc[e][1][j]*g,
                                    gacc[e][2][j]*g, gacc[e][3][j]*g);
            *(float4*)&mb[e][l + 64*j][0] = mv;
        }
    __syncthreads();

    const int c4 = l >> 4;
    float jv[4] = {0.f, 0.f, 0.f, 0.f};
    #pragma unroll 4
    for (int r = 0; r < NH; r++) {
        float w1v = W1[r * NS + s4];
        #pragma unroll
        for (int e = 0; e < 4; e++) jv[e] += mb[e][r][c4] * w1v;
    }
    __syncthreads();

    float* jlds = (float*)hb;
    #pragma unroll
    for (int e = 0; e < 4; e++) jlds[e * 64 + c4 * 16 + s4] = jv[e];
    __syncthreads();

    float acol[4];
    acol[0] = jlds[e4 * 64 +      s4];
    acol[1] = jlds[e4 * 64 + 16 + s4];
    acol[2] = jlds[e4 * 64 + 32 + s4];
    acol[3] = jlds[e4 * 64 + 48 + s4];
    #pragma unroll
    for (int c = 0; c < 4; c++) {
        float n2 = wsum16(acol[c] * acol[c]);
        float inv = (n2 > 1e-30f) ? (1.0f / sqrtf(n2)) : 0.0f;
        float q = acol[c] * inv;
        #pragma unroll
        for (int cc = c + 1; cc < 4; cc++) {
            float p = wsum16(acol[cc] * q);
            acol[cc] -= p * q;
        }
        float pd = wsum16(dval * q);
        dval -= pd * q;
    }
    OUT[ebase * NS + l] = dval;
}

extern "C" void kernel_launch(void* const* d_in, const int* in_sizes, int n_in,
                              void* d_out, int out_size, void* d_ws, size_t ws_size,
                              hipStream_t stream) {
    const float* Z  = (const float*)d_in[0];
    const float* W1 = (const float*)d_in[1];
    const float* W2 = (const float*)d_in[2];
    const float* W3 = (const float*)d_in[3];
    const float* W4 = (const float*)d_in[4];
    float* OUT = (float*)d_out;

    const size_t need = (size_t)WS_HALVES * sizeof(_Float16);

    if (ws_size >= need) {
        _Float16* ws = (_Float16*)d_ws;
        hipLaunchKernelGGL(prep_big, dim3(NH, 2), dim3(NH), 0, stream, W2, W3, ws);
        hipLaunchKernelGGL(prep_small, dim3(1), dim3(NH), 0, stream, W1, W4, ws);
        hipLaunchKernelGGL(comet_mfma, dim3(BATCH / EPB), dim3(512), 0, stream,
                           Z, W4, ws, OUT);
    } else {
        hipLaunchKernelGGL(comet_fused_f32, dim3(BATCH / 16), dim3(256), 0, stream,
                           Z, W1, W2, W3, W4, OUT);
    }
}

// Round 11
// 891.555 us; speedup vs baseline: 2.7576x; 1.1533x over previous
//
#include <hip/hip_runtime.h>
#include <math.h>

#define NS 16
#define NC 4
#define NH 256
#define BATCH 262144
#define EPB 64      // elements per block
#define HSTR 264    // LDS row stride in halves (528 B); natural 4-bank rotation (no swizzle — R6)

typedef _Float16 half8 __attribute__((ext_vector_type(8)));
typedef _Float16 half4v __attribute__((ext_vector_type(4)));
typedef _Float16 half2v __attribute__((ext_vector_type(2)));
typedef float f32x4 __attribute__((ext_vector_type(4)));

#define MFMA16(a, b, c) __builtin_amdgcn_mfma_f32_16x16x32_f16((a), (b), (c), 0, 0, 0)

// ---------- ws layout (in halves) ----------
#define OFF_W2HI   0
#define OFF_W2LO   65536
#define OFF_W3HI   131072
#define OFF_W3LO   196608
#define OFF_W2THI  262144
#define OFF_W2TLO  327680
#define OFF_W3THI  393216
#define OFF_W3TLO  458752
#define OFF_W1PHI  524288
#define OFF_W1PLO  532480
#define OFF_W1THI  540672
#define OFF_W1TLO  544768
#define OFF_W4HI   548864
#define OFF_W4LO   552960
#define WS_HALVES  557056   // * 2 bytes = 1,114,112

__device__ __forceinline__ float logsigf(float a) {
    return fminf(a, 0.f) - __logf(1.f + __expf(-fabsf(a)));
}
__device__ __forceinline__ float siggf(float a) {   // sigma(-a)
    return 1.f / (1.f + __expf(a));
}
__device__ __forceinline__ void split2(float x, _Float16& h, _Float16& l) {
    h = (_Float16)x;
    l = (_Float16)(x - (float)h);
}
__device__ __forceinline__ float wsum16(float v) {
    v += __shfl_xor(v, 1, 64);
    v += __shfl_xor(v, 2, 64);
    v += __shfl_xor(v, 4, 64);
    v += __shfl_xor(v, 8, 64);
    return v;
}
__device__ __forceinline__ unsigned h2u(half2v h) {
    union { half2v h; unsigned u; } c; c.h = h; return c.u;
}
__device__ __forceinline__ half2v u2h(unsigned u) {
    union { half2v h; unsigned u; } c; c.u = u; return c.h;
}
__device__ __forceinline__ uint2 packg(const float g[4]) {
    half2v a, b;
    a[0] = (_Float16)g[0]; a[1] = (_Float16)g[1];
    b[0] = (_Float16)g[2]; b[1] = (_Float16)g[3];
    return make_uint2(h2u(a), h2u(b));
}

// ---------------- prep kernels ----------------
extern "C" __global__ void __launch_bounds__(256)
prep_big(const float* __restrict__ W2, const float* __restrict__ W3,
         _Float16* __restrict__ ws) {
    const int mat = blockIdx.y;
    const float* W = mat ? W3 : W2;
    _Float16* Whi  = ws + (mat ? OFF_W3HI  : OFF_W2HI);
    _Float16* Wlo  = Whi + 65536;
    _Float16* WThi = ws + (mat ? OFF_W3THI : OFF_W2THI);
    _Float16* WTlo = WThi + 65536;
    const int r = blockIdx.x, c = threadIdx.x;
    float x = W[r * NH + c];
    _Float16 h, l; split2(x, h, l);
    Whi[r * NH + c] = h;  Wlo[r * NH + c] = l;
    WThi[c * NH + r] = h; WTlo[c * NH + r] = l;
}

extern "C" __global__ void __launch_bounds__(256)
prep_small(const float* __restrict__ W1, const float* __restrict__ W4,
           _Float16* __restrict__ ws) {
    _Float16* W1phi = ws + OFF_W1PHI;
    _Float16* W1plo = ws + OFF_W1PLO;
    _Float16* W1Thi = ws + OFF_W1THI;
    _Float16* W1Tlo = ws + OFF_W1TLO;
    _Float16* W4hi  = ws + OFF_W4HI;
    _Float16* W4lo  = ws + OFF_W4LO;
    const int t = threadIdx.x;   // 0..255 (= W1 row)
    #pragma unroll
    for (int s = 0; s < NS; s++) {
        float x = W1[t * NS + s];
        _Float16 h, l; split2(x, h, l);
        W1phi[t * 32 + s] = h;        W1plo[t * 32 + s] = l;
        W1phi[t * 32 + 16 + s] = (_Float16)0.f;
        W1plo[t * 32 + 16 + s] = (_Float16)0.f;
        W1Thi[s * NH + t] = h;        W1Tlo[s * NH + t] = l;
    }
    #pragma unroll
    for (int q = 0; q < 16; q++) {
        int idx = q * 256 + t;       // covers rows 0..15 of W4
        float x = W4[idx];
        _Float16 h, l; split2(x, h, l);
        W4hi[idx] = h; W4lo[idx] = l;
    }
}

// ---------------- main fused MFMA kernel ----------------
// E=64/block, 512 threads = 8 waves. Wave w owns hidden rows 32w..32w+31
// (2 m-tiles). Forward N=64 (4 e-tiles): F1 3-term, F2/F3 single-term,
// F4 3-term split-K (4 e-tiles x 2 k-halves over 8 waves). Backward:
// 2 passes x 32 elems (128 cotangent cols = 8 n-tiles each), single-term,
// acc2[2][8]. Gates packed f16x2 in uint2[2][4] per layer (48 regs).
// U union: fwd H-hi rows 0..63 (by elem), H-lo rows 64..127;
//          bwd M-hi rows 0..127 (by cotangent col).
// LDS = 92,928 B -> 1 block/CU. Barriers: 18 per 64 elems (R10: 24/64);
// forward weight L2 traffic per element halved vs R10.
// launch_bounds(512,1): reg cap 256 (8-wave block = 2 waves/SIMD), no spill.

__device__ __forceinline__ void gemm_fwd1(const _Float16* __restrict__ Ahi,
                                          const _Float16* U,
                                          int w, int lo16, int hi4, f32x4 acc[2][4]) {
    #pragma unroll
    for (int ks = 0; ks < 8; ks++) {
        half8 bh[4];
        #pragma unroll
        for (int n = 0; n < 4; n++)
            bh[n] = *(const half8*)&U[(16 * n + lo16) * HSTR + ks * 32 + hi4 * 8];
        #pragma unroll
        for (int m = 0; m < 2; m++) {
            int woff = (32 * w + 16 * m + lo16) * NH + ks * 32 + hi4 * 8;
            half8 ah = *(const half8*)&Ahi[woff];
            #pragma unroll
            for (int n = 0; n < 4; n++)
                acc[m][n] = MFMA16(ah, bh[n], acc[m][n]);
        }
    }
}

// single-term backward GEMM over 8 n-tiles (128 cols)
__device__ __forceinline__ void gemm_bwd1(const _Float16* __restrict__ Ahi,
                                          const _Float16* U,
                                          int w, int lo16, int hi4, f32x4 acc[2][8]) {
    #pragma unroll
    for (int ks = 0; ks < 8; ks++) {
        half8 bh[8];
        #pragma unroll
        for (int n = 0; n < 8; n++)
            bh[n] = *(const half8*)&U[(16 * n + lo16) * HSTR + ks * 32 + hi4 * 8];
        #pragma unroll
        for (int m = 0; m < 2; m++) {
            int woff = (32 * w + 16 * m + lo16) * NH + ks * 32 + hi4 * 8;
            half8 ah = *(const half8*)&Ahi[woff];
            #pragma unroll
            for (int n = 0; n < 8; n++)
                acc[m][n] = MFMA16(ah, bh[n], acc[m][n]);
        }
    }
}

__global__ void __launch_bounds__(512, 1)
comet_mfma(const float* __restrict__ Z,
           const float* __restrict__ W4,
           const _Float16* __restrict__ ws,
           float* __restrict__ OUT)
{
    const _Float16* W2hi  = ws + OFF_W2HI;
    const _Float16* W3hi  = ws + OFF_W3HI;
    const _Float16* W2Thi = ws + OFF_W2THI;
    const _Float16* W3Thi = ws + OFF_W3THI;
    const _Float16* W1phi = ws + OFF_W1PHI;
    const _Float16* W1plo = ws + OFF_W1PLO;
    const _Float16* W1Thi = ws + OFF_W1THI;
    const _Float16* W4hi  = ws + OFF_W4HI;
    const _Float16* W4lo  = ws + OFF_W4LO;

    __shared__ __align__(16) _Float16 U[128 * HSTR];   // 67,584 B
    __shared__ __align__(16) float Jfin[16 * 260];     // 16,640 B
    __shared__ __align__(16) float Pb[8 * 272];        //  8,704 B

    const int tid  = threadIdx.x;
    const int l    = tid & 63, w = tid >> 6;
    const int lo16 = l & 15, hi4 = l >> 4;
    const int ebase = blockIdx.x * EPB;
    const int c4 = lo16 & 3;

    // ---- V (rows 16..19 of W4) in registers ----
    float4 vreg[2];
    #pragma unroll
    for (int m = 0; m < 2; m++)
        vreg[m] = *(const float4*)&W4[(NS + c4) * NH + 32 * w + 16 * m + 4 * hi4];

    uint2 g1u[2][4], g2u[2][4], g3u[2][4];   // [m][e-tile] packed f16 gates

    // ---- F1 : a1 = W1p @ Zpad (3-term) ; B-frags direct from global ----
    {
        f32x4 acc[2][4];
        #pragma unroll
        for (int m = 0; m < 2; m++)
            #pragma unroll
            for (int n = 0; n < 4; n++) acc[m][n] = (f32x4)(0.f);
        half8 bh[4], bl[4];
        #pragma unroll
        for (int n = 0; n < 4; n++) {
            if (hi4 < 2) {
                const float* zp = &Z[(size_t)(ebase + 16 * n + lo16) * NS + hi4 * 8];
                float4 z0 = *(const float4*)zp;
                float4 z1 = *(const float4*)(zp + 4);
                float zz[8] = {z0.x, z0.y, z0.z, z0.w, z1.x, z1.y, z1.z, z1.w};
                #pragma unroll
                for (int r = 0; r < 8; r++) {
                    _Float16 h, lo; split2(zz[r], h, lo);
                    bh[n][r] = h; bl[n][r] = lo;
                }
            } else {
                #pragma unroll
                for (int r = 0; r < 8; r++) { bh[n][r] = (_Float16)0.f; bl[n][r] = (_Float16)0.f; }
            }
        }
        #pragma unroll
        for (int m = 0; m < 2; m++) {
            int woff = (32 * w + 16 * m + lo16) * 32 + hi4 * 8;
            half8 ah = *(const half8*)&W1phi[woff];
            half8 al = *(const half8*)&W1plo[woff];
            #pragma unroll
            for (int n = 0; n < 4; n++) {
                acc[m][n] = MFMA16(ah, bh[n], acc[m][n]);
                acc[m][n] = MFMA16(al, bh[n], acc[m][n]);
                acc[m][n] = MFMA16(ah, bl[n], acc[m][n]);
            }
        }
        #pragma unroll
        for (int m = 0; m < 2; m++)
            #pragma unroll
            for (int n = 0; n < 4; n++) {
                int hoff = (16 * n + lo16) * HSTR + 32 * w + 16 * m + 4 * hi4;
                float gv[4];
                half4v nh, nl;
                #pragma unroll
                for (int r = 0; r < 4; r++) {
                    float a = acc[m][n][r];
                    gv[r] = siggf(a);
                    float hv = logsigf(a);
                    _Float16 xh, xl; split2(hv, xh, xl);
                    nh[r] = xh; nl[r] = xl;
                }
                g1u[m][n] = packg(gv);
                *(half4v*)&U[hoff] = nh;
                *(half4v*)&U[64 * HSTR + hoff] = nl;
            }
    }
    __syncthreads();

    // ---- F2, F3 (single-term) ----
    #pragma unroll
    for (int L = 0; L < 2; L++) {
        f32x4 acc[2][4];
        #pragma unroll
        for (int m = 0; m < 2; m++)
            #pragma unroll
            for (int n = 0; n < 4; n++) acc[m][n] = (f32x4)(0.f);
        gemm_fwd1(L ? W3hi : W2hi, U, w, lo16, hi4, acc);
        __syncthreads();   // all reads of H done before update
        #pragma unroll
        for (int m = 0; m < 2; m++)
            #pragma unroll
            for (int n = 0; n < 4; n++) {
                int hoff = (16 * n + lo16) * HSTR + 32 * w + 16 * m + 4 * hi4;
                half4v oh = *(const half4v*)&U[hoff];
                half4v ol = *(const half4v*)&U[64 * HSTR + hoff];
                float gv[4];
                half4v nh, nl;
                #pragma unroll
                for (int r = 0; r < 4; r++) {
                    float a = acc[m][n][r];
                    gv[r] = siggf(a);
                    float hv = (float)oh[r] + (float)ol[r] + logsigf(a);
                    _Float16 xh, xl; split2(hv, xh, xl);
                    nh[r] = xh; nl[r] = xl;
                }
                if (L) g3u[m][n] = packg(gv); else g2u[m][n] = packg(gv);
                *(half4v*)&U[hoff] = nh;
                *(half4v*)&U[64 * HSTR + hoff] = nl;
            }
        __syncthreads();
    }

    // ---- F4 : d = W4[0:16] @ h3 ; 3-term, wave = (e-tile w&3, k-half w>>2) ----
    {
        const int et = w & 3, kh = w >> 2;
        f32x4 acc = (f32x4)(0.f);
        #pragma unroll
        for (int i = 0; i < 4; i++) {
            int ks = 4 * kh + i;
            int boff = (16 * et + lo16) * HSTR + ks * 32 + hi4 * 8;
            half8 bh = *(const half8*)&U[boff];
            half8 bl = *(const half8*)&U[64 * HSTR + boff];
            int woff = lo16 * NH + ks * 32 + hi4 * 8;
            half8 ah = *(const half8*)&W4hi[woff];
            half8 al = *(const half8*)&W4lo[woff];
            acc = MFMA16(ah, bh, acc);
            acc = MFMA16(al, bh, acc);
            acc = MFMA16(ah, bl, acc);
        }
        #pragma unroll
        for (int r = 0; r < 4; r++)
            Pb[w * 272 + (hi4 * 4 + r) * 17 + lo16] = acc[r];
    }
    __syncthreads();   // H (union) dead; M may be written

    // ---- backward: 2 passes x 32 elems (128 cotangent cols each) ----
    #pragma unroll
    for (int p = 0; p < 2; p++) {
        // m3 = V .* d3
        #pragma unroll
        for (int m = 0; m < 2; m++)
            #pragma unroll
            for (int n = 0; n < 8; n++) {
                const int src = (l & 48) | (4 * (n & 3) + (lo16 >> 2));
                const int et = 2 * p + (n >> 2);
                const int kbase = 32 * w + 16 * m + 4 * hi4;
                unsigned ux = (unsigned)__shfl((int)g3u[m][et].x, src, 64);
                unsigned uy = (unsigned)__shfl((int)g3u[m][et].y, src, 64);
                half2v h0 = u2h(ux), h1 = u2h(uy);
                float g[4] = {(float)h0[0], (float)h0[1], (float)h1[0], (float)h1[1]};
                half4v vh;
                #pragma unroll
                for (int r = 0; r < 4; r++)
                    vh[r] = (_Float16)(vreg[m][r] * g[r]);
                *(half4v*)&U[(16 * n + lo16) * HSTR + kbase] = vh;
            }
        __syncthreads();

        // B3: G2 = W3^T @ m3
        f32x4 acc2[2][8];
        #pragma unroll
        for (int m = 0; m < 2; m++)
            #pragma unroll
            for (int n = 0; n < 8; n++) acc2[m][n] = (f32x4)(0.f);
        gemm_bwd1(W3Thi, U, w, lo16, hi4, acc2);
        __syncthreads();   // readers of m3 done

        // g2 = V + G2 (f32 skip, exact) ; m2 = g2 .* d2 ; keep g2 in acc2
        #pragma unroll
        for (int m = 0; m < 2; m++)
            #pragma unroll
            for (int n = 0; n < 8; n++) {
                const int src = (l & 48) | (4 * (n & 3) + (lo16 >> 2));
                const int et = 2 * p + (n >> 2);
                const int kbase = 32 * w + 16 * m + 4 * hi4;
                unsigned ux = (unsigned)__shfl((int)g2u[m][et].x, src, 64);
                unsigned uy = (unsigned)__shfl((int)g2u[m][et].y, src, 64);
                half2v h0 = u2h(ux), h1 = u2h(uy);
                float g[4] = {(float)h0[0], (float)h0[1], (float)h1[0], (float)h1[1]};
                half4v vh;
                #pragma unroll
                for (int r = 0; r < 4; r++) {
                    float gg2 = vreg[m][r] + acc2[m][n][r];
                    acc2[m][n][r] = gg2;
                    vh[r] = (_Float16)(gg2 * g[r]);
                }
                *(half4v*)&U[(16 * n + lo16) * HSTR + kbase] = vh;
            }
        __syncthreads();

        // B2: g1tot = g2 + W2^T @ m2  (accumulate onto acc2)
        gemm_bwd1(W2Thi, U, w, lo16, hi4, acc2);
        __syncthreads();

        // m1 = g1tot .* d1
        #pragma unroll
        for (int m = 0; m < 2; m++)
            #pragma unroll
            for (int n = 0; n < 8; n++) {
                const int src = (l & 48) | (4 * (n & 3) + (lo16 >> 2));
                const int et = 2 * p + (n >> 2);
                const int kbase = 32 * w + 16 * m + 4 * hi4;
                unsigned ux = (unsigned)__shfl((int)g1u[m][et].x, src, 64);
                unsigned uy = (unsigned)__shfl((int)g1u[m][et].y, src, 64);
                half2v h0 = u2h(ux), h1 = u2h(uy);
                float g[4] = {(float)h0[0], (float)h0[1], (float)h1[0], (float)h1[1]};
                half4v vh;
                #pragma unroll
                for (int r = 0; r < 4; r++)
                    vh[r] = (_Float16)(acc2[m][n][r] * g[r]);
                *(half4v*)&U[(16 * n + lo16) * HSTR + kbase] = vh;
            }
        __syncthreads();

        // J = W1^T @ m1 ; all 8 waves, wave w = n-tile w, full K
        {
            f32x4 accj = (f32x4)(0.f);
            #pragma unroll
            for (int ks = 0; ks < 8; ks++) {
                int boff = (16 * w + lo16) * HSTR + ks * 32 + hi4 * 8;
                half8 bh = *(const half8*)&U[boff];
                int woff = lo16 * NH + ks * 32 + hi4 * 8;
                half8 ah = *(const half8*)&W1Thi[woff];
                accj = MFMA16(ah, bh, accj);
            }
            #pragma unroll
            for (int r = 0; r < 4; r++)
                Jfin[(4 * hi4 + r) * 260 + 128 * p + 16 * w + lo16] = accj[r];
        }
        __syncthreads();
    }

    // ---- projection: 2 halves, e = 8w + 4*half + hi4, s = lo16 ----
    #pragma unroll
    for (int half = 0; half < 2; half++) {
        const int e = 8 * w + 4 * half + hi4, s = lo16;
        float acol[4];
        #pragma unroll
        for (int c = 0; c < 4; c++) acol[c] = Jfin[s * 260 + 4 * e + c];
        const int et = e >> 4, c16 = e & 15;
        float dval = Pb[et * 272 + s * 17 + c16] + Pb[(et + 4) * 272 + s * 17 + c16];
        #pragma unroll
        for (int c = 0; c < 4; c++) {
            float n2 = wsum16(acol[c] * acol[c]);
            float inv = (n2 > 1e-30f) ? (1.0f / sqrtf(n2)) : 0.0f;
            float q = acol[c] * inv;
            #pragma unroll
            for (int cc = c + 1; cc < 4; cc++) {
                float pj = wsum16(acol[cc] * q);
                acol[cc] -= pj * q;
            }
            float pd = wsum16(dval * q);
            dval -= pd * q;
        }
        OUT[(size_t)(ebase + e) * NS + s] = dval;
    }
}

// ---------------- f32 fallback (round-1 kernel) ----------------
__device__ __forceinline__ float dot4f(float4 a, float4 b) {
    return a.x*b.x + a.y*b.y + a.z*b.z + a.w*b.w;
}

__global__ void __launch_bounds__(256, 2)
comet_fused_f32(const float* __restrict__ Z,
                const float* __restrict__ W1,
                const float* __restrict__ W2,
                const float* __restrict__ W3,
                const float* __restrict__ W4,
                float* __restrict__ OUT)
{
    __shared__ __align__(16) float h_lds[4][4][NH];
    __shared__ __align__(16) float m_lds[4][4][NH][NC];

    const int l = threadIdx.x & 63;
    const int w = threadIdx.x >> 6;
    float (*hb)[NH]     = h_lds[w];
    float (*mb)[NH][NC] = m_lds[w];
    const int ebase = (blockIdx.x * 4 + w) * 4;

    float d1g[4][4], d2g[4][4], d3g[4][4];

    {
        float acc[4][4];
        #pragma unroll
        for (int j = 0; j < 4; j++)
            #pragma unroll
            for (int e = 0; e < 4; e++) acc[j][e] = 0.f;
        #pragma unroll
        for (int s4 = 0; s4 < 4; s4++) {
            float4 wf[4];
            #pragma unroll
            for (int j = 0; j < 4; j++)
                wf[j] = *(const float4*)&W1[(l + 64*j) * NS + s4*4];
            #pragma unroll
            for (int e = 0; e < 4; e++) {
                float4 xv = *(const float4*)&Z[(ebase + e) * NS + s4*4];
                #pragma unroll
                for (int j = 0; j < 4; j++) acc[j][e] += dot4f(wf[j], xv);
            }
        }
        #pragma unroll
        for (int j = 0; j < 4; j++)
            #pragma unroll
            for (int e = 0; e < 4; e++) {
                float a = acc[j][e];
                d1g[j][e] = siggf(a);
                hb[e][l + 64*j] = logsigf(a);
            }
    }
    __syncthreads();

#define FWD_LAYER(WPTR, GARR)                                                   \
    {                                                                           \
        float acc[4][4];                                                        \
        _Pragma("unroll")                                                       \
        for (int j = 0; j < 4; j++) {                                           \
            _Pragma("unroll")                                                   \
            for (int e = 0; e < 4; e++) acc[j][e] = 0.f;                        \
        }                                                                       \
        _Pragma("unroll 2")                                                     \
        for (int kk = 0; kk < NH; kk += 4) {                                    \
            float wv[4][4];                                                     \
            _Pragma("unroll")                                                   \
            for (int j = 0; j < 4; j++) {                                       \
                float4 t = *(const float4*)&WPTR[(l + 64*j) * NH + kk];         \
                wv[0][j] = t.x; wv[1][j] = t.y; wv[2][j] = t.z; wv[3][j] = t.w; \
            }                                                                   \
            _Pragma("unroll")                                                   \
            for (int e = 0; e < 4; e++) {                                       \
                float4 hv = *(const float4*)&hb[e][kk];                         \
                _Pragma("unroll")                                               \
                for (int j = 0; j < 4; j++)                                     \
                    acc[j][e] += wv[0][j]*hv.x + wv[1][j]*hv.y                  \
                               + wv[2][j]*hv.z + wv[3][j]*hv.w;                 \
            }                                                                   \
        }                                                                       \
        __syncthreads();                                                        \
        _Pragma("unroll")                                                       \
        for (int j = 0; j < 4; j++) {                                           \
            _Pragma("unroll")                                                   \
            for (int e = 0; e < 4; e++) {                                       \
                float a = acc[j][e];                                            \
                GARR[j][e] = siggf(a);                                          \
                hb[e][l + 64*j] += logsigf(a);                                  \
            }                                                                   \
        }                                                                       \
        __syncthreads();                                                        \
    }

    FWD_LAYER(W2, d2g)
    FWD_LAYER(W3, d3g)
#undef FWD_LAYER

    const int e4 = l >> 4, s4 = l & 15;
    float dval = 0.f;
    {
        #pragma unroll 2
        for (int kk = 0; kk < NH; kk += 4) {
            float4 wf = *(const float4*)&W4[s4 * NH + kk];
            float4 hv = *(const float4*)&hb[e4][kk];
            dval += dot4f(wf, hv);
        }
    }

    float gacc[4][4][4];
    float vf[4][4];
    #pragma unroll
    for (int c = 0; c < 4; c++)
        #pragma unroll
        for (int j = 0; j < 4; j++)
            vf[c][j] = W4[(NS + c) * NH + l + 64*j];
    #pragma unroll
    for (int e = 0; e < 4; e++)
        #pragma unroll
        for (int c = 0; c < 4; c++)
            #pragma unroll
            for (int j = 0; j < 4; j++)
                gacc[e][c][j] = vf[c][j];
    #pragma unroll
    for (int j = 0; j < 4; j++)
        #pragma unroll
        for (int e = 0; e < 4; e++) {
            float g = d3g[j][e];
            float4 mv = make_float4(vf[0][j]*g, vf[1][j]*g, vf[2][j]*g, vf[3][j]*g);
            *(float4*)&mb[e][l + 64*j][0] = mv;
        }
    __syncthreads();

#define BWD_GEMM(WPTR)                                                          \
    {                                                                           \
        _Pragma("unroll 2")                                                     \
        for (int r = 0; r < NH; r++) {                                          \
            float wc[4];                                                        \
            _Pragma("unroll")                                                   \
            for (int j = 0; j < 4; j++) wc[j] = WPTR[r * NH + l + 64*j];        \
            _Pragma("unroll")                                                   \
            for (int e = 0; e < 4; e++) {                                       \
                float4 mv = *(const float4*)&mb[e][r][0];                       \
                _Pragma("unroll")                                               \
                for (int j = 0; j < 4; j++) {                                   \
                    gacc[e][0][j] += wc[j]*mv.x;                                \
                    gacc[e][1][j] += wc[j]*mv.y;                                \
                    gacc[e][2][j] += wc[j]*mv.z;                                \
                    gacc[e][3][j] += wc[j]*mv.w;                                \
                }                                                               \
            }                                                                   \
        }                                                                       \
    }

    BWD_GEMM(W3)
    __syncthreads();
    #pragma unroll
    for (int j = 0; j < 4; j++)
        #pragma unroll
        for (int e = 0; e < 4; e++) {
            float g = d2g[j][e];
            float4 mv = make_float4(gacc[e][0][j]*g, gacc[e][1][j]*g,
                                    gacc[e][2][j]*g, gacc[e][3][j]*g);
            *(float4*)&mb[e][l + 64*j][0] = mv;
        }
    __syncthreads();
    BWD_GEMM(W2)
#undef BWD_GEMM
    __syncthreads();
    #pragma unroll
    for (int j = 0; j < 4; j++)
        #pragma unroll
        for (int e = 0; e < 4; e++) {
            float g = d1g[j][e];
            float4 mv = make_float4(gacc[e][0][j]*g, gacc[e][1][j]*g,
                                    gacc[e][2][j]*g, gacc[e][3][j]*g);
            *(float4*)&mb[e][l + 64*j][0] = mv;
        }
    __syncthreads();

    const int c4 = l >> 4;
    float jv[4] = {0.f, 0.f, 0.f, 0.f};
    #pragma unroll 4
    for (int r = 0; r < NH; r++) {
        float w1v = W1[r * NS + s4];
        #pragma unroll
        for (int e = 0; e < 4; e++) jv[e] += mb[e][r][c4] * w1v;
    }
    __syncthreads();

    float* jlds = (float*)hb;
    #pragma unroll
    for (int e = 0; e < 4; e++) jlds[e * 64 + c4 * 16 + s4] = jv[e];
    __syncthreads();

    float acol[4];
    acol[0] = jlds[e4 * 64 +      s4];
    acol[1] = jlds[e4 * 64 + 16 + s4];
    acol[2] = jlds[e4 * 64 + 32 + s4];
    acol[3] = jlds[e4 * 64 + 48 + s4];
    #pragma unroll
    for (int c = 0; c < 4; c++) {
        float n2 = wsum16(acol[c] * acol[c]);
        float inv = (n2 > 1e-30f) ? (1.0f / sqrtf(n2)) : 0.0f;
        float q = acol[c] * inv;
        #pragma unroll
        for (int cc = c + 1; cc < 4; cc++) {
            float p = wsum16(acol[cc] * q);
            acol[cc] -= p * q;
        }
        float pd = wsum16(dval * q);
        dval -= pd * q;
    }
    OUT[ebase * NS + l] = dval;
}

extern "C" void kernel_launch(void* const* d_in, const int* in_sizes, int n_in,
                              void* d_out, int out_size, void* d_ws, size_t ws_size,
                              hipStream_t stream) {
    const float* Z  = (const float*)d_in[0];
    const float* W1 = (const float*)d_in[1];
    const float* W2 = (const float*)d_in[2];
    const float* W3 = (const float*)d_in[3];
    const float* W4 = (const float*)d_in[4];
    float* OUT = (float*)d_out;

    const size_t need = (size_t)WS_HALVES * sizeof(_Float16);

    if (ws_size >= need) {
        _Float16* ws = (_Float16*)d_ws;
        hipLaunchKernelGGL(prep_big, dim3(NH, 2), dim3(NH), 0, stream, W2, W3, ws);
        hipLaunchKernelGGL(prep_small, dim3(1), dim3(NH), 0, stream, W1, W4, ws);
        hipLaunchKernelGGL(comet_mfma, dim3(BATCH / EPB), dim3(512), 0, stream,
                           Z, W4, ws, OUT);
    } else {
        hipLaunchKernelGGL(comet_fused_f32, dim3(BATCH / 16), dim3(256), 0, stream,
                           Z, W1, W2, W3, W4, OUT);
    }
}

// Round 13
// 796.360 us; speedup vs baseline: 3.0872x; 1.1195x over previous
//
#include <hip/hip_runtime.h>
#include <math.h>

#define NS 16
#define NC 4
#define NH 256
#define BATCH 262144
#define EPB 64      // elements per block
#define HSTR 264    // halves; 528 B rows = 16B-aligned (b128 requirement), 4-word bank rotation

typedef _Float16 half8 __attribute__((ext_vector_type(8)));
typedef _Float16 half4v __attribute__((ext_vector_type(4)));
typedef _Float16 half2v __attribute__((ext_vector_type(2)));
typedef float f32x4 __attribute__((ext_vector_type(4)));

#define MFMA16(a, b, c) __builtin_amdgcn_mfma_f32_16x16x32_f16((a), (b), (c), 0, 0, 0)

// ---------- ws layout (in halves) ----------
#define OFF_W2HI   0
#define OFF_W2LO   65536
#define OFF_W3HI   131072
#define OFF_W3LO   196608
#define OFF_W2THI  262144
#define OFF_W2TLO  327680
#define OFF_W3THI  393216
#define OFF_W3TLO  458752
#define OFF_W1PHI  524288
#define OFF_W1PLO  532480
#define OFF_W1THI  540672
#define OFF_W1TLO  544768
#define OFF_W4HI   548864
#define OFF_W4LO   552960
#define WS_HALVES  557056   // * 2 bytes = 1,114,112

__device__ __forceinline__ float logsigf(float a) {
    return fminf(a, 0.f) - __logf(1.f + __expf(-fabsf(a)));
}
__device__ __forceinline__ float siggf(float a) {   // sigma(-a)
    return 1.f / (1.f + __expf(a));
}
// shared-exp: both logsig(a) and sigma(-a) from one exp
__device__ __forceinline__ void act2(float a, float& ls, float& g) {
    float e  = __expf(-fabsf(a));
    float om = 1.f + e;
    float r  = __builtin_amdgcn_rcpf(om);
    ls = fminf(a, 0.f) - __logf(om);
    g  = (a >= 0.f) ? e * r : r;
}
__device__ __forceinline__ void split2(float x, _Float16& h, _Float16& l) {
    h = (_Float16)x;
    l = (_Float16)(x - (float)h);
}
__device__ __forceinline__ float wsum16(float v) {
    v += __shfl_xor(v, 1, 64);
    v += __shfl_xor(v, 2, 64);
    v += __shfl_xor(v, 4, 64);
    v += __shfl_xor(v, 8, 64);
    return v;
}
__device__ __forceinline__ unsigned h2u(half2v h) {
    union { half2v h; unsigned u; } c; c.h = h; return c.u;
}
__device__ __forceinline__ half2v u2h(unsigned u) {
    union { half2v h; unsigned u; } c; c.u = u; return c.h;
}
__device__ __forceinline__ half2v pkrtz(float a, float b) {
    // builtin returns __fp16x2; bit-cast to _Float16x2
    auto t = __builtin_amdgcn_cvt_pkrtz(a, b);
    union { decltype(t) s; half2v d; } c; c.s = t; return c.d;
}
__device__ __forceinline__ uint2 packg2(float g0, float g1, float g2, float g3) {
    return make_uint2(h2u(pkrtz(g0, g1)), h2u(pkrtz(g2, g3)));
}
union H4u { half4v v4; half2v v2[2]; };

// ---------------- prep kernels ----------------
extern "C" __global__ void __launch_bounds__(256)
prep_big(const float* __restrict__ W2, const float* __restrict__ W3,
         _Float16* __restrict__ ws) {
    const int mat = blockIdx.y;
    const float* W = mat ? W3 : W2;
    _Float16* Whi  = ws + (mat ? OFF_W3HI  : OFF_W2HI);
    _Float16* Wlo  = Whi + 65536;
    _Float16* WThi = ws + (mat ? OFF_W3THI : OFF_W2THI);
    _Float16* WTlo = WThi + 65536;
    const int r = blockIdx.x, c = threadIdx.x;
    float x = W[r * NH + c];
    _Float16 h, l; split2(x, h, l);
    Whi[r * NH + c] = h;  Wlo[r * NH + c] = l;
    WThi[c * NH + r] = h; WTlo[c * NH + r] = l;
}

extern "C" __global__ void __launch_bounds__(256)
prep_small(const float* __restrict__ W1, const float* __restrict__ W4,
           _Float16* __restrict__ ws) {
    _Float16* W1phi = ws + OFF_W1PHI;
    _Float16* W1plo = ws + OFF_W1PLO;
    _Float16* W1Thi = ws + OFF_W1THI;
    _Float16* W1Tlo = ws + OFF_W1TLO;
    _Float16* W4hi  = ws + OFF_W4HI;
    _Float16* W4lo  = ws + OFF_W4LO;
    const int t = threadIdx.x;   // 0..255 (= W1 row)
    #pragma unroll
    for (int s = 0; s < NS; s++) {
        float x = W1[t * NS + s];
        _Float16 h, l; split2(x, h, l);
        W1phi[t * 32 + s] = h;        W1plo[t * 32 + s] = l;
        W1phi[t * 32 + 16 + s] = (_Float16)0.f;
        W1plo[t * 32 + 16 + s] = (_Float16)0.f;
        W1Thi[s * NH + t] = h;        W1Tlo[s * NH + t] = l;
    }
    #pragma unroll
    for (int q = 0; q < 16; q++) {
        int idx = q * 256 + t;       // covers rows 0..15 of W4
        float x = W4[idx];
        _Float16 h, l; split2(x, h, l);
        W4hi[idx] = h; W4lo[idx] = l;
    }
}

// ---------------- main fused MFMA kernel ----------------
// E=64/block, 512 threads = 8 waves. Wave w owns hidden rows 32w..32w+31
// (2 m-tiles). Forward N=64 (4 e-tiles): F1 3-term; F2/F3 single-term;
// H stored SINGLE f16 (hi-only; f16/layer accumulation err ~1e-3 << floor);
// F4 2-term (W4 hi+lo x H) split-K over 8 waves. Backward: 2 passes x
// 32 elems (128 cols, 8 n-tiles), single-term, acc2[2][8]; m-stores use
// v_pk_mul_f16 + cvt_pkrtz (no f16<->f32 round trips for gates).
// Shared-exp act2(): 1 exp + 1 log + 1 rcp per activation (was 2 exp +
// 1 log + exact-div). LDS = 92,928 B -> 1 block/CU.

__device__ __forceinline__ void gemm_fwd1(const _Float16* __restrict__ Ahi,
                                          const _Float16* U,
                                          int w, int lo16, int hi4, f32x4 acc[2][4]) {
    #pragma unroll
    for (int ks = 0; ks < 8; ks++) {
        half8 bh[4];
        #pragma unroll
        for (int n = 0; n < 4; n++)
            bh[n] = *(const half8*)&U[(16 * n + lo16) * HSTR + ks * 32 + hi4 * 8];
        #pragma unroll
        for (int m = 0; m < 2; m++) {
            int woff = (32 * w + 16 * m + lo16) * NH + ks * 32 + hi4 * 8;
            half8 ah = *(const half8*)&Ahi[woff];
            #pragma unroll
            for (int n = 0; n < 4; n++)
                acc[m][n] = MFMA16(ah, bh[n], acc[m][n]);
        }
    }
}

// single-term backward GEMM over 8 n-tiles (128 cols)
__device__ __forceinline__ void gemm_bwd1(const _Float16* __restrict__ Ahi,
                                          const _Float16* U,
                                          int w, int lo16, int hi4, f32x4 acc[2][8]) {
    #pragma unroll
    for (int ks = 0; ks < 8; ks++) {
        half8 bh[8];
        #pragma unroll
        for (int n = 0; n < 8; n++)
            bh[n] = *(const half8*)&U[(16 * n + lo16) * HSTR + ks * 32 + hi4 * 8];
        #pragma unroll
        for (int m = 0; m < 2; m++) {
            int woff = (32 * w + 16 * m + lo16) * NH + ks * 32 + hi4 * 8;
            half8 ah = *(const half8*)&Ahi[woff];
            #pragma unroll
            for (int n = 0; n < 8; n++)
                acc[m][n] = MFMA16(ah, bh[n], acc[m][n]);
        }
    }
}

__global__ void __launch_bounds__(512, 1)
comet_mfma(const float* __restrict__ Z,
           const float* __restrict__ W4,
           const _Float16* __restrict__ ws,
           float* __restrict__ OUT)
{
    const _Float16* W2hi  = ws + OFF_W2HI;
    const _Float16* W3hi  = ws + OFF_W3HI;
    const _Float16* W2Thi = ws + OFF_W2THI;
    const _Float16* W3Thi = ws + OFF_W3THI;
    const _Float16* W1phi = ws + OFF_W1PHI;
    const _Float16* W1plo = ws + OFF_W1PLO;
    const _Float16* W1Thi = ws + OFF_W1THI;
    const _Float16* W4hi  = ws + OFF_W4HI;
    const _Float16* W4lo  = ws + OFF_W4LO;

    __shared__ __align__(16) _Float16 U[128 * HSTR];   // 67,584 B
    __shared__ __align__(16) float Jfin[16 * 260];     // 16,640 B
    __shared__ __align__(16) float Pb[8 * 272];        //  8,704 B

    const int tid  = threadIdx.x;
    const int l    = tid & 63, w = tid >> 6;
    const int lo16 = l & 15, hi4 = l >> 4;
    const int ebase = blockIdx.x * EPB;
    const int c4 = lo16 & 3;

    // ---- V (rows 16..19 of W4): f32 for the exact skip-add, f16x2 for pk_mul ----
    float4 vreg[2];
    half2v vregh[2][2];
    #pragma unroll
    for (int m = 0; m < 2; m++) {
        vreg[m] = *(const float4*)&W4[(NS + c4) * NH + 32 * w + 16 * m + 4 * hi4];
        vregh[m][0] = pkrtz(vreg[m].x, vreg[m].y);
        vregh[m][1] = pkrtz(vreg[m].z, vreg[m].w);
    }

    uint2 g1u[2][4], g2u[2][4], g3u[2][4];   // [m][e-tile] packed f16 gates

    // ---- F1 : a1 = W1p @ Zpad (3-term) ; B-frags direct from global ----
    {
        f32x4 acc[2][4];
        #pragma unroll
        for (int m = 0; m < 2; m++)
            #pragma unroll
            for (int n = 0; n < 4; n++) acc[m][n] = (f32x4)(0.f);
        half8 bh[4], bl[4];
        #pragma unroll
        for (int n = 0; n < 4; n++) {
            if (hi4 < 2) {
                const float* zp = &Z[(size_t)(ebase + 16 * n + lo16) * NS + hi4 * 8];
                float4 z0 = *(const float4*)zp;
                float4 z1 = *(const float4*)(zp + 4);
                float zz[8] = {z0.x, z0.y, z0.z, z0.w, z1.x, z1.y, z1.z, z1.w};
                #pragma unroll
                for (int r = 0; r < 8; r++) {
                    _Float16 h, lo; split2(zz[r], h, lo);
                    bh[n][r] = h; bl[n][r] = lo;
                }
            } else {
                #pragma unroll
                for (int r = 0; r < 8; r++) { bh[n][r] = (_Float16)0.f; bl[n][r] = (_Float16)0.f; }
            }
        }
        #pragma unroll
        for (int m = 0; m < 2; m++) {
            int woff = (32 * w + 16 * m + lo16) * 32 + hi4 * 8;
            half8 ah = *(const half8*)&W1phi[woff];
            half8 al = *(const half8*)&W1plo[woff];
            #pragma unroll
            for (int n = 0; n < 4; n++) {
                acc[m][n] = MFMA16(ah, bh[n], acc[m][n]);
                acc[m][n] = MFMA16(al, bh[n], acc[m][n]);
                acc[m][n] = MFMA16(ah, bl[n], acc[m][n]);
            }
        }
        #pragma unroll
        for (int m = 0; m < 2; m++)
            #pragma unroll
            for (int n = 0; n < 4; n++) {
                int hoff = (16 * n + lo16) * HSTR + 32 * w + 16 * m + 4 * hi4;
                float gv[4];
                half4v nh;
                #pragma unroll
                for (int r = 0; r < 4; r++) {
                    float ls, g;
                    act2(acc[m][n][r], ls, g);
                    gv[r] = g;
                    nh[r] = (_Float16)ls;
                }
                g1u[m][n] = packg2(gv[0], gv[1], gv[2], gv[3]);
                *(half4v*)&U[hoff] = nh;
            }
    }
    __syncthreads();

    // ---- F2, F3 (single-term, single-f16 H) ----
    #pragma unroll
    for (int L = 0; L < 2; L++) {
        f32x4 acc[2][4];
        #pragma unroll
        for (int m = 0; m < 2; m++)
            #pragma unroll
            for (int n = 0; n < 4; n++) acc[m][n] = (f32x4)(0.f);
        gemm_fwd1(L ? W3hi : W2hi, U, w, lo16, hi4, acc);
        __syncthreads();   // all reads of H done before update
        #pragma unroll
        for (int m = 0; m < 2; m++)
            #pragma unroll
            for (int n = 0; n < 4; n++) {
                int hoff = (16 * n + lo16) * HSTR + 32 * w + 16 * m + 4 * hi4;
                half4v oh = *(const half4v*)&U[hoff];
                float gv[4];
                half4v nh;
                #pragma unroll
                for (int r = 0; r < 4; r++) {
                    float ls, g;
                    act2(acc[m][n][r], ls, g);
                    gv[r] = g;
                    nh[r] = (_Float16)((float)oh[r] + ls);
                }
                if (L) g3u[m][n] = packg2(gv[0], gv[1], gv[2], gv[3]);
                else   g2u[m][n] = packg2(gv[0], gv[1], gv[2], gv[3]);
                *(half4v*)&U[hoff] = nh;
            }
        __syncthreads();
    }

    // ---- F4 : d = W4[0:16] @ h3 ; 2-term, wave = (e-tile w&3, k-half w>>2) ----
    {
        const int et = w & 3, kh = w >> 2;
        f32x4 acc = (f32x4)(0.f);
        #pragma unroll
        for (int i = 0; i < 4; i++) {
            int ks = 4 * kh + i;
            int boff = (16 * et + lo16) * HSTR + ks * 32 + hi4 * 8;
            half8 bh = *(const half8*)&U[boff];
            int woff = lo16 * NH + ks * 32 + hi4 * 8;
            half8 ah = *(const half8*)&W4hi[woff];
            half8 al = *(const half8*)&W4lo[woff];
            acc = MFMA16(ah, bh, acc);
            acc = MFMA16(al, bh, acc);
        }
        #pragma unroll
        for (int r = 0; r < 4; r++)
            Pb[w * 272 + (hi4 * 4 + r) * 17 + lo16] = acc[r];
    }
    __syncthreads();   // H (union) dead; M may be written

    // ---- backward: 2 passes x 32 elems (128 cotangent cols each) ----
    #pragma unroll
    for (int p = 0; p < 2; p++) {
        // m3 = V .* d3  (pure packed-f16 math)
        #pragma unroll
        for (int m = 0; m < 2; m++)
            #pragma unroll
            for (int n = 0; n < 8; n++) {
                const int src = (l & 48) | (4 * (n & 3) + (lo16 >> 2));
                const int et = 2 * p + (n >> 2);
                const int kbase = 32 * w + 16 * m + 4 * hi4;
                half2v g01 = u2h((unsigned)__shfl((int)g3u[m][et].x, src, 64));
                half2v g23 = u2h((unsigned)__shfl((int)g3u[m][et].y, src, 64));
                H4u t;
                t.v2[0] = vregh[m][0] * g01;
                t.v2[1] = vregh[m][1] * g23;
                *(half4v*)&U[(16 * n + lo16) * HSTR + kbase] = t.v4;
            }
        __syncthreads();

        // B3: G2 = W3^T @ m3
        f32x4 acc2[2][8];
        #pragma unroll
        for (int m = 0; m < 2; m++)
            #pragma unroll
            for (int n = 0; n < 8; n++) acc2[m][n] = (f32x4)(0.f);
        gemm_bwd1(W3Thi, U, w, lo16, hi4, acc2);
        __syncthreads();   // readers of m3 done

        // g2 = V + G2 (f32 skip, exact) ; m2 = f16(g2) .* f16(d2-gate)
        #pragma unroll
        for (int m = 0; m < 2; m++)
            #pragma unroll
            for (int n = 0; n < 8; n++) {
                const int src = (l & 48) | (4 * (n & 3) + (lo16 >> 2));
                const int et = 2 * p + (n >> 2);
                const int kbase = 32 * w + 16 * m + 4 * hi4;
                half2v g01 = u2h((unsigned)__shfl((int)g2u[m][et].x, src, 64));
                half2v g23 = u2h((unsigned)__shfl((int)g2u[m][et].y, src, 64));
                float gg[4];
                #pragma unroll
                for (int r = 0; r < 4; r++) {
                    gg[r] = vreg[m][r] + acc2[m][n][r];
                    acc2[m][n][r] = gg[r];
                }
                H4u t;
                t.v2[0] = pkrtz(gg[0], gg[1]) * g01;
                t.v2[1] = pkrtz(gg[2], gg[3]) * g23;
                *(half4v*)&U[(16 * n + lo16) * HSTR + kbase] = t.v4;
            }
        __syncthreads();

        // B2: g1tot = g2 + W2^T @ m2  (accumulate onto acc2)
        gemm_bwd1(W2Thi, U, w, lo16, hi4, acc2);
        __syncthreads();

        // m1 = g1tot .* d1
        #pragma unroll
        for (int m = 0; m < 2; m++)
            #pragma unroll
            for (int n = 0; n < 8; n++) {
                const int src = (l & 48) | (4 * (n & 3) + (lo16 >> 2));
                const int et = 2 * p + (n >> 2);
                const int kbase = 32 * w + 16 * m + 4 * hi4;
                half2v g01 = u2h((unsigned)__shfl((int)g1u[m][et].x, src, 64));
                half2v g23 = u2h((unsigned)__shfl((int)g1u[m][et].y, src, 64));
                H4u t;
                t.v2[0] = pkrtz(acc2[m][n][0], acc2[m][n][1]) * g01;
                t.v2[1] = pkrtz(acc2[m][n][2], acc2[m][n][3]) * g23;
                *(half4v*)&U[(16 * n + lo16) * HSTR + kbase] = t.v4;
            }
        __syncthreads();

        // J = W1^T @ m1 ; all 8 waves, wave w = n-tile w, full K
        {
            f32x4 accj = (f32x4)(0.f);
            #pragma unroll
            for (int ks = 0; ks < 8; ks++) {
                int boff = (16 * w + lo16) * HSTR + ks * 32 + hi4 * 8;
                half8 bh = *(const half8*)&U[boff];
                int woff = lo16 * NH + ks * 32 + hi4 * 8;
                half8 ah = *(const half8*)&W1Thi[woff];
                accj = MFMA16(ah, bh, accj);
            }
            #pragma unroll
            for (int r = 0; r < 4; r++)
                Jfin[(4 * hi4 + r) * 260 + 128 * p + 16 * w + lo16] = accj[r];
        }
        __syncthreads();
    }

    // ---- projection: 2 halves, e = 8w + 4*half + hi4, s = lo16 ----
    #pragma unroll
    for (int half = 0; half < 2; half++) {
        const int e = 8 * w + 4 * half + hi4, s = lo16;
        float acol[4];
        #pragma unroll
        for (int c = 0; c < 4; c++) acol[c] = Jfin[s * 260 + 4 * e + c];
        const int et = e >> 4, c16 = e & 15;
        float dval = Pb[et * 272 + s * 17 + c16] + Pb[(et + 4) * 272 + s * 17 + c16];
        #pragma unroll
        for (int c = 0; c < 4; c++) {
            float n2 = wsum16(acol[c] * acol[c]);
            float inv = (n2 > 1e-30f) ? (1.0f / sqrtf(n2)) : 0.0f;
            float q = acol[c] * inv;
            #pragma unroll
            for (int cc = c + 1; cc < 4; cc++) {
                float pj = wsum16(acol[cc] * q);
                acol[cc] -= pj * q;
            }
            float pd = wsum16(dval * q);
            dval -= pd * q;
        }
        OUT[(size_t)(ebase + e) * NS + s] = dval;
    }
}

// ---------------- f32 fallback (round-1 kernel) ----------------
__device__ __forceinline__ float dot4f(float4 a, float4 b) {
    return a.x*b.x + a.y*b.y + a.z*b.z + a.w*b.w;
}

__global__ void __launch_bounds__(256, 2)
comet_fused_f32(const float* __restrict__ Z,
                const float* __restrict__ W1,
                const float* __restrict__ W2,
                const float* __restrict__ W3,
                const float* __restrict__ W4,
                float* __restrict__ OUT)
{
    __shared__ __align__(16) float h_lds[4][4][NH];
    __shared__ __align__(16) float m_lds[4][4][NH][NC];

    const int l = threadIdx.x & 63;
    const int w = threadIdx.x >> 6;
    float (*hb)[NH]     = h_lds[w];
    float (*mb)[NH][NC] = m_lds[w];
    const int ebase = (blockIdx.x * 4 + w) * 4;

    float d1g[4][4], d2g[4][4], d3g[4][4];

    {
        float acc[4][4];
        #pragma unroll
        for (int j = 0; j < 4; j++)
            #pragma unroll
            for (int e = 0; e < 4; e++) acc[j][e] = 0.f;
        #pragma unroll
        for (int s4 = 0; s4 < 4; s4++) {
            float4 wf[4];
            #pragma unroll
            for (int j = 0; j < 4; j++)
                wf[j] = *(const float4*)&W1[(l + 64*j) * NS + s4*4];
            #pragma unroll
            for (int e = 0; e < 4; e++) {
                float4 xv = *(const float4*)&Z[(ebase + e) * NS + s4*4];
                #pragma unroll
                for (int j = 0; j < 4; j++) acc[j][e] += dot4f(wf[j], xv);
            }
        }
        #pragma unroll
        for (int j = 0; j < 4; j++)
            #pragma unroll
            for (int e = 0; e < 4; e++) {
                float a = acc[j][e];
                d1g[j][e] = siggf(a);
                hb[e][l + 64*j] = logsigf(a);
            }
    }
    __syncthreads();

#define FWD_LAYER(WPTR, GARR)                                                   \
    {                                                                           \
        float acc[4][4];                                                        \
        _Pragma("unroll")                                                       \
        for (int j = 0; j < 4; j++) {                                           \
            _Pragma("unroll")                                                   \
            for (int e = 0; e < 4; e++) acc[j][e] = 0.f;                        \
        }                                                                       \
        _Pragma("unroll 2")                                                     \
        for (int kk = 0; kk < NH; kk += 4) {                                    \
            float wv[4][4];                                                     \
            _Pragma("unroll")                                                   \
            for (int j = 0; j < 4; j++) {                                       \
                float4 t = *(const float4*)&WPTR[(l + 64*j) * NH + kk];         \
                wv[0][j] = t.x; wv[1][j] = t.y; wv[2][j] = t.z; wv[3][j] = t.w; \
            }                                                                   \
            _Pragma("unroll")                                                   \
            for (int e = 0; e < 4; e++) {                                       \
                float4 hv = *(const float4*)&hb[e][kk];                         \
                _Pragma("unroll")                                               \
                for (int j = 0; j < 4; j++)                                     \
                    acc[j][e] += wv[0][j]*hv.x + wv[1][j]*hv.y                  \
                               + wv[2][j]*hv.z + wv[3][j]*hv.w;                 \
            }                                                                   \
        }                                                                       \
        __syncthreads();                                                        \
        _Pragma("unroll")                                                       \
        for (int j = 0; j < 4; j++) {                                           \
            _Pragma("unroll")                                                   \
            for (int e = 0; e < 4; e++) {                                       \
                float a = acc[j][e];                                            \
                GARR[j][e] = siggf(a);                                          \
                hb[e][l + 64*j] += logsigf(a);                                  \
            }                                                                   \
        }                                                                       \
        __syncthreads();                                                        \
    }

    FWD_LAYER(W2, d2g)
    FWD_LAYER(W3, d3g)
#undef FWD_LAYER

    const int e4 = l >> 4, s4 = l & 15;
    float dval = 0.f;
    {
        #pragma unroll 2
        for (int kk = 0; kk < NH; kk += 4) {
            float4 wf = *(const float4*)&W4[s4 * NH + kk];
            float4 hv = *(const float4*)&hb[e4][kk];
            dval += dot4f(wf, hv);
        }
    }

    float gacc[4][4][4];
    float vf[4][4];
    #pragma unroll
    for (int c = 0; c < 4; c++)
        #pragma unroll
        for (int j = 0; j < 4; j++)
            vf[c][j] = W4[(NS + c) * NH + l + 64*j];
    #pragma unroll
    for (int e = 0; e < 4; e++)
        #pragma unroll
        for (int c = 0; c < 4; c++)
            #pragma unroll
            for (int j = 0; j < 4; j++)
                gacc[e][c][j] = vf[c][j];
    #pragma unroll
    for (int j = 0; j < 4; j++)
        #pragma unroll
        for (int e = 0; e < 4; e++) {
            float g = d3g[j][e];
            float4 mv = make_float4(vf[0][j]*g, vf[1][j]*g, vf[2][j]*g, vf[3][j]*g);
            *(float4*)&mb[e][l + 64*j][0] = mv;
        }
    __syncthreads();

#define BWD_GEMM(WPTR)                                                          \
    {                                                                           \
        _Pragma("unroll 2")                                                     \
        for (int r = 0; r < NH; r++) {                                          \
            float wc[4];                                                        \
            _Pragma("unroll")                                                   \
            for (int j = 0; j < 4; j++) wc[j] = WPTR[r * NH + l + 64*j];        \
            _Pragma("unroll")                                                   \
            for (int e = 0; e < 4; e++) {                                       \
                float4 mv = *(const float4*)&mb[e][r][0];                       \
                _Pragma("unroll")                                               \
                for (int j = 0; j < 4; j++) {                                   \
                    gacc[e][0][j] += wc[j]*mv.x;                                \
                    gacc[e][1][j] += wc[j]*mv.y;                                \
                    gacc[e][2][j] += wc[j]*mv.z;                                \
                    gacc[e][3][j] += wc[j]*mv.w;                                \
                }                                                               \
            }                                                                   \
        }                                                                       \
    }

    BWD_GEMM(W3)
    __syncthreads();
    #pragma unroll
    for (int j = 0; j < 4; j++)
        #pragma unroll
        for (int e = 0; e < 4; e++) {
            float g = d2g[j][e];
            float4 mv = make_float4(gacc[e][0][j]*g, gacc[e][1][j]*g,
                                    gacc[e][2][j]*g, gacc[e][3][j]*g);
            *(float4*)&mb[e][l + 64*j][0] = mv;
        }
    __syncthreads();
    BWD_GEMM(W2)
#undef BWD_GEMM
    __syncthreads();
    #pragma unroll
    for (int j = 0; j < 4; j++)
        #pragma unroll
        for (int e = 0; e < 4; e++) {
            float g = d1g[j][e];
            float4 mv = make_float4(gacc[e][0][j]*g, gacc[e][1][j]*g,
                                    gacc[e][2][j]*g, gacc[e][3][j]*g);
            *(float4*)&mb[e][l + 64*j][0] = mv;
        }
    __syncthreads();

    const int c4 = l >> 4;
    float jv[4] = {0.f, 0.f, 0.f, 0.f};
    #pragma unroll 4
    for (int r = 0; r < NH; r++) {
        float w1v = W1[r * NS + s4];
        #pragma unroll
        for (int e = 0; e < 4; e++) jv[e] += mb[e][r][c4] * w1v;
    }
    __syncthreads();

    float* jlds = (float*)hb;
    #pragma unroll
    for (int e = 0; e < 4; e++) jlds[e * 64 + c4 * 16 + s4] = jv[e];
    __syncthreads();

    float acol[4];
    acol[0] = jlds[e4 * 64 +      s4];
    acol[1] = jlds[e4 * 64 + 16 + s4];
    acol[2] = jlds[e4 * 64 + 32 + s4];
    acol[3] = jlds[e4 * 64 + 48 + s4];
    #pragma unroll
    for (int c = 0; c < 4; c++) {
        float n2 = wsum16(acol[c] * acol[c]);
        float inv = (n2 > 1e-30f) ? (1.0f / sqrtf(n2)) : 0.0f;
        float q = acol[c] * inv;
        #pragma unroll
        for (int cc = c + 1; cc < 4; cc++) {
            float p = wsum16(acol[cc] * q);
            acol[cc] -= p * q;
        }
        float pd = wsum16(dval * q);
        dval -= pd * q;
    }
    OUT[ebase * NS + l] = dval;
}

extern "C" void kernel_launch(void* const* d_in, const int* in_sizes, int n_in,
                              void* d_out, int out_size, void* d_ws, size_t ws_size,
                              hipStream_t stream) {
    const float* Z  = (const float*)d_in[0];
    const float* W1 = (const float*)d_in[1];
    const float* W2 = (const float*)d_in[2];
    const float* W3 = (const float*)d_in[3];
    const float* W4 = (const float*)d_in[4];
    float* OUT = (float*)d_out;

    const size_t need = (size_t)WS_HALVES * sizeof(_Float16);

    if (ws_size >= need) {
        _Float16* ws = (_Float16*)d_ws;
        hipLaunchKernelGGL(prep_big, dim3(NH, 2), dim3(NH), 0, stream, W2, W3, ws);
        hipLaunchKernelGGL(prep_small, dim3(1), dim3(NH), 0, stream, W1, W4, ws);
        hipLaunchKernelGGL(comet_mfma, dim3(BATCH / EPB), dim3(512), 0, stream,
                           Z, W4, ws, OUT);
    } else {
        hipLaunchKernelGGL(comet_fused_f32, dim3(BATCH / 16), dim3(256), 0, stream,
                           Z, W1, W2, W3, W4, OUT);
    }
}

// Round 14
// 740.123 us; speedup vs baseline: 3.3218x; 1.0760x over previous
//
#include <hip/hip_runtime.h>
#include <math.h>

#define NS 16
#define NC 4
#define NH 256
#define BATCH 262144
#define EPB 64      // elements per block
#define HSTR 264    // halves; 528 B rows = 16B-aligned (b128 requirement), 4-word bank rotation

typedef _Float16 half8 __attribute__((ext_vector_type(8)));
typedef _Float16 half4v __attribute__((ext_vector_type(4)));
typedef _Float16 half2v __attribute__((ext_vector_type(2)));
typedef float f32x4 __attribute__((ext_vector_type(4)));

#define MFMA16(a, b, c) __builtin_amdgcn_mfma_f32_16x16x32_f16((a), (b), (c), 0, 0, 0)

// ---------- ws layout (in halves) ----------
#define OFF_W2HI   0
#define OFF_W2LO   65536
#define OFF_W3HI   131072
#define OFF_W3LO   196608
#define OFF_W2THI  262144
#define OFF_W2TLO  327680
#define OFF_W3THI  393216
#define OFF_W3TLO  458752
#define OFF_W1PHI  524288
#define OFF_W1PLO  532480
#define OFF_W1THI  540672
#define OFF_W1TLO  544768
#define OFF_W4HI   548864
#define OFF_W4LO   552960
#define WS_HALVES  557056   // * 2 bytes = 1,114,112

__device__ __forceinline__ float logsigf(float a) {
    return fminf(a, 0.f) - __logf(1.f + __expf(-fabsf(a)));
}
__device__ __forceinline__ float siggf(float a) {   // sigma(-a)
    return 1.f / (1.f + __expf(a));
}
// shared-exp: both logsig(a) and sigma(-a) from one exp
__device__ __forceinline__ void act2(float a, float& ls, float& g) {
    float e  = __expf(-fabsf(a));
    float om = 1.f + e;
    float r  = __builtin_amdgcn_rcpf(om);
    ls = fminf(a, 0.f) - __logf(om);
    g  = (a >= 0.f) ? e * r : r;
}
__device__ __forceinline__ void split2(float x, _Float16& h, _Float16& l) {
    h = (_Float16)x;
    l = (_Float16)(x - (float)h);
}
__device__ __forceinline__ float wsum16(float v) {
    v += __shfl_xor(v, 1, 64);
    v += __shfl_xor(v, 2, 64);
    v += __shfl_xor(v, 4, 64);
    v += __shfl_xor(v, 8, 64);
    return v;
}
__device__ __forceinline__ unsigned h2u(half2v h) {
    union { half2v h; unsigned u; } c; c.h = h; return c.u;
}
__device__ __forceinline__ half2v u2h(unsigned u) {
    union { half2v h; unsigned u; } c; c.u = u; return c.h;
}
__device__ __forceinline__ half2v pkrtz(float a, float b) {
    // builtin returns __fp16x2; bit-cast to _Float16x2
    auto t = __builtin_amdgcn_cvt_pkrtz(a, b);
    union { decltype(t) s; half2v d; } c; c.s = t; return c.d;
}
__device__ __forceinline__ uint2 packg2(float g0, float g1, float g2, float g3) {
    return make_uint2(h2u(pkrtz(g0, g1)), h2u(pkrtz(g2, g3)));
}
union H4u { half4v v4; half2v v2[2]; };

// ---------------- prep kernels ----------------
extern "C" __global__ void __launch_bounds__(256)
prep_big(const float* __restrict__ W2, const float* __restrict__ W3,
         _Float16* __restrict__ ws) {
    const int mat = blockIdx.y;
    const float* W = mat ? W3 : W2;
    _Float16* Whi  = ws + (mat ? OFF_W3HI  : OFF_W2HI);
    _Float16* Wlo  = Whi + 65536;
    _Float16* WThi = ws + (mat ? OFF_W3THI : OFF_W2THI);
    _Float16* WTlo = WThi + 65536;
    const int r = blockIdx.x, c = threadIdx.x;
    float x = W[r * NH + c];
    _Float16 h, l; split2(x, h, l);
    Whi[r * NH + c] = h;  Wlo[r * NH + c] = l;
    WThi[c * NH + r] = h; WTlo[c * NH + r] = l;
}

extern "C" __global__ void __launch_bounds__(256)
prep_small(const float* __restrict__ W1, const float* __restrict__ W4,
           _Float16* __restrict__ ws) {
    _Float16* W1phi = ws + OFF_W1PHI;
    _Float16* W1plo = ws + OFF_W1PLO;
    _Float16* W1Thi = ws + OFF_W1THI;
    _Float16* W1Tlo = ws + OFF_W1TLO;
    _Float16* W4hi  = ws + OFF_W4HI;
    _Float16* W4lo  = ws + OFF_W4LO;
    const int t = threadIdx.x;   // 0..255 (= W1 row)
    #pragma unroll
    for (int s = 0; s < NS; s++) {
        float x = W1[t * NS + s];
        _Float16 h, l; split2(x, h, l);
        W1phi[t * 32 + s] = h;        W1plo[t * 32 + s] = l;
        W1phi[t * 32 + 16 + s] = (_Float16)0.f;
        W1plo[t * 32 + 16 + s] = (_Float16)0.f;
        W1Thi[s * NH + t] = h;        W1Tlo[s * NH + t] = l;
    }
    #pragma unroll
    for (int q = 0; q < 16; q++) {
        int idx = q * 256 + t;       // covers rows 0..15 of W4
        float x = W4[idx];
        _Float16 h, l; split2(x, h, l);
        W4hi[idx] = h; W4lo[idx] = l;
    }
}

// ---------------- main fused MFMA kernel ----------------
// E=64/block, 512 threads = 8 waves. Wave w owns hidden rows 32w..32w+31
// (2 m-tiles). Forward N=64 (4 e-tiles): F1 3-term; F2/F3 single-term;
// H single f16. F4 2-term split-K. Backward: 2 passes x 32 elems
// (128 cols, 8 n-tiles), single-term, acc2[2][8].
// SHUFFLE-FREE gate mapping: backward col j = 16n+lo16 represents
// (E = 32p + 16(n&1) + lo16, c = n>>1). Gate owner has lo16 == E&15 ==
// this lane's lo16 -> gates are OWN-LANE (g*u[m][2p+(n&1)], static idx).
// V moves to LDS tables (Vb f32 for exact skip-add, Vbh f16 for pk_mul):
// 32 ds_reads replace 192 ds_bpermutes per wave. Projection reads J via
// col = 32c + 16((e>>4)&1) + (e&15) (+128 per pass).
// LDS = 99,200 B -> 1 block/CU.

__device__ __forceinline__ void gemm_fwd1(const _Float16* __restrict__ Ahi,
                                          const _Float16* U,
                                          int w, int lo16, int hi4, f32x4 acc[2][4]) {
    #pragma unroll
    for (int ks = 0; ks < 8; ks++) {
        half8 bh[4];
        #pragma unroll
        for (int n = 0; n < 4; n++)
            bh[n] = *(const half8*)&U[(16 * n + lo16) * HSTR + ks * 32 + hi4 * 8];
        #pragma unroll
        for (int m = 0; m < 2; m++) {
            int woff = (32 * w + 16 * m + lo16) * NH + ks * 32 + hi4 * 8;
            half8 ah = *(const half8*)&Ahi[woff];
            #pragma unroll
            for (int n = 0; n < 4; n++)
                acc[m][n] = MFMA16(ah, bh[n], acc[m][n]);
        }
    }
}

// single-term backward GEMM over 8 n-tiles (128 cols)
__device__ __forceinline__ void gemm_bwd1(const _Float16* __restrict__ Ahi,
                                          const _Float16* U,
                                          int w, int lo16, int hi4, f32x4 acc[2][8]) {
    #pragma unroll
    for (int ks = 0; ks < 8; ks++) {
        half8 bh[8];
        #pragma unroll
        for (int n = 0; n < 8; n++)
            bh[n] = *(const half8*)&U[(16 * n + lo16) * HSTR + ks * 32 + hi4 * 8];
        #pragma unroll
        for (int m = 0; m < 2; m++) {
            int woff = (32 * w + 16 * m + lo16) * NH + ks * 32 + hi4 * 8;
            half8 ah = *(const half8*)&Ahi[woff];
            #pragma unroll
            for (int n = 0; n < 8; n++)
                acc[m][n] = MFMA16(ah, bh[n], acc[m][n]);
        }
    }
}

__global__ void __launch_bounds__(512, 1)
comet_mfma(const float* __restrict__ Z,
           const float* __restrict__ W4,
           const _Float16* __restrict__ ws,
           float* __restrict__ OUT)
{
    const _Float16* W2hi  = ws + OFF_W2HI;
    const _Float16* W3hi  = ws + OFF_W3HI;
    const _Float16* W2Thi = ws + OFF_W2THI;
    const _Float16* W3Thi = ws + OFF_W3THI;
    const _Float16* W1phi = ws + OFF_W1PHI;
    const _Float16* W1plo = ws + OFF_W1PLO;
    const _Float16* W1Thi = ws + OFF_W1THI;
    const _Float16* W4hi  = ws + OFF_W4HI;
    const _Float16* W4lo  = ws + OFF_W4LO;

    __shared__ __align__(16) _Float16 U[128 * HSTR];   // 67,584 B
    __shared__ __align__(16) float Jfin[16 * 260];     // 16,640 B
    __shared__ __align__(16) float Pb[8 * 272];        //  8,704 B
    __shared__ __align__(16) float Vb[4 * 260];        //  4,160 B  (f32, skip-add)
    __shared__ __align__(16) _Float16 Vbh[4 * 264];    //  2,112 B  (f16, pk_mul)

    const int tid  = threadIdx.x;
    const int l    = tid & 63, w = tid >> 6;
    const int lo16 = l & 15, hi4 = l >> 4;
    const int ebase = blockIdx.x * EPB;

    // ---- stage V (rows 16..19 of W4) into LDS tables ----
    #pragma unroll
    for (int i = 0; i < 2; i++) {
        int idx = i * 512 + tid;
        int c = idx >> 8, k = idx & 255;
        float x = W4[(NS + c) * NH + k];
        Vb[c * 260 + k] = x;
        Vbh[c * 264 + k] = (_Float16)x;
    }

    uint2 g1u[2][4], g2u[2][4], g3u[2][4];   // [m][e-tile] packed f16 gates

    // ---- F1 : a1 = W1p @ Zpad (3-term) ; B-frags direct from global ----
    {
        f32x4 acc[2][4];
        #pragma unroll
        for (int m = 0; m < 2; m++)
            #pragma unroll
            for (int n = 0; n < 4; n++) acc[m][n] = (f32x4)(0.f);
        half8 bh[4], bl[4];
        #pragma unroll
        for (int n = 0; n < 4; n++) {
            if (hi4 < 2) {
                const float* zp = &Z[(size_t)(ebase + 16 * n + lo16) * NS + hi4 * 8];
                float4 z0 = *(const float4*)zp;
                float4 z1 = *(const float4*)(zp + 4);
                float zz[8] = {z0.x, z0.y, z0.z, z0.w, z1.x, z1.y, z1.z, z1.w};
                #pragma unroll
                for (int r = 0; r < 8; r++) {
                    _Float16 h, lo; split2(zz[r], h, lo);
                    bh[n][r] = h; bl[n][r] = lo;
                }
            } else {
                #pragma unroll
                for (int r = 0; r < 8; r++) { bh[n][r] = (_Float16)0.f; bl[n][r] = (_Float16)0.f; }
            }
        }
        #pragma unroll
        for (int m = 0; m < 2; m++) {
            int woff = (32 * w + 16 * m + lo16) * 32 + hi4 * 8;
            half8 ah = *(const half8*)&W1phi[woff];
            half8 al = *(const half8*)&W1plo[woff];
            #pragma unroll
            for (int n = 0; n < 4; n++) {
                acc[m][n] = MFMA16(ah, bh[n], acc[m][n]);
                acc[m][n] = MFMA16(al, bh[n], acc[m][n]);
                acc[m][n] = MFMA16(ah, bl[n], acc[m][n]);
            }
        }
        #pragma unroll
        for (int m = 0; m < 2; m++)
            #pragma unroll
            for (int n = 0; n < 4; n++) {
                int hoff = (16 * n + lo16) * HSTR + 32 * w + 16 * m + 4 * hi4;
                float gv[4];
                half4v nh;
                #pragma unroll
                for (int r = 0; r < 4; r++) {
                    float ls, g;
                    act2(acc[m][n][r], ls, g);
                    gv[r] = g;
                    nh[r] = (_Float16)ls;
                }
                g1u[m][n] = packg2(gv[0], gv[1], gv[2], gv[3]);
                *(half4v*)&U[hoff] = nh;
            }
    }
    __syncthreads();

    // ---- F2, F3 (single-term, single-f16 H) ----
    #pragma unroll
    for (int L = 0; L < 2; L++) {
        f32x4 acc[2][4];
        #pragma unroll
        for (int m = 0; m < 2; m++)
            #pragma unroll
            for (int n = 0; n < 4; n++) acc[m][n] = (f32x4)(0.f);
        gemm_fwd1(L ? W3hi : W2hi, U, w, lo16, hi4, acc);
        __syncthreads();   // all reads of H done before update
        #pragma unroll
        for (int m = 0; m < 2; m++)
            #pragma unroll
            for (int n = 0; n < 4; n++) {
                int hoff = (16 * n + lo16) * HSTR + 32 * w + 16 * m + 4 * hi4;
                half4v oh = *(const half4v*)&U[hoff];
                float gv[4];
                half4v nh;
                #pragma unroll
                for (int r = 0; r < 4; r++) {
                    float ls, g;
                    act2(acc[m][n][r], ls, g);
                    gv[r] = g;
                    nh[r] = (_Float16)((float)oh[r] + ls);
                }
                if (L) g3u[m][n] = packg2(gv[0], gv[1], gv[2], gv[3]);
                else   g2u[m][n] = packg2(gv[0], gv[1], gv[2], gv[3]);
                *(half4v*)&U[hoff] = nh;
            }
        __syncthreads();
    }

    // ---- F4 : d = W4[0:16] @ h3 ; 2-term, wave = (e-tile w&3, k-half w>>2) ----
    {
        const int et = w & 3, kh = w >> 2;
        f32x4 acc = (f32x4)(0.f);
        #pragma unroll
        for (int i = 0; i < 4; i++) {
            int ks = 4 * kh + i;
            int boff = (16 * et + lo16) * HSTR + ks * 32 + hi4 * 8;
            half8 bh = *(const half8*)&U[boff];
            int woff = lo16 * NH + ks * 32 + hi4 * 8;
            half8 ah = *(const half8*)&W4hi[woff];
            half8 al = *(const half8*)&W4lo[woff];
            acc = MFMA16(ah, bh, acc);
            acc = MFMA16(al, bh, acc);
        }
        #pragma unroll
        for (int r = 0; r < 4; r++)
            Pb[w * 272 + (hi4 * 4 + r) * 17 + lo16] = acc[r];
    }
    __syncthreads();   // H (union) dead; M may be written

    // ---- backward: 2 passes x 32 elems; col j=16n+lo16 <-> (E=32p+16(n&1)+lo16, c=n>>1) ----
    #pragma unroll
    for (int p = 0; p < 2; p++) {
        const int kbase = 32 * w + 4 * hi4;   // + 16*m below

        // m3 = V .* d3  (own-lane gates; V from f16 LDS table)
        #pragma unroll
        for (int m = 0; m < 2; m++)
            #pragma unroll
            for (int n = 0; n < 8; n++) {
                const int c  = n >> 1;
                const int et = 2 * p + (n & 1);
                const int kb = kbase + 16 * m;
                half4v vh4 = *(const half4v*)&Vbh[c * 264 + kb];
                H4u vv; vv.v4 = vh4;
                half2v g01 = u2h(g3u[m][et].x);
                half2v g23 = u2h(g3u[m][et].y);
                H4u t;
                t.v2[0] = vv.v2[0] * g01;
                t.v2[1] = vv.v2[1] * g23;
                *(half4v*)&U[(16 * n + lo16) * HSTR + kb] = t.v4;
            }
        __syncthreads();

        // B3: G2 = W3^T @ m3
        f32x4 acc2[2][8];
        #pragma unroll
        for (int m = 0; m < 2; m++)
            #pragma unroll
            for (int n = 0; n < 8; n++) acc2[m][n] = (f32x4)(0.f);
        gemm_bwd1(W3Thi, U, w, lo16, hi4, acc2);
        __syncthreads();   // readers of m3 done

        // g2 = V + G2 (f32 skip, exact) ; m2 = f16(g2) .* g2gate (own-lane)
        #pragma unroll
        for (int m = 0; m < 2; m++)
            #pragma unroll
            for (int n = 0; n < 8; n++) {
                const int c  = n >> 1;
                const int et = 2 * p + (n & 1);
                const int kb = kbase + 16 * m;
                f32x4 vf = *(const f32x4*)&Vb[c * 260 + kb];
                half2v g01 = u2h(g2u[m][et].x);
                half2v g23 = u2h(g2u[m][et].y);
                float gg[4];
                #pragma unroll
                for (int r = 0; r < 4; r++) {
                    gg[r] = vf[r] + acc2[m][n][r];
                    acc2[m][n][r] = gg[r];
                }
                H4u t;
                t.v2[0] = pkrtz(gg[0], gg[1]) * g01;
                t.v2[1] = pkrtz(gg[2], gg[3]) * g23;
                *(half4v*)&U[(16 * n + lo16) * HSTR + kb] = t.v4;
            }
        __syncthreads();

        // B2: g1tot = g2 + W2^T @ m2  (accumulate onto acc2)
        gemm_bwd1(W2Thi, U, w, lo16, hi4, acc2);
        __syncthreads();

        // m1 = g1tot .* d1 (own-lane gates)
        #pragma unroll
        for (int m = 0; m < 2; m++)
            #pragma unroll
            for (int n = 0; n < 8; n++) {
                const int et = 2 * p + (n & 1);
                const int kb = kbase + 16 * m;
                half2v g01 = u2h(g1u[m][et].x);
                half2v g23 = u2h(g1u[m][et].y);
                H4u t;
                t.v2[0] = pkrtz(acc2[m][n][0], acc2[m][n][1]) * g01;
                t.v2[1] = pkrtz(acc2[m][n][2], acc2[m][n][3]) * g23;
                *(half4v*)&U[(16 * n + lo16) * HSTR + kb] = t.v4;
            }
        __syncthreads();

        // J = W1^T @ m1 ; all 8 waves, wave w = n-tile w, full K
        {
            f32x4 accj = (f32x4)(0.f);
            #pragma unroll
            for (int ks = 0; ks < 8; ks++) {
                int boff = (16 * w + lo16) * HSTR + ks * 32 + hi4 * 8;
                half8 bh = *(const half8*)&U[boff];
                int woff = lo16 * NH + ks * 32 + hi4 * 8;
                half8 ah = *(const half8*)&W1Thi[woff];
                accj = MFMA16(ah, bh, accj);
            }
            #pragma unroll
            for (int r = 0; r < 4; r++)
                Jfin[(4 * hi4 + r) * 260 + 128 * p + 16 * w + lo16] = accj[r];
        }
        __syncthreads();
    }

    // ---- projection: 2 halves, e = 8w + 4*half + hi4, s = lo16 ----
    // col(e, c) = 128*(e>>5) + 32c + 16*((e>>4)&1) + (e&15)
    #pragma unroll
    for (int half = 0; half < 2; half++) {
        const int e = 8 * w + 4 * half + hi4, s = lo16;
        const int cb = 128 * (e >> 5) + 16 * ((e >> 4) & 1) + (e & 15);
        float acol[4];
        #pragma unroll
        for (int c = 0; c < 4; c++) acol[c] = Jfin[s * 260 + cb + 32 * c];
        const int et = e >> 4, c16 = e & 15;
        float dval = Pb[et * 272 + s * 17 + c16] + Pb[(et + 4) * 272 + s * 17 + c16];
        #pragma unroll
        for (int c = 0; c < 4; c++) {
            float n2 = wsum16(acol[c] * acol[c]);
            float inv = (n2 > 1e-30f) ? (1.0f / sqrtf(n2)) : 0.0f;
            float q = acol[c] * inv;
            #pragma unroll
            for (int cc = c + 1; cc < 4; cc++) {
                float pj = wsum16(acol[cc] * q);
                acol[cc] -= pj * q;
            }
            float pd = wsum16(dval * q);
            dval -= pd * q;
        }
        OUT[(size_t)(ebase + e) * NS + s] = dval;
    }
}

// ---------------- f32 fallback (round-1 kernel) ----------------
__device__ __forceinline__ float dot4f(float4 a, float4 b) {
    return a.x*b.x + a.y*b.y + a.z*b.z + a.w*b.w;
}

__global__ void __launch_bounds__(256, 2)
comet_fused_f32(const float* __restrict__ Z,
                const float* __restrict__ W1,
                const float* __restrict__ W2,
                const float* __restrict__ W3,
                const float* __restrict__ W4,
                float* __restrict__ OUT)
{
    __shared__ __align__(16) float h_lds[4][4][NH];
    __shared__ __align__(16) float m_lds[4][4][NH][NC];

    const int l = threadIdx.x & 63;
    const int w = threadIdx.x >> 6;
    float (*hb)[NH]     = h_lds[w];
    float (*mb)[NH][NC] = m_lds[w];
    const int ebase = (blockIdx.x * 4 + w) * 4;

    float d1g[4][4], d2g[4][4], d3g[4][4];

    {
        float acc[4][4];
        #pragma unroll
        for (int j = 0; j < 4; j++)
            #pragma unroll
            for (int e = 0; e < 4; e++) acc[j][e] = 0.f;
        #pragma unroll
        for (int s4 = 0; s4 < 4; s4++) {
            float4 wf[4];
            #pragma unroll
            for (int j = 0; j < 4; j++)
                wf[j] = *(const float4*)&W1[(l + 64*j) * NS + s4*4];
            #pragma unroll
            for (int e = 0; e < 4; e++) {
                float4 xv = *(const float4*)&Z[(ebase + e) * NS + s4*4];
                #pragma unroll
                for (int j = 0; j < 4; j++) acc[j][e] += dot4f(wf[j], xv);
            }
        }
        #pragma unroll
        for (int j = 0; j < 4; j++)
            #pragma unroll
            for (int e = 0; e < 4; e++) {
                float a = acc[j][e];
                d1g[j][e] = siggf(a);
                hb[e][l + 64*j] = logsigf(a);
            }
    }
    __syncthreads();

#define FWD_LAYER(WPTR, GARR)                                                   \
    {                                                                           \
        float acc[4][4];                                                        \
        _Pragma("unroll")                                                       \
        for (int j = 0; j < 4; j++) {                                           \
            _Pragma("unroll")                                                   \
            for (int e = 0; e < 4; e++) acc[j][e] = 0.f;                        \
        }                                                                       \
        _Pragma("unroll 2")                                                     \
        for (int kk = 0; kk < NH; kk += 4) {                                    \
            float wv[4][4];                                                     \
            _Pragma("unroll")                                                   \
            for (int j = 0; j < 4; j++) {                                       \
                float4 t = *(const float4*)&WPTR[(l + 64*j) * NH + kk];         \
                wv[0][j] = t.x; wv[1][j] = t.y; wv[2][j] = t.z; wv[3][j] = t.w; \
            }                                                                   \
            _Pragma("unroll")                                                   \
            for (int e = 0; e < 4; e++) {                                       \
                float4 hv = *(const float4*)&hb[e][kk];                         \
                _Pragma("unroll")                                               \
                for (int j = 0; j < 4; j++)                                     \
                    acc[j][e] += wv[0][j]*hv.x + wv[1][j]*hv.y                  \
                               + wv[2][j]*hv.z + wv[3][j]*hv.w;                 \
            }                                                                   \
        }                                                                       \
        __syncthreads();                                                        \
        _Pragma("unroll")                                                       \
        for (int j = 0; j < 4; j++) {                                           \
            _Pragma("unroll")                                                   \
            for (int e = 0; e < 4; e++) {                                       \
                float a = acc[j][e];                                            \
                GARR[j][e] = siggf(a);                                          \
                hb[e][l + 64*j] += logsigf(a);                                  \
            }                                                                   \
        }                                                                       \
        __syncthreads();                                                        \
    }

    FWD_LAYER(W2, d2g)
    FWD_LAYER(W3, d3g)
#undef FWD_LAYER

    const int e4 = l >> 4, s4 = l & 15;
    float dval = 0.f;
    {
        #pragma unroll 2
        for (int kk = 0; kk < NH; kk += 4) {
            float4 wf = *(const float4*)&W4[s4 * NH + kk];
            float4 hv = *(const float4*)&hb[e4][kk];
            dval += dot4f(wf, hv);
        }
    }

    float gacc[4][4][4];
    float vf[4][4];
    #pragma unroll
    for (int c = 0; c < 4; c++)
        #pragma unroll
        for (int j = 0; j < 4; j++)
            vf[c][j] = W4[(NS + c) * NH + l + 64*j];
    #pragma unroll
    for (int e = 0; e < 4; e++)
        #pragma unroll
        for (int c = 0; c < 4; c++)
            #pragma unroll
            for (int j = 0; j < 4; j++)
                gacc[e][c][j] = vf[c][j];
    #pragma unroll
    for (int j = 0; j < 4; j++)
        #pragma unroll
        for (int e = 0; e < 4; e++) {
            float g = d3g[j][e];
            float4 mv = make_float4(vf[0][j]*g, vf[1][j]*g, vf[2][j]*g, vf[3][j]*g);
            *(float4*)&mb[e][l + 64*j][0] = mv;
        }
    __syncthreads();

#define BWD_GEMM(WPTR)                                                          \
    {                                                                           \
        _Pragma("unroll 2")                                                     \
        for (int r = 0; r < NH; r++) {                                          \
            float wc[4];                                                        \
            _Pragma("unroll")                                                   \
            for (int j = 0; j < 4; j++) wc[j] = WPTR[r * NH + l + 64*j];        \
            _Pragma("unroll")                                                   \
            for (int e = 0; e < 4; e++) {                                       \
                float4 mv = *(const float4*)&mb[e][r][0];                       \
                _Pragma("unroll")                                               \
                for (int j = 0; j < 4; j++) {                                   \
                    gacc[e][0][j] += wc[j]*mv.x;                                \
                    gacc[e][1][j] += wc[j]*mv.y;                                \
                    gacc[e][2][j] += wc[j]*mv.z;                                \
                    gacc[e][3][j] += wc[j]*mv.w;                                \
                }                                                               \
            }                                                                   \
        }                                                                       \
    }

    BWD_GEMM(W3)
    __syncthreads();
    #pragma unroll
    for (int j = 0; j < 4; j++)
        #pragma unroll
        for (int e = 0; e < 4; e++) {
            float g = d2g[j][e];
            float4 mv = make_float4(gacc[e][0][j]*g, gacc[e][1][j]*g,
                                    gacc[e][2][j]*g, gacc[e][3][j]*g);
            *(float4*)&mb[e][l + 64*j][0] = mv;
        }
    __syncthreads();
    BWD_GEMM(W2)
#undef BWD_GEMM
    __syncthreads();
    #pragma unroll
    for (int j = 0; j < 4; j++)
        #pragma unroll
        for (int e = 0; e < 4; e++) {
            float g = d1g[j][e];
            float4 mv = make_float4(gacc[e][0][j]*g, gacc[e][1][j]*g,
                                    gacc[e][2][j]*g, gacc[e][3][j]*g);
            *(float4*)&mb[e][l + 64*j][0] = mv;
        }
    __syncthreads();

    const int c4 = l >> 4;
    float jv[4] = {0.f, 0.f, 0.f, 0.f};
    #pragma unroll 4
    for (int r = 0; r < NH; r++) {
        float w1v = W1[r * NS + s4];
        #pragma unroll
        for (int e = 0; e < 4; e++) jv[e] += mb[e][r][c4] * w1v;
    }
    __syncthreads();

    float* jlds = (float*)hb;
    #pragma unroll
    for (int e = 0; e < 4; e++) jlds[e * 64 + c4 * 16 + s4] = jv[e];
    __syncthreads();

    float acol[4];
    acol[0] = jlds[e4 * 64 +      s4];
    acol[1] = jlds[e4 * 64 + 16 + s4];
    acol[2] = jlds[e4 * 64 + 32 + s4];
    acol[3] = jlds[e4 * 64 + 48 + s4];
    #pragma unroll
    for (int c = 0; c < 4; c++) {
        float n2 = wsum16(acol[c] * acol[c]);
        float inv = (n2 > 1e-30f) ? (1.0f / sqrtf(n2)) : 0.0f;
        float q = acol[c] * inv;
        #pragma unroll
        for (int cc = c + 1; cc < 4; cc++) {
            float p = wsum16(acol[cc] * q);
            acol[cc] -= p * q;
        }
        float pd = wsum16(dval * q);
        dval -= pd * q;
    }
    OUT[ebase * NS + l] = dval;
}

extern "C" void kernel_launch(void* const* d_in, const int* in_sizes, int n_in,
                              void* d_out, int out_size, void* d_ws, size_t ws_size,
                              hipStream_t stream) {
    const float* Z  = (const float*)d_in[0];
    const float* W1 = (const float*)d_in[1];
    const float* W2 = (const float*)d_in[2];
    const float* W3 = (const float*)d_in[3];
    const float* W4 = (const float*)d_in[4];
    float* OUT = (float*)d_out;

    const size_t need = (size_t)WS_HALVES * sizeof(_Float16);

    if (ws_size >= need) {
        _Float16* ws = (_Float16*)d_ws;
        hipLaunchKernelGGL(prep_big, dim3(NH, 2), dim3(NH), 0, stream, W2, W3, ws);
        hipLaunchKernelGGL(prep_small, dim3(1), dim3(NH), 0, stream, W1, W4, ws);
        hipLaunchKernelGGL(comet_mfma, dim3(BATCH / EPB), dim3(512), 0, stream,
                           Z, W4, ws, OUT);
    } else {
        hipLaunchKernelGGL(comet_fused_f32, dim3(BATCH / 16), dim3(256), 0, stream,
                           Z, W1, W2, W3, W4, OUT);
    }
}

// Round 15
// 734.933 us; speedup vs baseline: 3.3452x; 1.0071x over previous
//
#include <hip/hip_runtime.h>
#include <math.h>

#define NS 16
#define NC 4
#define NH 256
#define BATCH 262144
#define EPB 64      // elements per block
#define HSTR 264    // halves; 528 B rows = 16B-aligned (b128 requirement), 4-word bank rotation

typedef _Float16 half8 __attribute__((ext_vector_type(8)));
typedef _Float16 half4v __attribute__((ext_vector_type(4)));
typedef _Float16 half2v __attribute__((ext_vector_type(2)));
typedef float f32x4 __attribute__((ext_vector_type(4)));

#define MFMA16(a, b, c) __builtin_amdgcn_mfma_f32_16x16x32_f16((a), (b), (c), 0, 0, 0)

// ---------- ws layout (in halves) ----------
#define OFF_W2HI   0
#define OFF_W2LO   65536
#define OFF_W3HI   131072
#define OFF_W3LO   196608
#define OFF_W2THI  262144
#define OFF_W2TLO  327680
#define OFF_W3THI  393216
#define OFF_W3TLO  458752
#define OFF_W1PHI  524288
#define OFF_W1PLO  532480
#define OFF_W1THI  540672
#define OFF_W1TLO  544768
#define OFF_W4HI   548864
#define OFF_W4LO   552960
#define WS_HALVES  557056   // * 2 bytes = 1,114,112

__device__ __forceinline__ float logsigf(float a) {
    return fminf(a, 0.f) - __logf(1.f + __expf(-fabsf(a)));
}
__device__ __forceinline__ float siggf(float a) {   // sigma(-a)
    return 1.f / (1.f + __expf(a));
}
// shared-exp: both logsig(a) and sigma(-a) from one exp
__device__ __forceinline__ void act2(float a, float& ls, float& g) {
    float e  = __expf(-fabsf(a));
    float om = 1.f + e;
    float r  = __builtin_amdgcn_rcpf(om);
    ls = fminf(a, 0.f) - __logf(om);
    g  = (a >= 0.f) ? e * r : r;
}
__device__ __forceinline__ void split2(float x, _Float16& h, _Float16& l) {
    h = (_Float16)x;
    l = (_Float16)(x - (float)h);
}
__device__ __forceinline__ float wsum16(float v) {
    v += __shfl_xor(v, 1, 64);
    v += __shfl_xor(v, 2, 64);
    v += __shfl_xor(v, 4, 64);
    v += __shfl_xor(v, 8, 64);
    return v;
}
__device__ __forceinline__ unsigned h2u(half2v h) {
    union { half2v h; unsigned u; } c; c.h = h; return c.u;
}
__device__ __forceinline__ half2v u2h(unsigned u) {
    union { half2v h; unsigned u; } c; c.u = u; return c.h;
}
__device__ __forceinline__ half2v pkrtz(float a, float b) {
    // builtin returns __fp16x2; bit-cast to _Float16x2
    auto t = __builtin_amdgcn_cvt_pkrtz(a, b);
    union { decltype(t) s; half2v d; } c; c.s = t; return c.d;
}
__device__ __forceinline__ uint2 packg2(float g0, float g1, float g2, float g3) {
    return make_uint2(h2u(pkrtz(g0, g1)), h2u(pkrtz(g2, g3)));
}
union H4u { half4v v4; half2v v2[2]; };

// ---------------- prep kernels ----------------
extern "C" __global__ void __launch_bounds__(256)
prep_big(const float* __restrict__ W2, const float* __restrict__ W3,
         _Float16* __restrict__ ws) {
    const int mat = blockIdx.y;
    const float* W = mat ? W3 : W2;
    _Float16* Whi  = ws + (mat ? OFF_W3HI  : OFF_W2HI);
    _Float16* Wlo  = Whi + 65536;
    _Float16* WThi = ws + (mat ? OFF_W3THI : OFF_W2THI);
    _Float16* WTlo = WThi + 65536;
    const int r = blockIdx.x, c = threadIdx.x;
    float x = W[r * NH + c];
    _Float16 h, l; split2(x, h, l);
    Whi[r * NH + c] = h;  Wlo[r * NH + c] = l;
    WThi[c * NH + r] = h; WTlo[c * NH + r] = l;
}

extern "C" __global__ void __launch_bounds__(256)
prep_small(const float* __restrict__ W1, const float* __restrict__ W4,
           _Float16* __restrict__ ws) {
    _Float16* W1phi = ws + OFF_W1PHI;
    _Float16* W1plo = ws + OFF_W1PLO;
    _Float16* W1Thi = ws + OFF_W1THI;
    _Float16* W1Tlo = ws + OFF_W1TLO;
    _Float16* W4hi  = ws + OFF_W4HI;
    _Float16* W4lo  = ws + OFF_W4LO;
    const int t = threadIdx.x;   // 0..255 (= W1 row)
    #pragma unroll
    for (int s = 0; s < NS; s++) {
        float x = W1[t * NS + s];
        _Float16 h, l; split2(x, h, l);
        W1phi[t * 32 + s] = h;        W1plo[t * 32 + s] = l;
        W1phi[t * 32 + 16 + s] = (_Float16)0.f;
        W1plo[t * 32 + 16 + s] = (_Float16)0.f;
        W1Thi[s * NH + t] = h;        W1Tlo[s * NH + t] = l;
    }
    #pragma unroll
    for (int q = 0; q < 16; q++) {
        int idx = q * 256 + t;       // covers rows 0..15 of W4
        float x = W4[idx];
        _Float16 h, l; split2(x, h, l);
        W4hi[idx] = h; W4lo[idx] = l;
    }
}

// ---------------- main fused MFMA kernel ----------------
// E=64/block, 512 threads = 8 waves. Wave w owns hidden rows 32w..32w+31
// (2 m-tiles). Forward N=64 (4 e-tiles): F1 3-term; F2/F3 single-term;
// H single f16, running value kept in REGISTERS (h_reg[2][4], f16x4) —
// the (m,n,r)->(e,k) mapping is identical every layer, so no LDS RMW.
// H ping-pong: F1 writes region A (U rows 0..63); F2 reads A, writes B
// (rows 64..127); F3 reads B, writes A; F4 reads A. ONE barrier per
// layer (no WAR barrier). 16 barriers total (was 18).
// Backward: 2 passes x 32 elems (128 cols, 8 n-tiles), single-term,
// shuffle-free gate mapping: col j=16n+lo16 <-> (E=32p+16(n&1)+lo16,
// c=n>>1); gates own-lane; V from LDS tables. LDS = 99,328 B.

__device__ __forceinline__ void gemm_fwd1(const _Float16* __restrict__ Ahi,
                                          const _Float16* U, int ubase,
                                          int w, int lo16, int hi4, f32x4 acc[2][4]) {
    #pragma unroll
    for (int ks = 0; ks < 8; ks++) {
        half8 bh[4];
        #pragma unroll
        for (int n = 0; n < 4; n++)
            bh[n] = *(const half8*)&U[(ubase + 16 * n + lo16) * HSTR + ks * 32 + hi4 * 8];
        #pragma unroll
        for (int m = 0; m < 2; m++) {
            int woff = (32 * w + 16 * m + lo16) * NH + ks * 32 + hi4 * 8;
            half8 ah = *(const half8*)&Ahi[woff];
            #pragma unroll
            for (int n = 0; n < 4; n++)
                acc[m][n] = MFMA16(ah, bh[n], acc[m][n]);
        }
    }
}

// single-term backward GEMM over 8 n-tiles (128 cols)
__device__ __forceinline__ void gemm_bwd1(const _Float16* __restrict__ Ahi,
                                          const _Float16* U,
                                          int w, int lo16, int hi4, f32x4 acc[2][8]) {
    #pragma unroll
    for (int ks = 0; ks < 8; ks++) {
        half8 bh[8];
        #pragma unroll
        for (int n = 0; n < 8; n++)
            bh[n] = *(const half8*)&U[(16 * n + lo16) * HSTR + ks * 32 + hi4 * 8];
        #pragma unroll
        for (int m = 0; m < 2; m++) {
            int woff = (32 * w + 16 * m + lo16) * NH + ks * 32 + hi4 * 8;
            half8 ah = *(const half8*)&Ahi[woff];
            #pragma unroll
            for (int n = 0; n < 8; n++)
                acc[m][n] = MFMA16(ah, bh[n], acc[m][n]);
        }
    }
}

__global__ void __launch_bounds__(512, 1)
comet_mfma(const float* __restrict__ Z,
           const float* __restrict__ W4,
           const _Float16* __restrict__ ws,
           float* __restrict__ OUT)
{
    const _Float16* W2hi  = ws + OFF_W2HI;
    const _Float16* W3hi  = ws + OFF_W3HI;
    const _Float16* W2Thi = ws + OFF_W2THI;
    const _Float16* W3Thi = ws + OFF_W3THI;
    const _Float16* W1phi = ws + OFF_W1PHI;
    const _Float16* W1plo = ws + OFF_W1PLO;
    const _Float16* W1Thi = ws + OFF_W1THI;
    const _Float16* W4hi  = ws + OFF_W4HI;
    const _Float16* W4lo  = ws + OFF_W4LO;

    __shared__ __align__(16) _Float16 U[128 * HSTR];   // 67,584 B
    __shared__ __align__(16) float Jfin[16 * 260];     // 16,640 B
    __shared__ __align__(16) float Pb[8 * 272];        //  8,704 B
    __shared__ __align__(16) float Vb[4 * 260];        //  4,160 B  (f32, skip-add)
    __shared__ __align__(16) _Float16 Vbh[4 * 264];    //  2,112 B  (f16, pk_mul)

    const int tid  = threadIdx.x;
    const int l    = tid & 63, w = tid >> 6;
    const int lo16 = l & 15, hi4 = l >> 4;
    const int ebase = blockIdx.x * EPB;

    // ---- stage V (rows 16..19 of W4) into LDS tables ----
    #pragma unroll
    for (int i = 0; i < 2; i++) {
        int idx = i * 512 + tid;
        int c = idx >> 8, k = idx & 255;
        float x = W4[(NS + c) * NH + k];
        Vb[c * 260 + k] = x;
        Vbh[c * 264 + k] = (_Float16)x;
    }

    uint2 g1u[2][4], g2u[2][4], g3u[2][4];   // [m][e-tile] packed f16 gates
    half4v h_reg[2][4];                      // running h value (f16), own (m,n,r)

    // ---- F1 : a1 = W1p @ Zpad (3-term) ; writes H region A + h_reg ----
    {
        f32x4 acc[2][4];
        #pragma unroll
        for (int m = 0; m < 2; m++)
            #pragma unroll
            for (int n = 0; n < 4; n++) acc[m][n] = (f32x4)(0.f);
        half8 bh[4], bl[4];
        #pragma unroll
        for (int n = 0; n < 4; n++) {
            if (hi4 < 2) {
                const float* zp = &Z[(size_t)(ebase + 16 * n + lo16) * NS + hi4 * 8];
                float4 z0 = *(const float4*)zp;
                float4 z1 = *(const float4*)(zp + 4);
                float zz[8] = {z0.x, z0.y, z0.z, z0.w, z1.x, z1.y, z1.z, z1.w};
                #pragma unroll
                for (int r = 0; r < 8; r++) {
                    _Float16 h, lo; split2(zz[r], h, lo);
                    bh[n][r] = h; bl[n][r] = lo;
                }
            } else {
                #pragma unroll
                for (int r = 0; r < 8; r++) { bh[n][r] = (_Float16)0.f; bl[n][r] = (_Float16)0.f; }
            }
        }
        #pragma unroll
        for (int m = 0; m < 2; m++) {
            int woff = (32 * w + 16 * m + lo16) * 32 + hi4 * 8;
            half8 ah = *(const half8*)&W1phi[woff];
            half8 al = *(const half8*)&W1plo[woff];
            #pragma unroll
            for (int n = 0; n < 4; n++) {
                acc[m][n] = MFMA16(ah, bh[n], acc[m][n]);
                acc[m][n] = MFMA16(al, bh[n], acc[m][n]);
                acc[m][n] = MFMA16(ah, bl[n], acc[m][n]);
            }
        }
        #pragma unroll
        for (int m = 0; m < 2; m++)
            #pragma unroll
            for (int n = 0; n < 4; n++) {
                int hoff = (16 * n + lo16) * HSTR + 32 * w + 16 * m + 4 * hi4;
                float gv[4];
                half4v nh;
                #pragma unroll
                for (int r = 0; r < 4; r++) {
                    float ls, g;
                    act2(acc[m][n][r], ls, g);
                    gv[r] = g;
                    nh[r] = (_Float16)ls;
                }
                g1u[m][n] = packg2(gv[0], gv[1], gv[2], gv[3]);
                h_reg[m][n] = nh;
                *(half4v*)&U[hoff] = nh;
            }
    }
    __syncthreads();

    // ---- F2 : reads region A, writes region B (h_reg update, no LDS RMW) ----
    {
        f32x4 acc[2][4];
        #pragma unroll
        for (int m = 0; m < 2; m++)
            #pragma unroll
            for (int n = 0; n < 4; n++) acc[m][n] = (f32x4)(0.f);
        gemm_fwd1(W2hi, U, 0, w, lo16, hi4, acc);
        #pragma unroll
        for (int m = 0; m < 2; m++)
            #pragma unroll
            for (int n = 0; n < 4; n++) {
                int hoff = (64 + 16 * n + lo16) * HSTR + 32 * w + 16 * m + 4 * hi4;
                float gv[4];
                half4v nh;
                #pragma unroll
                for (int r = 0; r < 4; r++) {
                    float ls, g;
                    act2(acc[m][n][r], ls, g);
                    gv[r] = g;
                    nh[r] = (_Float16)((float)h_reg[m][n][r] + ls);
                }
                g2u[m][n] = packg2(gv[0], gv[1], gv[2], gv[3]);
                h_reg[m][n] = nh;
                *(half4v*)&U[hoff] = nh;
            }
    }
    __syncthreads();

    // ---- F3 : reads region B, writes region A ----
    {
        f32x4 acc[2][4];
        #pragma unroll
        for (int m = 0; m < 2; m++)
            #pragma unroll
            for (int n = 0; n < 4; n++) acc[m][n] = (f32x4)(0.f);
        gemm_fwd1(W3hi, U, 64, w, lo16, hi4, acc);
        #pragma unroll
        for (int m = 0; m < 2; m++)
            #pragma unroll
            for (int n = 0; n < 4; n++) {
                int hoff = (16 * n + lo16) * HSTR + 32 * w + 16 * m + 4 * hi4;
                float gv[4];
                half4v nh;
                #pragma unroll
                for (int r = 0; r < 4; r++) {
                    float ls, g;
                    act2(acc[m][n][r], ls, g);
                    gv[r] = g;
                    nh[r] = (_Float16)((float)h_reg[m][n][r] + ls);
                }
                g3u[m][n] = packg2(gv[0], gv[1], gv[2], gv[3]);
                *(half4v*)&U[hoff] = nh;
            }
    }
    __syncthreads();

    // ---- F4 : d = W4[0:16] @ h3 (region A) ; 2-term, wave=(e-tile w&3, k-half w>>2) ----
    {
        const int et = w & 3, kh = w >> 2;
        f32x4 acc = (f32x4)(0.f);
        #pragma unroll
        for (int i = 0; i < 4; i++) {
            int ks = 4 * kh + i;
            int boff = (16 * et + lo16) * HSTR + ks * 32 + hi4 * 8;
            half8 bh = *(const half8*)&U[boff];
            int woff = lo16 * NH + ks * 32 + hi4 * 8;
            half8 ah = *(const half8*)&W4hi[woff];
            half8 al = *(const half8*)&W4lo[woff];
            acc = MFMA16(ah, bh, acc);
            acc = MFMA16(al, bh, acc);
        }
        #pragma unroll
        for (int r = 0; r < 4; r++)
            Pb[w * 272 + (hi4 * 4 + r) * 17 + lo16] = acc[r];
    }
    __syncthreads();   // H dead; M may be written

    // ---- backward: 2 passes x 32 elems; col j=16n+lo16 <-> (E=32p+16(n&1)+lo16, c=n>>1) ----
    #pragma unroll
    for (int p = 0; p < 2; p++) {
        const int kbase = 32 * w + 4 * hi4;   // + 16*m below

        // m3 = V .* d3  (own-lane gates; V from f16 LDS table)
        #pragma unroll
        for (int m = 0; m < 2; m++)
            #pragma unroll
            for (int n = 0; n < 8; n++) {
                const int c  = n >> 1;
                const int et = 2 * p + (n & 1);
                const int kb = kbase + 16 * m;
                half4v vh4 = *(const half4v*)&Vbh[c * 264 + kb];
                H4u vv; vv.v4 = vh4;
                half2v g01 = u2h(g3u[m][et].x);
                half2v g23 = u2h(g3u[m][et].y);
                H4u t;
                t.v2[0] = vv.v2[0] * g01;
                t.v2[1] = vv.v2[1] * g23;
                *(half4v*)&U[(16 * n + lo16) * HSTR + kb] = t.v4;
            }
        __syncthreads();

        // B3: G2 = W3^T @ m3
        f32x4 acc2[2][8];
        #pragma unroll
        for (int m = 0; m < 2; m++)
            #pragma unroll
            for (int n = 0; n < 8; n++) acc2[m][n] = (f32x4)(0.f);
        gemm_bwd1(W3Thi, U, w, lo16, hi4, acc2);
        __syncthreads();   // readers of m3 done

        // g2 = V + G2 (f32 skip, exact) ; m2 = f16(g2) .* g2gate (own-lane)
        #pragma unroll
        for (int m = 0; m < 2; m++)
            #pragma unroll
            for (int n = 0; n < 8; n++) {
                const int c  = n >> 1;
                const int et = 2 * p + (n & 1);
                const int kb = kbase + 16 * m;
                f32x4 vf = *(const f32x4*)&Vb[c * 260 + kb];
                half2v g01 = u2h(g2u[m][et].x);
                half2v g23 = u2h(g2u[m][et].y);
                float gg[4];
                #pragma unroll
                for (int r = 0; r < 4; r++) {
                    gg[r] = vf[r] + acc2[m][n][r];
                    acc2[m][n][r] = gg[r];
                }
                H4u t;
                t.v2[0] = pkrtz(gg[0], gg[1]) * g01;
                t.v2[1] = pkrtz(gg[2], gg[3]) * g23;
                *(half4v*)&U[(16 * n + lo16) * HSTR + kb] = t.v4;
            }
        __syncthreads();

        // B2: g1tot = g2 + W2^T @ m2  (accumulate onto acc2)
        gemm_bwd1(W2Thi, U, w, lo16, hi4, acc2);
        __syncthreads();

        // m1 = g1tot .* d1 (own-lane gates)
        #pragma unroll
        for (int m = 0; m < 2; m++)
            #pragma unroll
            for (int n = 0; n < 8; n++) {
                const int et = 2 * p + (n & 1);
                const int kb = kbase + 16 * m;
                half2v g01 = u2h(g1u[m][et].x);
                half2v g23 = u2h(g1u[m][et].y);
                H4u t;
                t.v2[0] = pkrtz(acc2[m][n][0], acc2[m][n][1]) * g01;
                t.v2[1] = pkrtz(acc2[m][n][2], acc2[m][n][3]) * g23;
                *(half4v*)&U[(16 * n + lo16) * HSTR + kb] = t.v4;
            }
        __syncthreads();

        // J = W1^T @ m1 ; all 8 waves, wave w = n-tile w, full K
        {
            f32x4 accj = (f32x4)(0.f);
            #pragma unroll
            for (int ks = 0; ks < 8; ks++) {
                int boff = (16 * w + lo16) * HSTR + ks * 32 + hi4 * 8;
                half8 bh = *(const half8*)&U[boff];
                int woff = lo16 * NH + ks * 32 + hi4 * 8;
                half8 ah = *(const half8*)&W1Thi[woff];
                accj = MFMA16(ah, bh, accj);
            }
            #pragma unroll
            for (int r = 0; r < 4; r++)
                Jfin[(4 * hi4 + r) * 260 + 128 * p + 16 * w + lo16] = accj[r];
        }
        __syncthreads();
    }

    // ---- projection: 2 halves, e = 8w + 4*half + hi4, s = lo16 ----
    // col(e, c) = 128*(e>>5) + 32c + 16*((e>>4)&1) + (e&15)
    #pragma unroll
    for (int half = 0; half < 2; half++) {
        const int e = 8 * w + 4 * half + hi4, s = lo16;
        const int cb = 128 * (e >> 5) + 16 * ((e >> 4) & 1) + (e & 15);
        float acol[4];
        #pragma unroll
        for (int c = 0; c < 4; c++) acol[c] = Jfin[s * 260 + cb + 32 * c];
        const int et = e >> 4, c16 = e & 15;
        float dval = Pb[et * 272 + s * 17 + c16] + Pb[(et + 4) * 272 + s * 17 + c16];
        #pragma unroll
        for (int c = 0; c < 4; c++) {
            float n2 = wsum16(acol[c] * acol[c]);
            float inv = (n2 > 1e-30f) ? (1.0f / sqrtf(n2)) : 0.0f;
            float q = acol[c] * inv;
            #pragma unroll
            for (int cc = c + 1; cc < 4; cc++) {
                float pj = wsum16(acol[cc] * q);
                acol[cc] -= pj * q;
            }
            float pd = wsum16(dval * q);
            dval -= pd * q;
        }
        OUT[(size_t)(ebase + e) * NS + s] = dval;
    }
}

// ---------------- f32 fallback (round-1 kernel) ----------------
__device__ __forceinline__ float dot4f(float4 a, float4 b) {
    return a.x*b.x + a.y*b.y + a.z*b.z + a.w*b.w;
}

__global__ void __launch_bounds__(256, 2)
comet_fused_f32(const float* __restrict__ Z,
                const float* __restrict__ W1,
                const float* __restrict__ W2,
                const float* __restrict__ W3,
                const float* __restrict__ W4,
                float* __restrict__ OUT)
{
    __shared__ __align__(16) float h_lds[4][4][NH];
    __shared__ __align__(16) float m_lds[4][4][NH][NC];

    const int l = threadIdx.x & 63;
    const int w = threadIdx.x >> 6;
    float (*hb)[NH]     = h_lds[w];
    float (*mb)[NH][NC] = m_lds[w];
    const int ebase = (blockIdx.x * 4 + w) * 4;

    float d1g[4][4], d2g[4][4], d3g[4][4];

    {
        float acc[4][4];
        #pragma unroll
        for (int j = 0; j < 4; j++)
            #pragma unroll
            for (int e = 0; e < 4; e++) acc[j][e] = 0.f;
        #pragma unroll
        for (int s4 = 0; s4 < 4; s4++) {
            float4 wf[4];
            #pragma unroll
            for (int j = 0; j < 4; j++)
                wf[j] = *(const float4*)&W1[(l + 64*j) * NS + s4*4];
            #pragma unroll
            for (int e = 0; e < 4; e++) {
                float4 xv = *(const float4*)&Z[(ebase + e) * NS + s4*4];
                #pragma unroll
                for (int j = 0; j < 4; j++) acc[j][e] += dot4f(wf[j], xv);
            }
        }
        #pragma unroll
        for (int j = 0; j < 4; j++)
            #pragma unroll
            for (int e = 0; e < 4; e++) {
                float a = acc[j][e];
                d1g[j][e] = siggf(a);
                hb[e][l + 64*j] = logsigf(a);
            }
    }
    __syncthreads();

#define FWD_LAYER(WPTR, GARR)                                                   \
    {                                                                           \
        float acc[4][4];                                                        \
        _Pragma("unroll")                                                       \
        for (int j = 0; j < 4; j++) {                                           \
            _Pragma("unroll")                                                   \
            for (int e = 0; e < 4; e++) acc[j][e] = 0.f;                        \
        }                                                                       \
        _Pragma("unroll 2")                                                     \
        for (int kk = 0; kk < NH; kk += 4) {                                    \
            float wv[4][4];                                                     \
            _Pragma("unroll")                                                   \
            for (int j = 0; j < 4; j++) {                                       \
                float4 t = *(const float4*)&WPTR[(l + 64*j) * NH + kk];         \
                wv[0][j] = t.x; wv[1][j] = t.y; wv[2][j] = t.z; wv[3][j] = t.w; \
            }                                                                   \
            _Pragma("unroll")                                                   \
            for (int e = 0; e < 4; e++) {                                       \
                float4 hv = *(const float4*)&hb[e][kk];                         \
                _Pragma("unroll")                                               \
                for (int j = 0; j < 4; j++)                                     \
                    acc[j][e] += wv[0][j]*hv.x + wv[1][j]*hv.y                  \
                               + wv[2][j]*hv.z + wv[3][j]*hv.w;                 \
            }                                                                   \
        }                                                                       \
        __syncthreads();                                                        \
        _Pragma("unroll")                                                       \
        for (int j = 0; j < 4; j++) {                                           \
            _Pragma("unroll")                                                   \
            for (int e = 0; e < 4; e++) {                                       \
                float a = acc[j][e];                                            \
                GARR[j][e] = siggf(a);                                          \
                hb[e][l + 64*j] += logsigf(a);                                  \
            }                                                                   \
        }                                                                       \
        __syncthreads();                                                        \
    }

    FWD_LAYER(W2, d2g)
    FWD_LAYER(W3, d3g)
#undef FWD_LAYER

    const int e4 = l >> 4, s4 = l & 15;
    float dval = 0.f;
    {
        #pragma unroll 2
        for (int kk = 0; kk < NH; kk += 4) {
            float4 wf = *(const float4*)&W4[s4 * NH + kk];
            float4 hv = *(const float4*)&hb[e4][kk];
            dval += dot4f(wf, hv);
        }
    }

    float gacc[4][4][4];
    float vf[4][4];
    #pragma unroll
    for (int c = 0; c < 4; c++)
        #pragma unroll
        for (int j = 0; j < 4; j++)
            vf[c][j] = W4[(NS + c) * NH + l + 64*j];
    #pragma unroll
    for (int e = 0; e < 4; e++)
        #pragma unroll
        for (int c = 0; c < 4; c++)
            #pragma unroll
            for (int j = 0; j < 4; j++)
                gacc[e][c][j] = vf[c][j];
    #pragma unroll
    for (int j = 0; j < 4; j++)
        #pragma unroll
        for (int e = 0; e < 4; e++) {
            float g = d3g[j][e];
            float4 mv = make_float4(vf[0][j]*g, vf[1][j]*g, vf[2][j]*g, vf[3][j]*g);
            *(float4*)&mb[e][l + 64*j][0] = mv;
        }
    __syncthreads();

#define BWD_GEMM(WPTR)                                                          \
    {                                                                           \
        _Pragma("unroll 2")                                                     \
        for (int r = 0; r < NH; r++) {                                          \
            float wc[4];                                                        \
            _Pragma("unroll")                                                   \
            for (int j = 0; j < 4; j++) wc[j] = WPTR[r * NH + l + 64*j];        \
            _Pragma("unroll")                                                   \
            for (int e = 0; e < 4; e++) {                                       \
                float4 mv = *(const float4*)&mb[e][r][0];                       \
                _Pragma("unroll")                                               \
                for (int j = 0; j < 4; j++) {                                   \
                    gacc[e][0][j] += wc[j]*mv.x;                                \
                    gacc[e][1][j] += wc[j]*mv.y;                                \
                    gacc[e][2][j] += wc[j]*mv.z;                                \
                    gacc[e][3][j] += wc[j]*mv.w;                                \
                }                                                               \
            }                                                                   \
        }                                                                       \
    }

    BWD_GEMM(W3)
    __syncthreads();
    #pragma unroll
    for (int j = 0; j < 4; j++)
        #pragma unroll
        for (int e = 0; e < 4; e++) {
            float g = d2g[j][e];
            float4 mv = make_float4(gacc[e][0][j]*g, gacc[e][1][j]*g,
                                    gacc[e][2][j]*g, gacc[e][3][j]*g);
            *(float4*)&mb[e][l + 64*j][0] = mv;
        }
    __syncthreads();
    BWD_GEMM(W2)
#undef BWD_GEMM
    __syncthreads();
    #pragma unroll
    for (int j = 0; j < 4; j++)
        #pragma unroll
        for (int e = 0; e < 4; e++) {
            float g = d1g[j][e];
            float4 mv = make_float4(gacc[e][0][j]*g, gacc[e][1][j]*g,
                                    gacc[e][2][j]*g, gacc[e][3][j]*g);
            *(float4*)&mb[e][l + 64*j][0] = mv;
        }
    __syncthreads();

    const int c4 = l >> 4;
    float jv[4] = {0.f, 0.f, 0.f, 0.f};
    #pragma unroll 4
    for (int r = 0; r < NH; r++) {
        float w1v = W1[r * NS + s4];
        #pragma unroll
        for (int e = 0; e < 4; e++) jv[e] += mb[e][r][c4] * w1v;
    }
    __syncthreads();

    float* jlds = (float*)hb;
    #pragma unroll
    for (int e = 0; e < 4; e++) jlds[e * 64 + c4 * 16 + s4] = jv[e];
    __syncthreads();

    float acol[4];
    acol[0] = jlds[e4 * 64 +      s4];
    acol[1] = jlds[e4 * 64 + 16 + s4];
    acol[2] = jlds[e4 * 64 + 32 + s4];
    acol[3] = jlds[e4 * 64 + 48 + s4];
    #pragma unroll
    for (int c = 0; c < 4; c++) {
        float n2 = wsum16(acol[c] * acol[c]);
        float inv = (n2 > 1e-30f) ? (1.0f / sqrtf(n2)) : 0.0f;
        float q = acol[c] * inv;
        #pragma unroll
        for (int cc = c + 1; cc < 4; cc++) {
            float p = wsum16(acol[cc] * q);
            acol[cc] -= p * q;
        }
        float pd = wsum16(dval * q);
        dval -= pd * q;
    }
    OUT[ebase * NS + l] = dval;
}

extern "C" void kernel_launch(void* const* d_in, const int* in_sizes, int n_in,
                              void* d_out, int out_size, void* d_ws, size_t ws_size,
                              hipStream_t stream) {
    const float* Z  = (const float*)d_in[0];
    const float* W1 = (const float*)d_in[1];
    const float* W2 = (const float*)d_in[2];
    const float* W3 = (const float*)d_in[3];
    const float* W4 = (const float*)d_in[4];
    float* OUT = (float*)d_out;

    const size_t need = (size_t)WS_HALVES * sizeof(_Float16);

    if (ws_size >= need) {
        _Float16* ws = (_Float16*)d_ws;
        hipLaunchKernelGGL(prep_big, dim3(NH, 2), dim3(NH), 0, stream, W2, W3, ws);
        hipLaunchKernelGGL(prep_small, dim3(1), dim3(NH), 0, stream, W1, W4, ws);
        hipLaunchKernelGGL(comet_mfma, dim3(BATCH / EPB), dim3(512), 0, stream,
                           Z, W4, ws, OUT);
    } else {
        hipLaunchKernelGGL(comet_fused_f32, dim3(BATCH / 16), dim3(256), 0, stream,
                           Z, W1, W2, W3, W4, OUT);
    }
}